// Round 3
// baseline (226.934 us; speedup 1.0000x reference)
//
#include <hip/hip_runtime.h>
#include <hip/hip_bf16.h>

#define BLOCK 512
#define IPB 8            // images per block
#define FB_STRIDE 1608   // featbuf row stride in shorts: 804 dwords = 4 mod 32 -> conflict-free

typedef __attribute__((ext_vector_type(8))) short short8;
typedef __attribute__((ext_vector_type(4))) float f32x4;

static __device__ __forceinline__ unsigned short f2bf(float f) {
    unsigned int u = __builtin_bit_cast(unsigned int, f);
    u = (u + 0x7FFFu + ((u >> 16) & 1u)) >> 16;   // RNE
    return (unsigned short)u;
}

// ---------------- prep kernel: build bf16 weight layouts in d_ws ----------------
// ws[0 .. 18432)            : w2t [kpos=9][oc=64][ic=32] bf16
// ws[18432 .. 18432+102400) : ewt [ks=50][n=64][k=32] bf16 (n<50 experts, 50..54 gate, rest 0)
__global__ void moe_prep(const float* __restrict__ w2, const float* __restrict__ gw,
                         const float* __restrict__ ew, unsigned short* __restrict__ ws) {
    int i = blockIdx.x * 256 + threadIdx.x;
    if (i < 18432) {
        int kpos = i >> 11, rem = i & 2047, oc = rem >> 5, ic = rem & 31;
        ws[i] = f2bf(w2[(kpos * 32 + ic) * 64 + oc]);
    }
    int j = i - 18432;
    if (j >= 0 && j < 102400) {
        int ks = j >> 11, rem = j & 2047, n = rem >> 5, k = rem & 31;
        int d = ks * 32 + k;
        float v = 0.f;
        if (n < 50)      v = ew[(n / 10) * 16000 + d * 10 + (n % 10)];
        else if (n < 55) v = gw[d * 5 + (n - 50)];
        ws[18432 + j] = f2bf(v);
    }
}

// ---------------- main fused kernel ----------------
__global__ __launch_bounds__(BLOCK, 6)
void moe_main(const float* __restrict__ x, const float* __restrict__ w1,
              const float* __restrict__ b1, const float* __restrict__ b2,
              const float* __restrict__ gb, const float* __restrict__ eb,
              const unsigned short* __restrict__ ws, float* __restrict__ out, int B)
{
    __shared__ float xs[2][784];                              // 6272 B, fp32 double-buffered
    __shared__ __align__(16) unsigned short h1p[6760];        // [169][40] bf16, 13520 B
    __shared__ __align__(16) unsigned short featbuf[IPB * FB_STRIDE]; // 25728 B
    __shared__ float w1s[288];
    __shared__ float b1s[32];
    __shared__ float b2s[64];
    __shared__ float allC[2][448];                            // split-K halves, [8 img][56]

    const int tid  = threadIdx.x;
    const int wid  = tid >> 6;
    const int lane = tid & 63;
    const int l15  = lane & 15;
    const int lg   = lane >> 4;
    const int nt   = wid & 3;   // conv2 N-tile (16 oc) owned by this wave
    const int mh   = wid >> 2;  // conv2 M-half

    // -------- per-block setup --------
    for (int i = tid; i < 288; i += BLOCK) w1s[i] = w1[i];
    if (tid < 32) b1s[tid] = b1[tid];
    if (tid < 64) b2s[tid] = b2[tid];

    // conv2 B fragments straight from global (coalesced 1KB/wave, L2-resident)
    short8 bfrag[9];
    #pragma unroll
    for (int kp = 0; kp < 9; kp++)
        bfrag[kp] = *(const short8*)&ws[(kp * 64 + nt * 16 + l15) * 32 + lg * 8];

    const int img0 = blockIdx.x * IPB;
    {   // stage first image (fp32)
        int im = img0 < B ? img0 : B - 1;
        const float* xg = x + (size_t)im * 784;
        for (int i = tid; i < 784; i += BLOCK) xs[0][i] = xg[i];
    }
    __syncthreads();

    for (int it = 0; it < IPB; ++it) {
        const int cur = it & 1;

        // -------- conv1 (fp32) + relu + pool -> h1p[169][40] bf16 --------
        {
            const int g = tid & 7;
            #pragma unroll
            for (int round = 0; round < 3; ++round) {
                const int pidx = round * 64 + (tid >> 3);
                if (pidx < 169) {
                    const int py = pidx / 13, px = pidx % 13;
                    float xr[4][4];
                    #pragma unroll
                    for (int r = 0; r < 4; r++) {
                        const int base = (2 * py + r) * 28 + 2 * px;
                        const float2 a = *(const float2*)&xs[cur][base];
                        const float2 b = *(const float2*)&xs[cur][base + 2];
                        xr[r][0] = a.x; xr[r][1] = a.y; xr[r][2] = b.x; xr[r][3] = b.y;
                    }
                    float acc[4][4];
                    #pragma unroll
                    for (int wdw = 0; wdw < 4; wdw++)
                        #pragma unroll
                        for (int j = 0; j < 4; j++) acc[wdw][j] = 0.f;
                    #pragma unroll
                    for (int ky = 0; ky < 3; ky++) {
                        #pragma unroll
                        for (int kx = 0; kx < 3; kx++) {
                            const float4 w4 = *(const float4*)&w1s[(ky * 3 + kx) * 32 + g * 4];
                            #pragma unroll
                            for (int wy = 0; wy < 2; wy++) {
                                #pragma unroll
                                for (int wx = 0; wx < 2; wx++) {
                                    const float xv = xr[wy + ky][wx + kx];
                                    acc[wy * 2 + wx][0] += w4.x * xv;
                                    acc[wy * 2 + wx][1] += w4.y * xv;
                                    acc[wy * 2 + wx][2] += w4.z * xv;
                                    acc[wy * 2 + wx][3] += w4.w * xv;
                                }
                            }
                        }
                    }
                    unsigned short o[4];
                    #pragma unroll
                    for (int j = 0; j < 4; j++) {
                        float m = fmaxf(fmaxf(acc[0][j], acc[1][j]), fmaxf(acc[2][j], acc[3][j]))
                                  + b1s[g * 4 + j];
                        o[j] = f2bf(fmaxf(m, 0.f));
                    }
                    uint2 pk;
                    pk.x = (unsigned int)o[0] | ((unsigned int)o[1] << 16);
                    pk.y = (unsigned int)o[2] | ((unsigned int)o[3] << 16);
                    *(uint2*)&h1p[pidx * 40 + g * 4] = pk;
                }
            }
        }
        __syncthreads();

        // -------- conv2 phase: prefetch next x, then implicit-GEMM MFMA --------
        if (it + 1 < IPB) {
            int im = img0 + it + 1; if (im >= B) im = B - 1;
            const float* xg = x + (size_t)im * 784;
            for (int i = tid; i < 784; i += BLOCK) xs[cur ^ 1][i] = xg[i];
        }
        for (int mt = mh; mt < 7; mt += 2) {
            const int m = mt * 16 + l15;
            int wsrc = m >> 2; if (wsrc > 24) wsrc = 24;
            const int s = m & 3;
            const int cy = 2 * (wsrc / 5) + (s >> 1);
            const int cx = 2 * (wsrc % 5) + (s & 1);
            short8 afrag[9];
            #pragma unroll
            for (int ky = 0; ky < 3; ky++)
                #pragma unroll
                for (int kx = 0; kx < 3; kx++)
                    afrag[ky * 3 + kx] =
                        *(const short8*)&h1p[((cy + ky) * 13 + (cx + kx)) * 40 + lg * 8];
            f32x4 acc = {0.f, 0.f, 0.f, 0.f};
            #pragma unroll
            for (int kp = 0; kp < 9; kp++)
                acc = __builtin_amdgcn_mfma_f32_16x16x32_bf16(afrag[kp], bfrag[kp], acc, 0, 0, 0);
            const int wv = mt * 4 + lg;     // pool window this lane's acc belongs to
            if (wv < 25) {
                const int oc = nt * 16 + l15;
                float mx = fmaxf(fmaxf(acc.x, acc.y), fmaxf(acc.z, acc.w)) + b2s[oc];
                featbuf[it * FB_STRIDE + wv * 64 + oc] = f2bf(fmaxf(mx, 0.f));
            }
        }
        __syncthreads();
    } // it

    // -------- experts + gate GEMM, split-K over 8 waves: [8 x 1600] @ [1600 x 55] --------
    {
        const unsigned short* ewt = ws + 18432;
        const int kh = wid >> 2;            // K-half
        const int bc = nt * 16 + l15;       // output col
        const int arow = l15 & 7;           // image row (rows 8-15 duplicated)
        f32x4 acc = {0.f, 0.f, 0.f, 0.f};
        const int ks0 = kh * 25;
        for (int ks = ks0; ks < ks0 + 25; ++ks) {
            short8 af = *(const short8*)&featbuf[arow * FB_STRIDE + ks * 32 + lg * 8];
            short8 bf = *(const short8*)&ewt[(ks * 64 + bc) * 32 + lg * 8];
            acc = __builtin_amdgcn_mfma_f32_16x16x32_bf16(af, bf, acc, 0, 0, 0);
        }
        if (lane < 32 && bc < 56) {         // rows 0..7, cols 0..55
            const int r0 = lg * 4;
            allC[kh][(r0 + 0) * 56 + bc] = acc.x;
            allC[kh][(r0 + 1) * 56 + bc] = acc.y;
            allC[kh][(r0 + 2) * 56 + bc] = acc.z;
            allC[kh][(r0 + 3) * 56 + bc] = acc.w;
        }
    }
    __syncthreads();

    // -------- epilogue: gate softmax, top-3, combine, final softmax --------
    if (tid < 8) {
        const int img = img0 + tid;
        if (img < B) {
            float gv[5], mx = -1e30f;
            #pragma unroll
            for (int g = 0; g < 5; g++) {
                gv[g] = allC[0][tid * 56 + 50 + g] + allC[1][tid * 56 + 50 + g] + gb[g];
                mx = fmaxf(mx, gv[g]);
            }
            float ssum = 0.f;
            #pragma unroll
            for (int g = 0; g < 5; g++) { gv[g] = expf(gv[g] - mx); ssum += gv[g]; }
            const float inv = 1.f / ssum;
            #pragma unroll
            for (int g = 0; g < 5; g++) gv[g] *= inv;

            int idx[3]; float wv[3];
            bool used[5] = {false, false, false, false, false};
            for (int k = 0; k < 3; k++) {
                int bi = 0; float bv = -1e30f;
                for (int g = 0; g < 5; g++)
                    if (!used[g] && gv[g] > bv) { bv = gv[g]; bi = g; }  // strict >: lowest idx on tie
                used[bi] = true; idx[k] = bi; wv[k] = bv;
            }
            float comb[10];
            #pragma unroll
            for (int cc = 0; cc < 10; cc++) {
                float s = 0.f;
                for (int k = 0; k < 3; k++)
                    s += wv[k] * (allC[0][tid * 56 + idx[k] * 10 + cc]
                                + allC[1][tid * 56 + idx[k] * 10 + cc]
                                + eb[idx[k] * 10 + cc]);
                comb[cc] = s;
            }
            float m2 = -1e30f;
            #pragma unroll
            for (int cc = 0; cc < 10; cc++) m2 = fmaxf(m2, comb[cc]);
            float e[10], s2 = 0.f;
            #pragma unroll
            for (int cc = 0; cc < 10; cc++) { e[cc] = expf(comb[cc] - m2); s2 += e[cc]; }
            const float inv2 = 1.f / s2;
            #pragma unroll
            for (int cc = 0; cc < 10; cc++) out[(size_t)img * 10 + cc] = e[cc] * inv2;
        }
    }
}

// ---------------- fallback (round-1 style, used only if ws too small) ----------------
__global__ __launch_bounds__(BLOCK, 1)
void moe_fused_fallback(const float* __restrict__ x, const float* __restrict__ w1,
                        const float* __restrict__ b1, const float* __restrict__ w2,
                        const float* __restrict__ b2, const float* __restrict__ gw,
                        const float* __restrict__ gb, const float* __restrict__ ew,
                        const float* __restrict__ eb, float* __restrict__ out)
{
    __shared__ float xs[784];
    __shared__ float w1s[288];
    __shared__ float b1s[32];
    __shared__ float w2s[18432];
    __shared__ float b2s[64];
    __shared__ float h1[5408];
    __shared__ float feat[1600];
    __shared__ float allout[5][10];
    __shared__ float gsm[5];

    const int tid = threadIdx.x;
    const int img = blockIdx.x;
    const float* xg = x + img * 784;
    for (int i = tid; i < 784; i += BLOCK) xs[i] = xg[i];
    for (int i = tid; i < 288; i += BLOCK) w1s[i] = w1[i];
    if (tid < 32) b1s[tid] = b1[tid];
    for (int i = tid; i < 18432; i += BLOCK) w2s[i] = w2[i];
    if (tid < 64) b2s[tid] = b2[tid];
    __syncthreads();

    for (int i = tid; i < 5408; i += BLOCK) {
        const int oc = i & 31, sp = i >> 5, px = sp % 13, py = sp / 13;
        float a0 = 0.f, a1 = 0.f, a2 = 0.f, a3 = 0.f;
        #pragma unroll
        for (int ky = 0; ky < 3; ky++)
            #pragma unroll
            for (int kx = 0; kx < 3; kx++) {
                const float w = w1s[(ky * 3 + kx) * 32 + oc];
                const int r0 = 2 * py + ky, c0 = 2 * px + kx;
                a0 += w * xs[r0 * 28 + c0];       a1 += w * xs[r0 * 28 + c0 + 1];
                a2 += w * xs[(r0 + 1) * 28 + c0]; a3 += w * xs[(r0 + 1) * 28 + c0 + 1];
            }
        h1[i] = fmaxf(fmaxf(fmaxf(a0, a1), fmaxf(a2, a3)) + b1s[oc], 0.f);
    }
    __syncthreads();

    for (int i = tid; i < 1600; i += BLOCK) {
        const int oc = i & 63, sp = i >> 6, px = sp % 5, py = sp / 5;
        float a0 = 0.f, a1 = 0.f, a2 = 0.f, a3 = 0.f;
        #pragma unroll
        for (int ky = 0; ky < 3; ky++)
            #pragma unroll
            for (int kx = 0; kx < 3; kx++) {
                const int hb = ((2 * py + ky) * 13 + (2 * px + kx)) * 32;
                const float* wrow = &w2s[((ky * 3 + kx) * 32) * 64 + oc];
                #pragma unroll 8
                for (int ic = 0; ic < 32; ic++) {
                    const float w = wrow[ic * 64];
                    a0 += w * h1[hb + ic];        a1 += w * h1[hb + 32 + ic];
                    a2 += w * h1[hb + 416 + ic];  a3 += w * h1[hb + 448 + ic];
                }
            }
        feat[i] = fmaxf(fmaxf(fmaxf(a0, a1), fmaxf(a2, a3)) + b2s[oc], 0.f);
    }
    __syncthreads();

    const int wid = tid >> 6, lane = tid & 63;
    if (wid < 5) {
        const float* ewp = ew + wid * 16000;
        float acc[10];
        #pragma unroll
        for (int c = 0; c < 10; c++) acc[c] = 0.f;
        for (int d = lane; d < 1600; d += 64) {
            const float f = feat[d]; const float* wr = ewp + d * 10;
            #pragma unroll
            for (int c = 0; c < 10; c++) acc[c] += f * wr[c];
        }
        #pragma unroll
        for (int c = 0; c < 10; c++)
            for (int off = 32; off; off >>= 1) acc[c] += __shfl_down(acc[c], off);
        if (lane == 0)
            #pragma unroll
            for (int c = 0; c < 10; c++) allout[wid][c] = acc[c] + eb[wid * 10 + c];
    } else if (wid == 5) {
        float acc[5] = {0.f, 0.f, 0.f, 0.f, 0.f};
        for (int d = lane; d < 1600; d += 64) {
            const float f = feat[d]; const float* wr = gw + d * 5;
            #pragma unroll
            for (int g = 0; g < 5; g++) acc[g] += f * wr[g];
        }
        #pragma unroll
        for (int g = 0; g < 5; g++)
            for (int off = 32; off; off >>= 1) acc[g] += __shfl_down(acc[g], off);
        if (lane == 0) {
            float l[5], mx = -1e30f;
            #pragma unroll
            for (int g = 0; g < 5; g++) { l[g] = acc[g] + gb[g]; mx = fmaxf(mx, l[g]); }
            float s = 0.f;
            #pragma unroll
            for (int g = 0; g < 5; g++) { l[g] = expf(l[g] - mx); s += l[g]; }
            const float inv = 1.f / s;
            #pragma unroll
            for (int g = 0; g < 5; g++) gsm[g] = l[g] * inv;
        }
    }
    __syncthreads();

    if (tid == 0) {
        float gv[5];
        #pragma unroll
        for (int g = 0; g < 5; g++) gv[g] = gsm[g];
        int idx[3]; float wv[3];
        bool used[5] = {false, false, false, false, false};
        for (int k = 0; k < 3; k++) {
            int bi = 0; float bv = -1e30f;
            for (int g = 0; g < 5; g++)
                if (!used[g] && gv[g] > bv) { bv = gv[g]; bi = g; }
            used[bi] = true; idx[k] = bi; wv[k] = bv;
        }
        float comb[10];
        #pragma unroll
        for (int cc = 0; cc < 10; cc++) {
            float s = 0.f;
            for (int k = 0; k < 3; k++) s += wv[k] * allout[idx[k]][cc];
            comb[cc] = s;
        }
        float mx = -1e30f;
        #pragma unroll
        for (int cc = 0; cc < 10; cc++) mx = fmaxf(mx, comb[cc]);
        float e[10], s = 0.f;
        #pragma unroll
        for (int cc = 0; cc < 10; cc++) { e[cc] = expf(comb[cc] - mx); s += e[cc]; }
        const float inv = 1.f / s;
        #pragma unroll
        for (int cc = 0; cc < 10; cc++) out[img * 10 + cc] = e[cc] * inv;
    }
}

extern "C" void kernel_launch(void* const* d_in, const int* in_sizes, int n_in,
                              void* d_out, int out_size, void* d_ws, size_t ws_size,
                              hipStream_t stream) {
    const float* x   = (const float*)d_in[0];
    const float* w1  = (const float*)d_in[1];
    const float* b1  = (const float*)d_in[2];
    const float* w2  = (const float*)d_in[3];
    const float* b2  = (const float*)d_in[4];
    const float* gw  = (const float*)d_in[5];
    const float* gb  = (const float*)d_in[6];
    const float* ew  = (const float*)d_in[7];
    const float* eb  = (const float*)d_in[8];
    float* out = (float*)d_out;
    const int B = in_sizes[0] / 784;

    const size_t WS_NEEDED = (18432 + 102400) * sizeof(unsigned short);
    if (ws_size >= WS_NEEDED) {
        unsigned short* ws = (unsigned short*)d_ws;
        moe_prep<<<472, 256, 0, stream>>>(w2, gw, ew, ws);
        const int nblk = (B + IPB - 1) / IPB;
        moe_main<<<nblk, BLOCK, 0, stream>>>(x, w1, b1, b2, gb, eb, ws, out, B);
    } else {
        moe_fused_fallback<<<B, BLOCK, 0, stream>>>(x, w1, b1, w2, b2, gw, gb, ew, eb, out);
    }
}

// Round 4
// 153.822 us; speedup vs baseline: 1.4753x; 1.4753x over previous
//
#include <hip/hip_runtime.h>
#include <hip/hip_bf16.h>

#define BLOCK 512
#define IPB 8            // images per block
#define FB_STRIDE 1608   // featbuf row stride in shorts: 804 dwords = 4 mod 32 -> conflict-free

typedef __attribute__((ext_vector_type(8))) short short8;
typedef __attribute__((ext_vector_type(4))) float f32x4;

static __device__ __forceinline__ unsigned short f2bf(float f) {
    unsigned int u = __builtin_bit_cast(unsigned int, f);
    u = (u + 0x7FFFu + ((u >> 16) & 1u)) >> 16;   // RNE
    return (unsigned short)u;
}

// ---------------- prep kernel: build bf16 weight layouts in d_ws ----------------
// ws[0 .. 18432)            : w2t [kpos=9][oc=64][ic=32] bf16
// ws[18432 .. 18432+102400) : ewt [ks=50][n=64][k=32] bf16 (n<50 experts, 50..54 gate, rest 0)
__global__ void moe_prep(const float* __restrict__ w2, const float* __restrict__ gw,
                         const float* __restrict__ ew, unsigned short* __restrict__ ws) {
    int i = blockIdx.x * 256 + threadIdx.x;
    if (i < 18432) {
        int kpos = i >> 11, rem = i & 2047, oc = rem >> 5, ic = rem & 31;
        ws[i] = f2bf(w2[(kpos * 32 + ic) * 64 + oc]);
    }
    int j = i - 18432;
    if (j >= 0 && j < 102400) {
        int ks = j >> 11, rem = j & 2047, n = rem >> 5, k = rem & 31;
        int d = ks * 32 + k;
        float v = 0.f;
        if (n < 50)      v = ew[(n / 10) * 16000 + d * 10 + (n % 10)];
        else if (n < 55) v = gw[d * 5 + (n - 50)];
        ws[18432 + j] = f2bf(v);
    }
}

// ---------------- main fused kernel ----------------
// NOTE: on this toolchain __launch_bounds__ arg2 behaves as min BLOCKS/CU
// (evidence: VGPR caps 64@N=4, 40@N=6 == 2048/(N*8 waves)). N=2 -> 128-reg cap.
__global__ __launch_bounds__(BLOCK, 2)
void moe_main(const float* __restrict__ x, const float* __restrict__ w1,
              const float* __restrict__ b1, const float* __restrict__ b2,
              const float* __restrict__ gb, const float* __restrict__ eb,
              const unsigned short* __restrict__ ws, float* __restrict__ out, int B)
{
    __shared__ float xs[2][784];                              // 6272 B, fp32 double-buffered
    __shared__ __align__(16) unsigned short h1p[6760];        // [169][40] bf16, 13520 B
    __shared__ __align__(16) unsigned short featbuf[IPB * FB_STRIDE]; // 25728 B
    __shared__ float w1s[288];
    __shared__ float b1s[32];
    __shared__ float b2s[64];
    __shared__ float allC[2][448];                            // split-K halves, [8 img][56]

    const int tid  = threadIdx.x;
    const int wid  = tid >> 6;
    const int lane = tid & 63;
    const int l15  = lane & 15;
    const int lg   = lane >> 4;
    const int nt   = wid & 3;   // conv2 N-tile (16 oc) owned by this wave
    const int mh   = wid >> 2;  // conv2 M-half

    // -------- per-block setup --------
    for (int i = tid; i < 288; i += BLOCK) w1s[i] = w1[i];
    if (tid < 32) b1s[tid] = b1[tid];
    if (tid < 64) b2s[tid] = b2[tid];

    // conv2 B fragments straight from global (coalesced 1KB/wave, L2-resident)
    short8 bfrag[9];
    #pragma unroll
    for (int kp = 0; kp < 9; kp++)
        bfrag[kp] = *(const short8*)&ws[(kp * 64 + nt * 16 + l15) * 32 + lg * 8];

    const int img0 = blockIdx.x * IPB;
    {   // stage first image (fp32)
        int im = img0 < B ? img0 : B - 1;
        const float* xg = x + (size_t)im * 784;
        for (int i = tid; i < 784; i += BLOCK) xs[0][i] = xg[i];
    }
    __syncthreads();

    for (int it = 0; it < IPB; ++it) {
        const int cur = it & 1;

        // -------- conv1 (fp32) + relu + pool -> h1p[169][40] bf16 --------
        {
            const int g = tid & 7;
            #pragma unroll
            for (int round = 0; round < 3; ++round) {
                const int pidx = round * 64 + (tid >> 3);
                if (pidx < 169) {
                    const int py = pidx / 13, px = pidx % 13;
                    float xr[4][4];
                    #pragma unroll
                    for (int r = 0; r < 4; r++) {
                        const int base = (2 * py + r) * 28 + 2 * px;
                        const float2 a = *(const float2*)&xs[cur][base];
                        const float2 b = *(const float2*)&xs[cur][base + 2];
                        xr[r][0] = a.x; xr[r][1] = a.y; xr[r][2] = b.x; xr[r][3] = b.y;
                    }
                    float acc[4][4];
                    #pragma unroll
                    for (int wdw = 0; wdw < 4; wdw++)
                        #pragma unroll
                        for (int j = 0; j < 4; j++) acc[wdw][j] = 0.f;
                    #pragma unroll
                    for (int ky = 0; ky < 3; ky++) {
                        #pragma unroll
                        for (int kx = 0; kx < 3; kx++) {
                            const float4 w4 = *(const float4*)&w1s[(ky * 3 + kx) * 32 + g * 4];
                            #pragma unroll
                            for (int wy = 0; wy < 2; wy++) {
                                #pragma unroll
                                for (int wx = 0; wx < 2; wx++) {
                                    const float xv = xr[wy + ky][wx + kx];
                                    acc[wy * 2 + wx][0] += w4.x * xv;
                                    acc[wy * 2 + wx][1] += w4.y * xv;
                                    acc[wy * 2 + wx][2] += w4.z * xv;
                                    acc[wy * 2 + wx][3] += w4.w * xv;
                                }
                            }
                        }
                    }
                    unsigned short o[4];
                    #pragma unroll
                    for (int j = 0; j < 4; j++) {
                        float m = fmaxf(fmaxf(acc[0][j], acc[1][j]), fmaxf(acc[2][j], acc[3][j]))
                                  + b1s[g * 4 + j];
                        o[j] = f2bf(fmaxf(m, 0.f));
                    }
                    uint2 pk;
                    pk.x = (unsigned int)o[0] | ((unsigned int)o[1] << 16);
                    pk.y = (unsigned int)o[2] | ((unsigned int)o[3] << 16);
                    *(uint2*)&h1p[pidx * 40 + g * 4] = pk;
                }
            }
        }
        __syncthreads();

        // -------- conv2 phase: prefetch next x, then implicit-GEMM MFMA --------
        if (it + 1 < IPB) {
            int im = img0 + it + 1; if (im >= B) im = B - 1;
            const float* xg = x + (size_t)im * 784;
            for (int i = tid; i < 784; i += BLOCK) xs[cur ^ 1][i] = xg[i];
        }
        for (int mt = mh; mt < 7; mt += 2) {
            const int m = mt * 16 + l15;
            int wsrc = m >> 2; if (wsrc > 24) wsrc = 24;
            const int s = m & 3;
            const int cy = 2 * (wsrc / 5) + (s >> 1);
            const int cx = 2 * (wsrc % 5) + (s & 1);
            short8 afrag[9];
            #pragma unroll
            for (int ky = 0; ky < 3; ky++)
                #pragma unroll
                for (int kx = 0; kx < 3; kx++)
                    afrag[ky * 3 + kx] =
                        *(const short8*)&h1p[((cy + ky) * 13 + (cx + kx)) * 40 + lg * 8];
            f32x4 acc = {0.f, 0.f, 0.f, 0.f};
            #pragma unroll
            for (int kp = 0; kp < 9; kp++)
                acc = __builtin_amdgcn_mfma_f32_16x16x32_bf16(afrag[kp], bfrag[kp], acc, 0, 0, 0);
            const int wv = mt * 4 + lg;     // pool window this lane's acc belongs to
            if (wv < 25) {
                const int oc = nt * 16 + l15;
                float mx = fmaxf(fmaxf(acc.x, acc.y), fmaxf(acc.z, acc.w)) + b2s[oc];
                featbuf[it * FB_STRIDE + wv * 64 + oc] = f2bf(fmaxf(mx, 0.f));
            }
        }
        __syncthreads();
    } // it

    // -------- experts + gate GEMM, split-K over 8 waves: [8 x 1600] @ [1600 x 55] --------
    {
        const unsigned short* ewt = ws + 18432;
        const int kh = wid >> 2;            // K-half
        const int bc = nt * 16 + l15;       // output col
        const int arow = l15 & 7;           // image row (rows 8-15 duplicated)
        f32x4 acc = {0.f, 0.f, 0.f, 0.f};
        const int ks0 = kh * 25;
        for (int ks = ks0; ks < ks0 + 25; ++ks) {
            short8 af = *(const short8*)&featbuf[arow * FB_STRIDE + ks * 32 + lg * 8];
            short8 bf = *(const short8*)&ewt[(ks * 64 + bc) * 32 + lg * 8];
            acc = __builtin_amdgcn_mfma_f32_16x16x32_bf16(af, bf, acc, 0, 0, 0);
        }
        if (lane < 32 && bc < 56) {         // rows 0..7, cols 0..55
            const int r0 = lg * 4;
            allC[kh][(r0 + 0) * 56 + bc] = acc.x;
            allC[kh][(r0 + 1) * 56 + bc] = acc.y;
            allC[kh][(r0 + 2) * 56 + bc] = acc.z;
            allC[kh][(r0 + 3) * 56 + bc] = acc.w;
        }
    }
    __syncthreads();

    // -------- epilogue: gate softmax, top-3 (bitmask, no local arrays), combine, softmax --------
    if (tid < 8) {
        const int img = img0 + tid;
        if (img < B) {
            float gv[5], mx = -1e30f;
            #pragma unroll
            for (int g = 0; g < 5; g++) {
                gv[g] = allC[0][tid * 56 + 50 + g] + allC[1][tid * 56 + 50 + g] + gb[g];
                mx = fmaxf(mx, gv[g]);
            }
            float ssum = 0.f;
            #pragma unroll
            for (int g = 0; g < 5; g++) { gv[g] = expf(gv[g] - mx); ssum += gv[g]; }
            const float inv = 1.f / ssum;
            #pragma unroll
            for (int g = 0; g < 5; g++) gv[g] *= inv;

            int idx0, idx1, idx2; float wv0, wv1, wv2;
            unsigned usedMask = 0;
            {
                int bi = 0; float bv = -1e30f;
                #pragma unroll
                for (int g = 0; g < 5; g++)
                    if (gv[g] > bv) { bv = gv[g]; bi = g; }   // strict >: lowest idx on tie
                idx0 = bi; wv0 = bv; usedMask |= (1u << bi);
            }
            {
                int bi = 0; float bv = -1e30f;
                #pragma unroll
                for (int g = 0; g < 5; g++)
                    if (!(usedMask & (1u << g)) && gv[g] > bv) { bv = gv[g]; bi = g; }
                idx1 = bi; wv1 = bv; usedMask |= (1u << bi);
            }
            {
                int bi = 0; float bv = -1e30f;
                #pragma unroll
                for (int g = 0; g < 5; g++)
                    if (!(usedMask & (1u << g)) && gv[g] > bv) { bv = gv[g]; bi = g; }
                idx2 = bi; wv2 = bv;
            }
            float comb[10];
            #pragma unroll
            for (int cc = 0; cc < 10; cc++) {
                comb[cc] = wv0 * (allC[0][tid * 56 + idx0 * 10 + cc] + allC[1][tid * 56 + idx0 * 10 + cc] + eb[idx0 * 10 + cc])
                         + wv1 * (allC[0][tid * 56 + idx1 * 10 + cc] + allC[1][tid * 56 + idx1 * 10 + cc] + eb[idx1 * 10 + cc])
                         + wv2 * (allC[0][tid * 56 + idx2 * 10 + cc] + allC[1][tid * 56 + idx2 * 10 + cc] + eb[idx2 * 10 + cc]);
            }
            float m2 = -1e30f;
            #pragma unroll
            for (int cc = 0; cc < 10; cc++) m2 = fmaxf(m2, comb[cc]);
            float e[10], s2 = 0.f;
            #pragma unroll
            for (int cc = 0; cc < 10; cc++) { e[cc] = expf(comb[cc] - m2); s2 += e[cc]; }
            const float inv2 = 1.f / s2;
            #pragma unroll
            for (int cc = 0; cc < 10; cc++) out[(size_t)img * 10 + cc] = e[cc] * inv2;
        }
    }
}

// ---------------- fallback (round-1 style, used only if ws too small) ----------------
__global__ __launch_bounds__(BLOCK, 1)
void moe_fused_fallback(const float* __restrict__ x, const float* __restrict__ w1,
                        const float* __restrict__ b1, const float* __restrict__ w2,
                        const float* __restrict__ b2, const float* __restrict__ gw,
                        const float* __restrict__ gb, const float* __restrict__ ew,
                        const float* __restrict__ eb, float* __restrict__ out)
{
    __shared__ float xs[784];
    __shared__ float w1s[288];
    __shared__ float b1s[32];
    __shared__ float w2s[18432];
    __shared__ float b2s[64];
    __shared__ float h1[5408];
    __shared__ float feat[1600];
    __shared__ float allout[5][10];
    __shared__ float gsm[5];

    const int tid = threadIdx.x;
    const int img = blockIdx.x;
    const float* xg = x + img * 784;
    for (int i = tid; i < 784; i += BLOCK) xs[i] = xg[i];
    for (int i = tid; i < 288; i += BLOCK) w1s[i] = w1[i];
    if (tid < 32) b1s[tid] = b1[tid];
    for (int i = tid; i < 18432; i += BLOCK) w2s[i] = w2[i];
    if (tid < 64) b2s[tid] = b2[tid];
    __syncthreads();

    for (int i = tid; i < 5408; i += BLOCK) {
        const int oc = i & 31, sp = i >> 5, px = sp % 13, py = sp / 13;
        float a0 = 0.f, a1 = 0.f, a2 = 0.f, a3 = 0.f;
        #pragma unroll
        for (int ky = 0; ky < 3; ky++)
            #pragma unroll
            for (int kx = 0; kx < 3; kx++) {
                const float w = w1s[(ky * 3 + kx) * 32 + oc];
                const int r0 = 2 * py + ky, c0 = 2 * px + kx;
                a0 += w * xs[r0 * 28 + c0];       a1 += w * xs[r0 * 28 + c0 + 1];
                a2 += w * xs[(r0 + 1) * 28 + c0]; a3 += w * xs[(r0 + 1) * 28 + c0 + 1];
            }
        h1[i] = fmaxf(fmaxf(fmaxf(a0, a1), fmaxf(a2, a3)) + b1s[oc], 0.f);
    }
    __syncthreads();

    for (int i = tid; i < 1600; i += BLOCK) {
        const int oc = i & 63, sp = i >> 6, px = sp % 5, py = sp / 5;
        float a0 = 0.f, a1 = 0.f, a2 = 0.f, a3 = 0.f;
        #pragma unroll
        for (int ky = 0; ky < 3; ky++)
            #pragma unroll
            for (int kx = 0; kx < 3; kx++) {
                const int hb = ((2 * py + ky) * 13 + (2 * px + kx)) * 32;
                const float* wrow = &w2s[((ky * 3 + kx) * 32) * 64 + oc];
                #pragma unroll 8
                for (int ic = 0; ic < 32; ic++) {
                    const float w = wrow[ic * 64];
                    a0 += w * h1[hb + ic];        a1 += w * h1[hb + 32 + ic];
                    a2 += w * h1[hb + 416 + ic];  a3 += w * h1[hb + 448 + ic];
                }
            }
        feat[i] = fmaxf(fmaxf(fmaxf(a0, a1), fmaxf(a2, a3)) + b2s[oc], 0.f);
    }
    __syncthreads();

    const int wid = tid >> 6, lane = tid & 63;
    if (wid < 5) {
        const float* ewp = ew + wid * 16000;
        float acc[10];
        #pragma unroll
        for (int c = 0; c < 10; c++) acc[c] = 0.f;
        for (int d = lane; d < 1600; d += 64) {
            const float f = feat[d]; const float* wr = ewp + d * 10;
            #pragma unroll
            for (int c = 0; c < 10; c++) acc[c] += f * wr[c];
        }
        #pragma unroll
        for (int c = 0; c < 10; c++)
            for (int off = 32; off; off >>= 1) acc[c] += __shfl_down(acc[c], off);
        if (lane == 0)
            #pragma unroll
            for (int c = 0; c < 10; c++) allout[wid][c] = acc[c] + eb[wid * 10 + c];
    } else if (wid == 5) {
        float acc[5] = {0.f, 0.f, 0.f, 0.f, 0.f};
        for (int d = lane; d < 1600; d += 64) {
            const float f = feat[d]; const float* wr = gw + d * 5;
            #pragma unroll
            for (int g = 0; g < 5; g++) acc[g] += f * wr[g];
        }
        #pragma unroll
        for (int g = 0; g < 5; g++)
            for (int off = 32; off; off >>= 1) acc[g] += __shfl_down(acc[g], off);
        if (lane == 0) {
            float l[5], mx = -1e30f;
            #pragma unroll
            for (int g = 0; g < 5; g++) { l[g] = acc[g] + gb[g]; mx = fmaxf(mx, l[g]); }
            float s = 0.f;
            #pragma unroll
            for (int g = 0; g < 5; g++) { l[g] = expf(l[g] - mx); s += l[g]; }
            const float inv = 1.f / s;
            #pragma unroll
            for (int g = 0; g < 5; g++) gsm[g] = l[g] * inv;
        }
    }
    __syncthreads();

    if (tid == 0) {
        float gv[5];
        #pragma unroll
        for (int g = 0; g < 5; g++) gv[g] = gsm[g];
        int idx0, idx1, idx2; float wv0, wv1, wv2;
        unsigned usedMask = 0;
        {
            int bi = 0; float bv = -1e30f;
            #pragma unroll
            for (int g = 0; g < 5; g++) if (gv[g] > bv) { bv = gv[g]; bi = g; }
            idx0 = bi; wv0 = bv; usedMask |= (1u << bi);
        }
        {
            int bi = 0; float bv = -1e30f;
            #pragma unroll
            for (int g = 0; g < 5; g++) if (!(usedMask & (1u << g)) && gv[g] > bv) { bv = gv[g]; bi = g; }
            idx1 = bi; wv1 = bv; usedMask |= (1u << bi);
        }
        {
            int bi = 0; float bv = -1e30f;
            #pragma unroll
            for (int g = 0; g < 5; g++) if (!(usedMask & (1u << g)) && gv[g] > bv) { bv = gv[g]; bi = g; }
            idx2 = bi; wv2 = bv;
        }
        float comb[10];
        #pragma unroll
        for (int cc = 0; cc < 10; cc++)
            comb[cc] = wv0 * allout[idx0][cc] + wv1 * allout[idx1][cc] + wv2 * allout[idx2][cc];
        float mx = -1e30f;
        #pragma unroll
        for (int cc = 0; cc < 10; cc++) mx = fmaxf(mx, comb[cc]);
        float e[10], s = 0.f;
        #pragma unroll
        for (int cc = 0; cc < 10; cc++) { e[cc] = expf(comb[cc] - mx); s += e[cc]; }
        const float inv = 1.f / s;
        #pragma unroll
        for (int cc = 0; cc < 10; cc++) out[img * 10 + cc] = e[cc] * inv;
    }
}

extern "C" void kernel_launch(void* const* d_in, const int* in_sizes, int n_in,
                              void* d_out, int out_size, void* d_ws, size_t ws_size,
                              hipStream_t stream) {
    const float* x   = (const float*)d_in[0];
    const float* w1  = (const float*)d_in[1];
    const float* b1  = (const float*)d_in[2];
    const float* w2  = (const float*)d_in[3];
    const float* b2  = (const float*)d_in[4];
    const float* gw  = (const float*)d_in[5];
    const float* gb  = (const float*)d_in[6];
    const float* ew  = (const float*)d_in[7];
    const float* eb  = (const float*)d_in[8];
    float* out = (float*)d_out;
    const int B = in_sizes[0] / 784;

    const size_t WS_NEEDED = (18432 + 102400) * sizeof(unsigned short);
    if (ws_size >= WS_NEEDED) {
        unsigned short* ws = (unsigned short*)d_ws;
        moe_prep<<<472, 256, 0, stream>>>(w2, gw, ew, ws);
        const int nblk = (B + IPB - 1) / IPB;
        moe_main<<<nblk, BLOCK, 0, stream>>>(x, w1, b1, b2, gb, eb, ws, out, B);
    } else {
        moe_fused_fallback<<<B, BLOCK, 0, stream>>>(x, w1, b1, w2, b2, gw, gb, ew, eb, out);
    }
}

// Round 5
// 144.208 us; speedup vs baseline: 1.5737x; 1.0667x over previous
//
#include <hip/hip_runtime.h>
#include <hip/hip_bf16.h>

#define BLOCK 512
#define IPB 4            // images per block
#define FB_STRIDE 1608   // featbuf row stride in shorts: 804 dwords = 4 mod 32 -> conflict-free

// ws layout (shorts):
#define W2T_OFF 0        // [kpos=9][oc=64][ic=32]                     18432
#define EWT_OFF 18432    // [ks=50][n=64][k=32] experts+gate           102400
#define W1C_OFF 120832   // [n=32][k=32] conv1 hi/lo B matrix          1024
#define WS_SHORTS 121856

typedef __attribute__((ext_vector_type(8))) short short8;
typedef __attribute__((ext_vector_type(4))) float f32x4;

static __device__ __forceinline__ unsigned short f2bf(float f) {
    unsigned int u = __builtin_bit_cast(unsigned int, f);
    u = (u + 0x7FFFu + ((u >> 16) & 1u)) >> 16;   // RNE
    return (unsigned short)u;
}
static __device__ __forceinline__ float bf2f(unsigned short h) {
    unsigned int u = ((unsigned int)h) << 16;
    return __builtin_bit_cast(float, u);
}

// ---------------- prep kernel: build bf16 weight layouts in d_ws ----------------
__global__ void moe_prep(const float* __restrict__ w2, const float* __restrict__ gw,
                         const float* __restrict__ ew, const float* __restrict__ w1,
                         unsigned short* __restrict__ ws) {
    int i = blockIdx.x * 256 + threadIdx.x;
    if (i < 18432) {
        int kpos = i >> 11, rem = i & 2047, oc = rem >> 5, ic = rem & 31;
        ws[W2T_OFF + i] = f2bf(w2[(kpos * 32 + ic) * 64 + oc]);
    }
    int j = i - EWT_OFF;
    if (j >= 0 && j < 102400) {
        int ks = j >> 11, rem = j & 2047, n = rem >> 5, k = rem & 31;
        int d = ks * 32 + k;
        float v = 0.f;
        if (n < 50)      v = ew[(n / 10) * 16000 + d * 10 + (n % 10)];
        else if (n < 55) v = gw[d * 5 + (n - 50)];
        ws[EWT_OFF + j] = f2bf(v);
    }
    int p = i - W1C_OFF;
    if (p >= 0 && p < 1024) {
        // conv1 B: [n=32][k=32]; k 0-8: w1hi(tap k), 9-17: w1lo(tap k-9), 18-26: w1hi(tap k-18)
        int n = p >> 5, k = p & 31;
        unsigned short val = 0;
        if (k < 27) {
            int t = (k < 9) ? k : (k < 18 ? k - 9 : k - 18);
            float w = w1[t * 32 + n];
            unsigned short hi = f2bf(w);
            val = (k >= 9 && k < 18) ? f2bf(w - bf2f(hi)) : hi;
        }
        ws[W1C_OFF + p] = val;
    }
}

// ---------------- main fused kernel ----------------
// NOTE: this toolchain treats __launch_bounds__ arg2 as min BLOCKS/CU (CUDA semantics).
// N=2 -> 128-VGPR cap (verified: N=4 -> 64, N=6 -> 40, spills).
__global__ __launch_bounds__(BLOCK, 2)
void moe_main(const float* __restrict__ x, const float* __restrict__ b1,
              const float* __restrict__ b2, const float* __restrict__ gb,
              const float* __restrict__ eb, const unsigned short* __restrict__ ws,
              float* __restrict__ out, int B)
{
    __shared__ float xs[2][784];                               // 6272 B
    __shared__ __align__(16) unsigned short ic1[688 * 32];     // conv1 im2col, 44032 B
    __shared__ __align__(16) unsigned short h1p[6760];         // [169][40] bf16, 13520 B
    __shared__ __align__(16) unsigned short featbuf[IPB * FB_STRIDE]; // 12864 B
    __shared__ float b1s[32];
    __shared__ float b2s[64];
    __shared__ float allC[2][224];                             // split-K halves, [4 img][56]

    const int tid  = threadIdx.x;
    const int wid  = tid >> 6;
    const int lane = tid & 63;
    const int l15  = lane & 15;
    const int lg   = lane >> 4;

    if (tid < 32) b1s[tid] = b1[tid];
    if (tid < 64) b2s[tid] = b2[tid];

    // ---- conv2: wave owns M-tiles {mt0, mt0+4} x N-tiles {n0, n0+1}; bfrag persistent ----
    const int mt0 = wid >> 1;
    const int n0  = (wid & 1) * 2;
    short8 bfA[9], bfB[9];
    #pragma unroll
    for (int kp = 0; kp < 9; kp++) {
        bfA[kp] = *(const short8*)&ws[W2T_OFF + (kp * 64 + n0 * 16 + l15) * 32 + lg * 8];
        bfB[kp] = *(const short8*)&ws[W2T_OFF + (kp * 64 + (n0 + 1) * 16 + l15) * 32 + lg * 8];
    }
    // ---- conv1 B fragments (both 16-col tiles), persistent ----
    const short8 c1f0 = *(const short8*)&ws[W1C_OFF + l15 * 32 + lg * 8];
    const short8 c1f1 = *(const short8*)&ws[W1C_OFF + (16 + l15) * 32 + lg * 8];

    const int img0 = blockIdx.x * IPB;
    {   // stage first image (fp32)
        int im = img0 < B ? img0 : B - 1;
        const float* xg = x + (size_t)im * 784;
        for (int i = tid; i < 784; i += BLOCK) xs[0][i] = xg[i];
    }
    __syncthreads();

    // per-lane conv1 A-fragment byte offset within a 16-row tile (XOR-swizzled halves)
    const int ic1_rowoff = l15 * 64 + ((lg ^ ((l15 >> 1) & 3)) << 4);

    for (int it = 0; it < IPB; ++it) {
        const int cur = it & 1;

        // ---- phase 1: build ic1 (hi/lo im2col) + prefetch next x ----
        if (it + 1 < IPB) {
            int im = img0 + it + 1; if (im >= B) im = B - 1;
            const float* xg = x + (size_t)im * 784;
            for (int i = tid; i < 784; i += BLOCK) xs[cur ^ 1][i] = xg[i];
        }
        for (int m = tid; m < 676; m += BLOCK) {
            const int window = m >> 2, s = m & 3;
            const int wy = window / 13, wx = window - wy * 13;
            const int cy = 2 * wy + (s >> 1), cx = 2 * wx + (s & 1);
            const float* xb = &xs[cur][cy * 28 + cx];
            unsigned int xh[9], xl[9];
            #pragma unroll
            for (int t = 0; t < 9; t++) {
                const float v = xb[(t / 3) * 28 + (t % 3)];
                const unsigned short h = f2bf(v);
                xh[t] = h;
                xl[t] = f2bf(v - bf2f(h));
            }
            const unsigned int d0  = xh[0] | (xh[1] << 16);
            const unsigned int d1  = xh[2] | (xh[3] << 16);
            const unsigned int d2  = xh[4] | (xh[5] << 16);
            const unsigned int d3  = xh[6] | (xh[7] << 16);
            const unsigned int d4  = xh[8] | (xh[0] << 16);
            const unsigned int d5  = xh[1] | (xh[2] << 16);
            const unsigned int d6  = xh[3] | (xh[4] << 16);
            const unsigned int d7  = xh[5] | (xh[6] << 16);
            const unsigned int d8  = xh[7] | (xh[8] << 16);
            const unsigned int d9  = xl[0] | (xl[1] << 16);
            const unsigned int d10 = xl[2] | (xl[3] << 16);
            const unsigned int d11 = xl[4] | (xl[5] << 16);
            const unsigned int d12 = xl[6] | (xl[7] << 16);
            const unsigned int d13 = xl[8];
            char* base = (char*)ic1 + m * 64;
            const int sw = ((m >> 1) & 3) << 4;
            *(uint4*)(base + (0  ^ sw)) = make_uint4(d0, d1, d2, d3);
            *(uint4*)(base + (16 ^ sw)) = make_uint4(d4, d5, d6, d7);
            *(uint4*)(base + (32 ^ sw)) = make_uint4(d8, d9, d10, d11);
            *(uint4*)(base + (48 ^ sw)) = make_uint4(d12, d13, 0u, 0u);
        }
        __syncthreads();

        // ---- phase 2: conv1 MFMA (86 tiles) + pool + relu -> h1p ----
        #pragma unroll
        for (int i = 0; i < 11; ++i) {
            const int t = wid + (i << 3);
            if (t < 86) {
                const int mt = t >> 1, ntc = t & 1;
                const short8 af = *(const short8*)((const char*)ic1 + mt * 1024 + ic1_rowoff);
                f32x4 acc = {0.f, 0.f, 0.f, 0.f};
                acc = __builtin_amdgcn_mfma_f32_16x16x32_bf16(af, ntc ? c1f1 : c1f0, acc, 0, 0, 0);
                const int window = mt * 4 + lg;        // lane's 4 accs = 2x2 pool window
                if (window < 169) {
                    const int oc = ntc * 16 + l15;
                    const float m1 = fmaxf(fmaxf(acc.x, acc.y), fmaxf(acc.z, acc.w)) + b1s[oc];
                    h1p[window * 40 + oc] = f2bf(fmaxf(m1, 0.f));
                }
            }
        }
        __syncthreads();

        // ---- phase 3: conv2 implicit-GEMM (2 mt x 2 nt per wave) + pool -> featbuf ----
        #pragma unroll
        for (int mi = 0; mi < 2; ++mi) {
            const int mt = mt0 + mi * 4;
            const int m = mt * 16 + l15;
            int wsrc = m >> 2; if (wsrc > 24) wsrc = 24;
            const int s = m & 3;
            const int cy = 2 * (wsrc / 5) + (s >> 1);
            const int cx = 2 * (wsrc % 5) + (s & 1);
            const char* abase = (const char*)h1p + (cy * 13 + cx) * 80 + lg * 16;
            f32x4 a0 = {0.f, 0.f, 0.f, 0.f};
            f32x4 a1 = {0.f, 0.f, 0.f, 0.f};
            #pragma unroll
            for (int ky = 0; ky < 3; ky++) {
                #pragma unroll
                for (int kx = 0; kx < 3; kx++) {
                    const short8 af = *(const short8*)(abase + (ky * 13 + kx) * 80);
                    a0 = __builtin_amdgcn_mfma_f32_16x16x32_bf16(af, bfA[ky * 3 + kx], a0, 0, 0, 0);
                    a1 = __builtin_amdgcn_mfma_f32_16x16x32_bf16(af, bfB[ky * 3 + kx], a1, 0, 0, 0);
                }
            }
            const int wv = mt * 4 + lg;
            if (wv < 25) {
                const int oc0 = n0 * 16 + l15;
                const float m0 = fmaxf(fmaxf(a0.x, a0.y), fmaxf(a0.z, a0.w)) + b2s[oc0];
                const float m1 = fmaxf(fmaxf(a1.x, a1.y), fmaxf(a1.z, a1.w)) + b2s[oc0 + 16];
                featbuf[it * FB_STRIDE + wv * 64 + oc0]      = f2bf(fmaxf(m0, 0.f));
                featbuf[it * FB_STRIDE + wv * 64 + oc0 + 16] = f2bf(fmaxf(m1, 0.f));
            }
        }
        __syncthreads();
    } // it

    // ---- experts + gate GEMM, split-K over 8 waves: [4 x 1600] @ [1600 x 55] ----
    {
        const unsigned short* ewt = ws + EWT_OFF;
        const int kh = wid >> 2;
        const int ntE = wid & 3;
        const int bc = ntE * 16 + l15;
        const int arow = l15 & 3;           // image row (rows 4-15 duplicated)
        f32x4 acc = {0.f, 0.f, 0.f, 0.f};
        const int ks0 = kh * 25;
        for (int ks = ks0; ks < ks0 + 25; ++ks) {
            const short8 af = *(const short8*)&featbuf[arow * FB_STRIDE + ks * 32 + lg * 8];
            const short8 bf = *(const short8*)&ewt[(ks * 64 + bc) * 32 + lg * 8];
            acc = __builtin_amdgcn_mfma_f32_16x16x32_bf16(af, bf, acc, 0, 0, 0);
        }
        if (lane < 16 && bc < 56) {         // lg==0 -> rows 0..3 (the 4 images)
            allC[kh][0 * 56 + bc] = acc.x;
            allC[kh][1 * 56 + bc] = acc.y;
            allC[kh][2 * 56 + bc] = acc.z;
            allC[kh][3 * 56 + bc] = acc.w;
        }
    }
    __syncthreads();

    // ---- epilogue: gate softmax, top-3 (bitmask), combine, final softmax ----
    if (tid < IPB) {
        const int img = img0 + tid;
        if (img < B) {
            float gv[5], mx = -1e30f;
            #pragma unroll
            for (int g = 0; g < 5; g++) {
                gv[g] = allC[0][tid * 56 + 50 + g] + allC[1][tid * 56 + 50 + g] + gb[g];
                mx = fmaxf(mx, gv[g]);
            }
            float ssum = 0.f;
            #pragma unroll
            for (int g = 0; g < 5; g++) { gv[g] = expf(gv[g] - mx); ssum += gv[g]; }
            const float inv = 1.f / ssum;
            #pragma unroll
            for (int g = 0; g < 5; g++) gv[g] *= inv;

            int idx0, idx1, idx2; float wv0, wv1, wv2;
            unsigned usedMask = 0;
            {
                int bi = 0; float bv = -1e30f;
                #pragma unroll
                for (int g = 0; g < 5; g++)
                    if (gv[g] > bv) { bv = gv[g]; bi = g; }   // strict >: lowest idx on tie
                idx0 = bi; wv0 = bv; usedMask |= (1u << bi);
            }
            {
                int bi = 0; float bv = -1e30f;
                #pragma unroll
                for (int g = 0; g < 5; g++)
                    if (!(usedMask & (1u << g)) && gv[g] > bv) { bv = gv[g]; bi = g; }
                idx1 = bi; wv1 = bv; usedMask |= (1u << bi);
            }
            {
                int bi = 0; float bv = -1e30f;
                #pragma unroll
                for (int g = 0; g < 5; g++)
                    if (!(usedMask & (1u << g)) && gv[g] > bv) { bv = gv[g]; bi = g; }
                idx2 = bi; wv2 = bv;
            }
            float comb[10];
            #pragma unroll
            for (int cc = 0; cc < 10; cc++) {
                comb[cc] = wv0 * (allC[0][tid * 56 + idx0 * 10 + cc] + allC[1][tid * 56 + idx0 * 10 + cc] + eb[idx0 * 10 + cc])
                         + wv1 * (allC[0][tid * 56 + idx1 * 10 + cc] + allC[1][tid * 56 + idx1 * 10 + cc] + eb[idx1 * 10 + cc])
                         + wv2 * (allC[0][tid * 56 + idx2 * 10 + cc] + allC[1][tid * 56 + idx2 * 10 + cc] + eb[idx2 * 10 + cc]);
            }
            float m2 = -1e30f;
            #pragma unroll
            for (int cc = 0; cc < 10; cc++) m2 = fmaxf(m2, comb[cc]);
            float e[10], s2 = 0.f;
            #pragma unroll
            for (int cc = 0; cc < 10; cc++) { e[cc] = expf(comb[cc] - m2); s2 += e[cc]; }
            const float inv2 = 1.f / s2;
            #pragma unroll
            for (int cc = 0; cc < 10; cc++) out[(size_t)img * 10 + cc] = e[cc] * inv2;
        }
    }
}

// ---------------- fallback (round-1 style, used only if ws too small) ----------------
__global__ __launch_bounds__(BLOCK, 1)
void moe_fused_fallback(const float* __restrict__ x, const float* __restrict__ w1,
                        const float* __restrict__ b1, const float* __restrict__ w2,
                        const float* __restrict__ b2, const float* __restrict__ gw,
                        const float* __restrict__ gb, const float* __restrict__ ew,
                        const float* __restrict__ eb, float* __restrict__ out)
{
    __shared__ float xs[784];
    __shared__ float w1s[288];
    __shared__ float b1s[32];
    __shared__ float w2s[18432];
    __shared__ float b2s[64];
    __shared__ float h1[5408];
    __shared__ float feat[1600];
    __shared__ float allout[5][10];
    __shared__ float gsm[5];

    const int tid = threadIdx.x;
    const int img = blockIdx.x;
    const float* xg = x + img * 784;
    for (int i = tid; i < 784; i += BLOCK) xs[i] = xg[i];
    for (int i = tid; i < 288; i += BLOCK) w1s[i] = w1[i];
    if (tid < 32) b1s[tid] = b1[tid];
    for (int i = tid; i < 18432; i += BLOCK) w2s[i] = w2[i];
    if (tid < 64) b2s[tid] = b2[tid];
    __syncthreads();

    for (int i = tid; i < 5408; i += BLOCK) {
        const int oc = i & 31, sp = i >> 5, px = sp % 13, py = sp / 13;
        float a0 = 0.f, a1 = 0.f, a2 = 0.f, a3 = 0.f;
        #pragma unroll
        for (int ky = 0; ky < 3; ky++)
            #pragma unroll
            for (int kx = 0; kx < 3; kx++) {
                const float w = w1s[(ky * 3 + kx) * 32 + oc];
                const int r0 = 2 * py + ky, c0 = 2 * px + kx;
                a0 += w * xs[r0 * 28 + c0];       a1 += w * xs[r0 * 28 + c0 + 1];
                a2 += w * xs[(r0 + 1) * 28 + c0]; a3 += w * xs[(r0 + 1) * 28 + c0 + 1];
            }
        h1[i] = fmaxf(fmaxf(fmaxf(a0, a1), fmaxf(a2, a3)) + b1s[oc], 0.f);
    }
    __syncthreads();

    for (int i = tid; i < 1600; i += BLOCK) {
        const int oc = i & 63, sp = i >> 6, px = sp % 5, py = sp / 5;
        float a0 = 0.f, a1 = 0.f, a2 = 0.f, a3 = 0.f;
        #pragma unroll
        for (int ky = 0; ky < 3; ky++)
            #pragma unroll
            for (int kx = 0; kx < 3; kx++) {
                const int hb = ((2 * py + ky) * 13 + (2 * px + kx)) * 32;
                const float* wrow = &w2s[((ky * 3 + kx) * 32) * 64 + oc];
                #pragma unroll 8
                for (int ic = 0; ic < 32; ic++) {
                    const float w = wrow[ic * 64];
                    a0 += w * h1[hb + ic];        a1 += w * h1[hb + 32 + ic];
                    a2 += w * h1[hb + 416 + ic];  a3 += w * h1[hb + 448 + ic];
                }
            }
        feat[i] = fmaxf(fmaxf(fmaxf(a0, a1), fmaxf(a2, a3)) + b2s[oc], 0.f);
    }
    __syncthreads();

    const int wid = tid >> 6, lane = tid & 63;
    if (wid < 5) {
        const float* ewp = ew + wid * 16000;
        float acc[10];
        #pragma unroll
        for (int c = 0; c < 10; c++) acc[c] = 0.f;
        for (int d = lane; d < 1600; d += 64) {
            const float f = feat[d]; const float* wr = ewp + d * 10;
            #pragma unroll
            for (int c = 0; c < 10; c++) acc[c] += f * wr[c];
        }
        #pragma unroll
        for (int c = 0; c < 10; c++)
            for (int off = 32; off; off >>= 1) acc[c] += __shfl_down(acc[c], off);
        if (lane == 0)
            #pragma unroll
            for (int c = 0; c < 10; c++) allout[wid][c] = acc[c] + eb[wid * 10 + c];
    } else if (wid == 5) {
        float acc[5] = {0.f, 0.f, 0.f, 0.f, 0.f};
        for (int d = lane; d < 1600; d += 64) {
            const float f = feat[d]; const float* wr = gw + d * 5;
            #pragma unroll
            for (int g = 0; g < 5; g++) acc[g] += f * wr[g];
        }
        #pragma unroll
        for (int g = 0; g < 5; g++)
            for (int off = 32; off; off >>= 1) acc[g] += __shfl_down(acc[g], off);
        if (lane == 0) {
            float l[5], mx = -1e30f;
            #pragma unroll
            for (int g = 0; g < 5; g++) { l[g] = acc[g] + gb[g]; mx = fmaxf(mx, l[g]); }
            float s = 0.f;
            #pragma unroll
            for (int g = 0; g < 5; g++) { l[g] = expf(l[g] - mx); s += l[g]; }
            const float inv = 1.f / s;
            #pragma unroll
            for (int g = 0; g < 5; g++) gsm[g] = l[g] * inv;
        }
    }
    __syncthreads();

    if (tid == 0) {
        float gv[5];
        #pragma unroll
        for (int g = 0; g < 5; g++) gv[g] = gsm[g];
        int idx0, idx1, idx2; float wv0, wv1, wv2;
        unsigned usedMask = 0;
        {
            int bi = 0; float bv = -1e30f;
            #pragma unroll
            for (int g = 0; g < 5; g++) if (gv[g] > bv) { bv = gv[g]; bi = g; }
            idx0 = bi; wv0 = bv; usedMask |= (1u << bi);
        }
        {
            int bi = 0; float bv = -1e30f;
            #pragma unroll
            for (int g = 0; g < 5; g++) if (!(usedMask & (1u << g)) && gv[g] > bv) { bv = gv[g]; bi = g; }
            idx1 = bi; wv1 = bv; usedMask |= (1u << bi);
        }
        {
            int bi = 0; float bv = -1e30f;
            #pragma unroll
            for (int g = 0; g < 5; g++) if (!(usedMask & (1u << g)) && gv[g] > bv) { bv = gv[g]; bi = g; }
            idx2 = bi; wv2 = bv;
        }
        float comb[10];
        #pragma unroll
        for (int cc = 0; cc < 10; cc++)
            comb[cc] = wv0 * allout[idx0][cc] + wv1 * allout[idx1][cc] + wv2 * allout[idx2][cc];
        float mx = -1e30f;
        #pragma unroll
        for (int cc = 0; cc < 10; cc++) mx = fmaxf(mx, comb[cc]);
        float e[10], s = 0.f;
        #pragma unroll
        for (int cc = 0; cc < 10; cc++) { e[cc] = expf(comb[cc] - mx); s += e[cc]; }
        const float inv = 1.f / s;
        #pragma unroll
        for (int cc = 0; cc < 10; cc++) out[img * 10 + cc] = e[cc] * inv;
    }
}

extern "C" void kernel_launch(void* const* d_in, const int* in_sizes, int n_in,
                              void* d_out, int out_size, void* d_ws, size_t ws_size,
                              hipStream_t stream) {
    const float* x   = (const float*)d_in[0];
    const float* w1  = (const float*)d_in[1];
    const float* b1  = (const float*)d_in[2];
    const float* w2  = (const float*)d_in[3];
    const float* b2  = (const float*)d_in[4];
    const float* gw  = (const float*)d_in[5];
    const float* gb  = (const float*)d_in[6];
    const float* ew  = (const float*)d_in[7];
    const float* eb  = (const float*)d_in[8];
    float* out = (float*)d_out;
    const int B = in_sizes[0] / 784;

    const size_t WS_NEEDED = WS_SHORTS * sizeof(unsigned short);
    if (ws_size >= WS_NEEDED) {
        unsigned short* ws = (unsigned short*)d_ws;
        moe_prep<<<(WS_SHORTS + 255) / 256, 256, 0, stream>>>(w2, gw, ew, w1, ws);
        const int nblk = (B + IPB - 1) / IPB;
        moe_main<<<nblk, BLOCK, 0, stream>>>(x, b1, b2, gb, eb, ws, out, B);
    } else {
        moe_fused_fallback<<<B, BLOCK, 0, stream>>>(x, w1, b1, w2, b2, gw, gb, ew, eb, out);
    }
}

// Round 6
// 132.362 us; speedup vs baseline: 1.7145x; 1.0895x over previous
//
#include <hip/hip_runtime.h>
#include <hip/hip_bf16.h>

#define BLOCK 512
#define IPB 2            // images per block
#define FB_STRIDE 1608   // featbuf row stride in shorts: 804 dwords = 4 mod 32 -> conflict-free

// ws layout (shorts):
#define W2T_OFF 0        // [kpos=9][oc=64][ic=32]                     18432
#define EWT_OFF 18432    // [ks=50][n=64][k=32] experts+gate           102400
#define W1C_OFF 120832   // [n=32][k=32] conv1 hi/lo B matrix          1024
#define WS_SHORTS 121856

typedef __attribute__((ext_vector_type(8))) short short8;
typedef __attribute__((ext_vector_type(4))) float f32x4;

static __device__ __forceinline__ unsigned short f2bf(float f) {
    unsigned int u = __builtin_bit_cast(unsigned int, f);
    u = (u + 0x7FFFu + ((u >> 16) & 1u)) >> 16;   // RNE
    return (unsigned short)u;
}
static __device__ __forceinline__ float bf2f(unsigned short h) {
    unsigned int u = ((unsigned int)h) << 16;
    return __builtin_bit_cast(float, u);
}

// ---------------- prep kernel: build bf16 weight layouts in d_ws ----------------
__global__ void moe_prep(const float* __restrict__ w2, const float* __restrict__ gw,
                         const float* __restrict__ ew, const float* __restrict__ w1,
                         unsigned short* __restrict__ ws) {
    int i = blockIdx.x * 256 + threadIdx.x;
    if (i < 18432) {
        int kpos = i >> 11, rem = i & 2047, oc = rem >> 5, ic = rem & 31;
        ws[W2T_OFF + i] = f2bf(w2[(kpos * 32 + ic) * 64 + oc]);
    }
    int j = i - EWT_OFF;
    if (j >= 0 && j < 102400) {
        int ks = j >> 11, rem = j & 2047, n = rem >> 5, k = rem & 31;
        int d = ks * 32 + k;
        float v = 0.f;
        if (n < 50)      v = ew[(n / 10) * 16000 + d * 10 + (n % 10)];
        else if (n < 55) v = gw[d * 5 + (n - 50)];
        ws[EWT_OFF + j] = f2bf(v);
    }
    int p = i - W1C_OFF;
    if (p >= 0 && p < 1024) {
        // conv1 B: [n=32][k=32]; k 0-8: w1hi(tap k), 9-17: w1lo(tap k-9), 18-26: w1hi(tap k-18)
        int n = p >> 5, k = p & 31;
        unsigned short val = 0;
        if (k < 27) {
            int t = (k < 9) ? k : (k < 18 ? k - 9 : k - 18);
            float w = w1[t * 32 + n];
            unsigned short hi = f2bf(w);
            val = (k >= 9 && k < 18) ? f2bf(w - bf2f(hi)) : hi;
        }
        ws[W1C_OFF + p] = val;
    }
}

// build one im2col row (A layout: [xh*9 | xh*9 | xl*9 | 0*5]) from (hi|lo)-packed xs
static __device__ __forceinline__ void build_row(const unsigned int* __restrict__ xsrc,
                                                 unsigned short* __restrict__ ic1h,
                                                 int rl, int rg) {
    int window = rg >> 2; if (window > 168) window = 168;
    const int s  = rg & 3;
    const int wy = window / 13, wx = window - wy * 13;
    const int cy = 2 * wy + (s >> 1), cx = 2 * wx + (s & 1);
    const unsigned int* xb = xsrc + cy * 28 + cx;
    const unsigned int t0 = xb[0],  t1 = xb[1],  t2 = xb[2];
    const unsigned int t3 = xb[28], t4 = xb[29], t5 = xb[30];
    const unsigned int t6 = xb[56], t7 = xb[57], t8 = xb[58];
    const unsigned int d0  = (t0 & 0xffffu) | (t1 << 16);
    const unsigned int d1  = (t2 & 0xffffu) | (t3 << 16);
    const unsigned int d2  = (t4 & 0xffffu) | (t5 << 16);
    const unsigned int d3  = (t6 & 0xffffu) | (t7 << 16);
    const unsigned int d4  = (t8 & 0xffffu) | (t0 << 16);
    const unsigned int d5  = (t1 & 0xffffu) | (t2 << 16);
    const unsigned int d6  = (t3 & 0xffffu) | (t4 << 16);
    const unsigned int d7  = (t5 & 0xffffu) | (t6 << 16);
    const unsigned int d8  = (t7 & 0xffffu) | (t8 << 16);
    const unsigned int d9  = (t0 >> 16) | (t1 & 0xffff0000u);
    const unsigned int d10 = (t2 >> 16) | (t3 & 0xffff0000u);
    const unsigned int d11 = (t4 >> 16) | (t5 & 0xffff0000u);
    const unsigned int d12 = (t6 >> 16) | (t7 & 0xffff0000u);
    const unsigned int d13 = (t8 >> 16);
    char* base = (char*)ic1h + rl * 64;
    const int sw = ((rl >> 1) & 3) << 4;
    *(uint4*)(base + (0  ^ sw)) = make_uint4(d0, d1, d2, d3);
    *(uint4*)(base + (16 ^ sw)) = make_uint4(d4, d5, d6, d7);
    *(uint4*)(base + (32 ^ sw)) = make_uint4(d8, d9, d10, d11);
    *(uint4*)(base + (48 ^ sw)) = make_uint4(d12, d13, 0u, 0u);
}

// ---------------- main fused kernel ----------------
// NOTE: this toolchain treats __launch_bounds__ arg2 as min BLOCKS/CU (CUDA semantics).
// N=3 -> 85-VGPR cap (24 waves/CU). Verified: N=4 -> 64, N=6 -> 40 (spills), N=2 -> 128.
__global__ __launch_bounds__(BLOCK, 3)
void moe_main(const float* __restrict__ x, const float* __restrict__ b1,
              const float* __restrict__ b2, const float* __restrict__ gb,
              const float* __restrict__ eb, const unsigned short* __restrict__ ws,
              float* __restrict__ out, int B)
{
    __shared__ unsigned int xsp[2][784];                       // (hi|lo) packed x, 6272 B
    __shared__ __align__(16) unsigned short ic1h[352 * 32];    // conv1 im2col HALF, 22528 B
    __shared__ __align__(16) unsigned short h1p[6760];         // [169][40] bf16, 13520 B
    __shared__ __align__(16) unsigned short featbuf[IPB * FB_STRIDE]; // 6432 B
    __shared__ float b1s[32];
    __shared__ float b2s[64];
    __shared__ float allC[2][112];                             // split-K halves, [2 img][56]

    const int tid  = threadIdx.x;
    const int wid  = tid >> 6;
    const int lane = tid & 63;
    const int l15  = lane & 15;
    const int lg   = lane >> 4;

    if (tid < 32) b1s[tid] = b1[tid];
    if (tid < 64) b2s[tid] = b2[tid];

    // ---- conv2: wave owns M-tiles {mt0, mt0+4} x N-tiles {n0, n0+1}; bfrag persistent ----
    const int mt0 = wid >> 1;
    const int n0  = (wid & 1) * 2;
    short8 bfA[9], bfB[9];
    #pragma unroll
    for (int kp = 0; kp < 9; kp++) {
        bfA[kp] = *(const short8*)&ws[W2T_OFF + (kp * 64 + n0 * 16 + l15) * 32 + lg * 8];
        bfB[kp] = *(const short8*)&ws[W2T_OFF + (kp * 64 + (n0 + 1) * 16 + l15) * 32 + lg * 8];
    }
    // ---- conv1 B fragments (both 16-col tiles), persistent ----
    const short8 c1f0 = *(const short8*)&ws[W1C_OFF + l15 * 32 + lg * 8];
    const short8 c1f1 = *(const short8*)&ws[W1C_OFF + (16 + l15) * 32 + lg * 8];

    const int img0 = blockIdx.x * IPB;
    {   // stage first image (fp32 -> hi|lo packed)
        int im = img0 < B ? img0 : B - 1;
        const float* xg = x + (size_t)im * 784;
        for (int i = tid; i < 784; i += BLOCK) {
            const float v = xg[i];
            const unsigned short h = f2bf(v);
            const unsigned short l = f2bf(v - bf2f(h));
            xsp[0][i] = (unsigned int)h | ((unsigned int)l << 16);
        }
    }
    __syncthreads();

    // per-lane conv1 A-fragment byte offset within a 16-row tile (XOR-swizzled 16B chunks)
    const int ic1_rowoff = l15 * 64 + ((lg ^ ((l15 >> 1) & 3)) << 4);

    for (int it = 0; it < IPB; ++it) {
        const int cur = it & 1;

        // ---- P1: build im2col half0 (rows 0..351) + prefetch next x ----
        if (it + 1 < IPB) {
            int im = img0 + it + 1; if (im >= B) im = B - 1;
            const float* xg = x + (size_t)im * 784;
            for (int i = tid; i < 784; i += BLOCK) {
                const float v = xg[i];
                const unsigned short h = f2bf(v);
                const unsigned short l = f2bf(v - bf2f(h));
                xsp[cur ^ 1][i] = (unsigned int)h | ((unsigned int)l << 16);
            }
        }
        if (tid < 352) build_row(xsp[cur], ic1h, tid, tid);
        __syncthreads();

        // ---- P2: conv1 MFMA half0 (mt 0..21) + pool + relu -> h1p ----
        for (int mt = wid; mt < 22; mt += 8) {
            const short8 af = *(const short8*)((const char*)ic1h + mt * 1024 + ic1_rowoff);
            f32x4 a0 = {0.f, 0.f, 0.f, 0.f};
            f32x4 a1 = {0.f, 0.f, 0.f, 0.f};
            a0 = __builtin_amdgcn_mfma_f32_16x16x32_bf16(af, c1f0, a0, 0, 0, 0);
            a1 = __builtin_amdgcn_mfma_f32_16x16x32_bf16(af, c1f1, a1, 0, 0, 0);
            const int window = mt * 4 + lg;        // lane's 4 accs = 2x2 pool window
            const float m0 = fmaxf(fmaxf(a0.x, a0.y), fmaxf(a0.z, a0.w)) + b1s[l15];
            const float m1 = fmaxf(fmaxf(a1.x, a1.y), fmaxf(a1.z, a1.w)) + b1s[16 + l15];
            h1p[window * 40 + l15]      = f2bf(fmaxf(m0, 0.f));
            h1p[window * 40 + 16 + l15] = f2bf(fmaxf(m1, 0.f));
        }
        __syncthreads();

        // ---- P3: build im2col half1 (rows 352..687) ----
        if (tid < 336) build_row(xsp[cur], ic1h, tid, 352 + tid);
        __syncthreads();

        // ---- P4: conv1 MFMA half1 (mt 22..42) ----
        for (int mt = 22 + wid; mt < 43; mt += 8) {
            const short8 af = *(const short8*)((const char*)ic1h + (mt - 22) * 1024 + ic1_rowoff);
            f32x4 a0 = {0.f, 0.f, 0.f, 0.f};
            f32x4 a1 = {0.f, 0.f, 0.f, 0.f};
            a0 = __builtin_amdgcn_mfma_f32_16x16x32_bf16(af, c1f0, a0, 0, 0, 0);
            a1 = __builtin_amdgcn_mfma_f32_16x16x32_bf16(af, c1f1, a1, 0, 0, 0);
            const int window = mt * 4 + lg;
            if (window < 169) {
                const float m0 = fmaxf(fmaxf(a0.x, a0.y), fmaxf(a0.z, a0.w)) + b1s[l15];
                const float m1 = fmaxf(fmaxf(a1.x, a1.y), fmaxf(a1.z, a1.w)) + b1s[16 + l15];
                h1p[window * 40 + l15]      = f2bf(fmaxf(m0, 0.f));
                h1p[window * 40 + 16 + l15] = f2bf(fmaxf(m1, 0.f));
            }
        }
        __syncthreads();

        // ---- P5: conv2 implicit-GEMM (2 mt x 2 nt per wave) + pool -> featbuf ----
        #pragma unroll
        for (int mi = 0; mi < 2; ++mi) {
            const int mt = mt0 + mi * 4;
            const int m = mt * 16 + l15;
            int wsrc = m >> 2; if (wsrc > 24) wsrc = 24;
            const int s = m & 3;
            const int cy = 2 * (wsrc / 5) + (s >> 1);
            const int cx = 2 * (wsrc % 5) + (s & 1);
            const char* abase = (const char*)h1p + (cy * 13 + cx) * 80 + lg * 16;
            f32x4 a0 = {0.f, 0.f, 0.f, 0.f};
            f32x4 a1 = {0.f, 0.f, 0.f, 0.f};
            #pragma unroll
            for (int ky = 0; ky < 3; ky++) {
                #pragma unroll
                for (int kx = 0; kx < 3; kx++) {
                    const short8 af = *(const short8*)(abase + (ky * 13 + kx) * 80);
                    a0 = __builtin_amdgcn_mfma_f32_16x16x32_bf16(af, bfA[ky * 3 + kx], a0, 0, 0, 0);
                    a1 = __builtin_amdgcn_mfma_f32_16x16x32_bf16(af, bfB[ky * 3 + kx], a1, 0, 0, 0);
                }
            }
            const int wv = mt * 4 + lg;
            if (wv < 25) {
                const int oc0 = n0 * 16 + l15;
                const float m0 = fmaxf(fmaxf(a0.x, a0.y), fmaxf(a0.z, a0.w)) + b2s[oc0];
                const float m1 = fmaxf(fmaxf(a1.x, a1.y), fmaxf(a1.z, a1.w)) + b2s[oc0 + 16];
                featbuf[it * FB_STRIDE + wv * 64 + oc0]      = f2bf(fmaxf(m0, 0.f));
                featbuf[it * FB_STRIDE + wv * 64 + oc0 + 16] = f2bf(fmaxf(m1, 0.f));
            }
        }
        __syncthreads();
    } // it

    // ---- experts + gate GEMM, split-K over 8 waves: [2 x 1600] @ [1600 x 55] ----
    {
        const unsigned short* ewt = ws + EWT_OFF;
        const int kh = wid >> 2;
        const int ntE = wid & 3;
        const int bc = ntE * 16 + l15;
        const int arow = l15 & 1;           // image row (rows 2-15 duplicated)
        f32x4 acc = {0.f, 0.f, 0.f, 0.f};
        const int ks0 = kh * 25;
        for (int ks = ks0; ks < ks0 + 25; ++ks) {
            const short8 af = *(const short8*)&featbuf[arow * FB_STRIDE + ks * 32 + lg * 8];
            const short8 bf = *(const short8*)&ewt[(ks * 64 + bc) * 32 + lg * 8];
            acc = __builtin_amdgcn_mfma_f32_16x16x32_bf16(af, bf, acc, 0, 0, 0);
        }
        if (lane < 16 && bc < 56) {         // lg==0 -> rows 0,1 = the 2 images
            allC[kh][0 * 56 + bc] = acc.x;
            allC[kh][1 * 56 + bc] = acc.y;
        }
    }
    __syncthreads();

    // ---- epilogue: gate softmax, top-3 (bitmask), combine, final softmax ----
    if (tid < IPB) {
        const int img = img0 + tid;
        if (img < B) {
            float gv[5], mx = -1e30f;
            #pragma unroll
            for (int g = 0; g < 5; g++) {
                gv[g] = allC[0][tid * 56 + 50 + g] + allC[1][tid * 56 + 50 + g] + gb[g];
                mx = fmaxf(mx, gv[g]);
            }
            float ssum = 0.f;
            #pragma unroll
            for (int g = 0; g < 5; g++) { gv[g] = expf(gv[g] - mx); ssum += gv[g]; }
            const float inv = 1.f / ssum;
            #pragma unroll
            for (int g = 0; g < 5; g++) gv[g] *= inv;

            int idx0, idx1, idx2; float wv0, wv1, wv2;
            unsigned usedMask = 0;
            {
                int bi = 0; float bv = -1e30f;
                #pragma unroll
                for (int g = 0; g < 5; g++)
                    if (gv[g] > bv) { bv = gv[g]; bi = g; }   // strict >: lowest idx on tie
                idx0 = bi; wv0 = bv; usedMask |= (1u << bi);
            }
            {
                int bi = 0; float bv = -1e30f;
                #pragma unroll
                for (int g = 0; g < 5; g++)
                    if (!(usedMask & (1u << g)) && gv[g] > bv) { bv = gv[g]; bi = g; }
                idx1 = bi; wv1 = bv; usedMask |= (1u << bi);
            }
            {
                int bi = 0; float bv = -1e30f;
                #pragma unroll
                for (int g = 0; g < 5; g++)
                    if (!(usedMask & (1u << g)) && gv[g] > bv) { bv = gv[g]; bi = g; }
                idx2 = bi; wv2 = bv;
            }
            float comb[10];
            #pragma unroll
            for (int cc = 0; cc < 10; cc++) {
                comb[cc] = wv0 * (allC[0][tid * 56 + idx0 * 10 + cc] + allC[1][tid * 56 + idx0 * 10 + cc] + eb[idx0 * 10 + cc])
                         + wv1 * (allC[0][tid * 56 + idx1 * 10 + cc] + allC[1][tid * 56 + idx1 * 10 + cc] + eb[idx1 * 10 + cc])
                         + wv2 * (allC[0][tid * 56 + idx2 * 10 + cc] + allC[1][tid * 56 + idx2 * 10 + cc] + eb[idx2 * 10 + cc]);
            }
            float m2 = -1e30f;
            #pragma unroll
            for (int cc = 0; cc < 10; cc++) m2 = fmaxf(m2, comb[cc]);
            float e[10], s2 = 0.f;
            #pragma unroll
            for (int cc = 0; cc < 10; cc++) { e[cc] = expf(comb[cc] - m2); s2 += e[cc]; }
            const float inv2 = 1.f / s2;
            #pragma unroll
            for (int cc = 0; cc < 10; cc++) out[(size_t)img * 10 + cc] = e[cc] * inv2;
        }
    }
}

// ---------------- fallback (round-1 style, used only if ws too small) ----------------
__global__ __launch_bounds__(BLOCK, 1)
void moe_fused_fallback(const float* __restrict__ x, const float* __restrict__ w1,
                        const float* __restrict__ b1, const float* __restrict__ w2,
                        const float* __restrict__ b2, const float* __restrict__ gw,
                        const float* __restrict__ gb, const float* __restrict__ ew,
                        const float* __restrict__ eb, float* __restrict__ out)
{
    __shared__ float xs[784];
    __shared__ float w1s[288];
    __shared__ float b1s[32];
    __shared__ float w2s[18432];
    __shared__ float b2s[64];
    __shared__ float h1[5408];
    __shared__ float feat[1600];
    __shared__ float allout[5][10];
    __shared__ float gsm[5];

    const int tid = threadIdx.x;
    const int img = blockIdx.x;
    const float* xg = x + img * 784;
    for (int i = tid; i < 784; i += BLOCK) xs[i] = xg[i];
    for (int i = tid; i < 288; i += BLOCK) w1s[i] = w1[i];
    if (tid < 32) b1s[tid] = b1[tid];
    for (int i = tid; i < 18432; i += BLOCK) w2s[i] = w2[i];
    if (tid < 64) b2s[tid] = b2[tid];
    __syncthreads();

    for (int i = tid; i < 5408; i += BLOCK) {
        const int oc = i & 31, sp = i >> 5, px = sp % 13, py = sp / 13;
        float a0 = 0.f, a1 = 0.f, a2 = 0.f, a3 = 0.f;
        #pragma unroll
        for (int ky = 0; ky < 3; ky++)
            #pragma unroll
            for (int kx = 0; kx < 3; kx++) {
                const float w = w1s[(ky * 3 + kx) * 32 + oc];
                const int r0 = 2 * py + ky, c0 = 2 * px + kx;
                a0 += w * xs[r0 * 28 + c0];       a1 += w * xs[r0 * 28 + c0 + 1];
                a2 += w * xs[(r0 + 1) * 28 + c0]; a3 += w * xs[(r0 + 1) * 28 + c0 + 1];
            }
        h1[i] = fmaxf(fmaxf(fmaxf(a0, a1), fmaxf(a2, a3)) + b1s[oc], 0.f);
    }
    __syncthreads();

    for (int i = tid; i < 1600; i += BLOCK) {
        const int oc = i & 63, sp = i >> 6, px = sp % 5, py = sp / 5;
        float a0 = 0.f, a1 = 0.f, a2 = 0.f, a3 = 0.f;
        #pragma unroll
        for (int ky = 0; ky < 3; ky++)
            #pragma unroll
            for (int kx = 0; kx < 3; kx++) {
                const int hb = ((2 * py + ky) * 13 + (2 * px + kx)) * 32;
                const float* wrow = &w2s[((ky * 3 + kx) * 32) * 64 + oc];
                #pragma unroll 8
                for (int ic = 0; ic < 32; ic++) {
                    const float w = wrow[ic * 64];
                    a0 += w * h1[hb + ic];        a1 += w * h1[hb + 32 + ic];
                    a2 += w * h1[hb + 416 + ic];  a3 += w * h1[hb + 448 + ic];
                }
            }
        feat[i] = fmaxf(fmaxf(fmaxf(a0, a1), fmaxf(a2, a3)) + b2s[oc], 0.f);
    }
    __syncthreads();

    const int wid = tid >> 6, lane = tid & 63;
    if (wid < 5) {
        const float* ewp = ew + wid * 16000;
        float acc[10];
        #pragma unroll
        for (int c = 0; c < 10; c++) acc[c] = 0.f;
        for (int d = lane; d < 1600; d += 64) {
            const float f = feat[d]; const float* wr = ewp + d * 10;
            #pragma unroll
            for (int c = 0; c < 10; c++) acc[c] += f * wr[c];
        }
        #pragma unroll
        for (int c = 0; c < 10; c++)
            for (int off = 32; off; off >>= 1) acc[c] += __shfl_down(acc[c], off);
        if (lane == 0)
            #pragma unroll
            for (int c = 0; c < 10; c++) allout[wid][c] = acc[c] + eb[wid * 10 + c];
    } else if (wid == 5) {
        float acc[5] = {0.f, 0.f, 0.f, 0.f, 0.f};
        for (int d = lane; d < 1600; d += 64) {
            const float f = feat[d]; const float* wr = gw + d * 5;
            #pragma unroll
            for (int g = 0; g < 5; g++) acc[g] += f * wr[g];
        }
        #pragma unroll
        for (int g = 0; g < 5; g++)
            for (int off = 32; off; off >>= 1) acc[g] += __shfl_down(acc[g], off);
        if (lane == 0) {
            float l[5], mx = -1e30f;
            #pragma unroll
            for (int g = 0; g < 5; g++) { l[g] = acc[g] + gb[g]; mx = fmaxf(mx, l[g]); }
            float s = 0.f;
            #pragma unroll
            for (int g = 0; g < 5; g++) { l[g] = expf(l[g] - mx); s += l[g]; }
            const float inv = 1.f / s;
            #pragma unroll
            for (int g = 0; g < 5; g++) gsm[g] = l[g] * inv;
        }
    }
    __syncthreads();

    if (tid == 0) {
        float gv[5];
        #pragma unroll
        for (int g = 0; g < 5; g++) gv[g] = gsm[g];
        int idx0, idx1, idx2; float wv0, wv1, wv2;
        unsigned usedMask = 0;
        {
            int bi = 0; float bv = -1e30f;
            #pragma unroll
            for (int g = 0; g < 5; g++) if (gv[g] > bv) { bv = gv[g]; bi = g; }
            idx0 = bi; wv0 = bv; usedMask |= (1u << bi);
        }
        {
            int bi = 0; float bv = -1e30f;
            #pragma unroll
            for (int g = 0; g < 5; g++) if (!(usedMask & (1u << g)) && gv[g] > bv) { bv = gv[g]; bi = g; }
            idx1 = bi; wv1 = bv; usedMask |= (1u << bi);
        }
        {
            int bi = 0; float bv = -1e30f;
            #pragma unroll
            for (int g = 0; g < 5; g++) if (!(usedMask & (1u << g)) && gv[g] > bv) { bv = gv[g]; bi = g; }
            idx2 = bi; wv2 = bv;
        }
        float comb[10];
        #pragma unroll
        for (int cc = 0; cc < 10; cc++)
            comb[cc] = wv0 * allout[idx0][cc] + wv1 * allout[idx1][cc] + wv2 * allout[idx2][cc];
        float mx = -1e30f;
        #pragma unroll
        for (int cc = 0; cc < 10; cc++) mx = fmaxf(mx, comb[cc]);
        float e[10], s = 0.f;
        #pragma unroll
        for (int cc = 0; cc < 10; cc++) { e[cc] = expf(comb[cc] - mx); s += e[cc]; }
        const float inv = 1.f / s;
        #pragma unroll
        for (int cc = 0; cc < 10; cc++) out[img * 10 + cc] = e[cc] * inv;
    }
}

extern "C" void kernel_launch(void* const* d_in, const int* in_sizes, int n_in,
                              void* d_out, int out_size, void* d_ws, size_t ws_size,
                              hipStream_t stream) {
    const float* x   = (const float*)d_in[0];
    const float* w1  = (const float*)d_in[1];
    const float* b1  = (const float*)d_in[2];
    const float* w2  = (const float*)d_in[3];
    const float* b2  = (const float*)d_in[4];
    const float* gw  = (const float*)d_in[5];
    const float* gb  = (const float*)d_in[6];
    const float* ew  = (const float*)d_in[7];
    const float* eb  = (const float*)d_in[8];
    float* out = (float*)d_out;
    const int B = in_sizes[0] / 784;

    const size_t WS_NEEDED = WS_SHORTS * sizeof(unsigned short);
    if (ws_size >= WS_NEEDED) {
        unsigned short* ws = (unsigned short*)d_ws;
        moe_prep<<<(WS_SHORTS + 255) / 256, 256, 0, stream>>>(w2, gw, ew, w1, ws);
        const int nblk = (B + IPB - 1) / IPB;
        moe_main<<<nblk, BLOCK, 0, stream>>>(x, b1, b2, gb, eb, ws, out, B);
    } else {
        moe_fused_fallback<<<B, BLOCK, 0, stream>>>(x, w1, b1, w2, b2, gw, gb, ew, eb, out);
    }
}

// Round 7
// 109.513 us; speedup vs baseline: 2.0722x; 1.2086x over previous
//
#include <hip/hip_runtime.h>
#include <hip/hip_bf16.h>

#define BLOCK 512
#define IPB 4            // images per block
#define FB_STRIDE 1600   // featbuf row stride (rows broadcast-read in expert GEMM)

// ws layout (shorts):
#define W2T_OFF 0        // [kpos=9][oc=64][ic=32]                     18432
#define EWT_OFF 18432    // [ks=50][n=64][k=32] experts+gate           102400
#define W1C_OFF 120832   // [n=32][k=32] conv1 hi/lo B matrix          1024
#define WS_SHORTS 121856

typedef __attribute__((ext_vector_type(8))) short short8;
typedef __attribute__((ext_vector_type(4))) float f32x4;

static __device__ __forceinline__ unsigned short f2bf(float f) {
    unsigned int u = __builtin_bit_cast(unsigned int, f);
    u = (u + 0x7FFFu + ((u >> 16) & 1u)) >> 16;   // RNE
    return (unsigned short)u;
}
static __device__ __forceinline__ float bf2f(unsigned short h) {
    unsigned int u = ((unsigned int)h) << 16;
    return __builtin_bit_cast(float, u);
}
static __device__ __forceinline__ unsigned int pk_lo(unsigned int a, unsigned int b) {
    return (a & 0xffffu) | (b << 16);              // bf16 pair from LOW halves (xh)
}
static __device__ __forceinline__ unsigned int pk_hi(unsigned int a, unsigned int b) {
    return (a >> 16) | (b & 0xffff0000u);          // bf16 pair from HIGH halves (xl)
}

// ---------------- prep kernel: build bf16 weight layouts in d_ws ----------------
__global__ void moe_prep(const float* __restrict__ w2, const float* __restrict__ gw,
                         const float* __restrict__ ew, const float* __restrict__ w1,
                         unsigned short* __restrict__ ws) {
    int i = blockIdx.x * 256 + threadIdx.x;
    if (i < 18432) {
        int kpos = i >> 11, rem = i & 2047, oc = rem >> 5, ic = rem & 31;
        ws[W2T_OFF + i] = f2bf(w2[(kpos * 32 + ic) * 64 + oc]);
    }
    int j = i - EWT_OFF;
    if (j >= 0 && j < 102400) {
        int ks = j >> 11, rem = j & 2047, n = rem >> 5, k = rem & 31;
        int d = ks * 32 + k;
        float v = 0.f;
        if (n < 50)      v = ew[(n / 10) * 16000 + d * 10 + (n % 10)];
        else if (n < 55) v = gw[d * 5 + (n - 50)];
        ws[EWT_OFF + j] = f2bf(v);
    }
    int p = i - W1C_OFF;
    if (p >= 0 && p < 1024) {
        // conv1 B: [n=32][k=32]; k 0-8: w1hi(tap k), 9-17: w1lo(tap k-9), 18-26: w1hi(tap k-18)
        int n = p >> 5, k = p & 31;
        unsigned short val = 0;
        if (k < 27) {
            int t = (k < 9) ? k : (k < 18 ? k - 9 : k - 18);
            float w = w1[t * 32 + n];
            unsigned short hi = f2bf(w);
            val = (k >= 9 && k < 18) ? f2bf(w - bf2f(hi)) : hi;
        }
        ws[W1C_OFF + p] = val;
    }
}

// ---------------- main fused kernel ----------------
// NOTE: this toolchain treats __launch_bounds__ arg2 as min BLOCKS/CU (CUDA semantics).
// N=4 -> 64-VGPR cap = 4 blocks/CU = 32 waves/CU (wave cap). Compiler already hit 64.
__global__ __launch_bounds__(BLOCK, 4)
void moe_main(const float* __restrict__ x, const float* __restrict__ b1,
              const float* __restrict__ b2, const float* __restrict__ gb,
              const float* __restrict__ eb, const unsigned short* __restrict__ ws,
              float* __restrict__ out, int B)
{
    __shared__ unsigned int xsp[784];                          // (hi|lo) packed x, 3136 B
    __shared__ __align__(16) unsigned short h1p[6760];         // [169][40] bf16, 13520 B
    __shared__ __align__(16) unsigned short featbuf[IPB * FB_STRIDE]; // 12800 B
    __shared__ float b1s[32];
    __shared__ float b2s[64];
    __shared__ float allC[2][IPB * 56];                        // split-K halves

    const int tid  = threadIdx.x;
    const int wid  = tid >> 6;
    const int lane = tid & 63;
    const int l15  = lane & 15;
    const int lg   = lane >> 4;

    if (tid < 32) b1s[tid] = b1[tid];
    if (tid < 64) b2s[tid] = b2[tid];

    // ---- conv2: wave owns M-tiles {mt0, mt0+4} x N-tiles {n0, n0+1}; bfrag persistent ----
    const int mt0 = wid >> 1;
    const int n0  = (wid & 1) * 2;
    short8 bfA[9], bfB[9];
    #pragma unroll
    for (int kp = 0; kp < 9; kp++) {
        bfA[kp] = *(const short8*)&ws[W2T_OFF + (kp * 64 + n0 * 16 + l15) * 32 + lg * 8];
        bfB[kp] = *(const short8*)&ws[W2T_OFF + (kp * 64 + (n0 + 1) * 16 + l15) * 32 + lg * 8];
    }
    // ---- conv1 B fragments (both 16-col tiles), persistent ----
    const short8 c1f0 = *(const short8*)&ws[W1C_OFF + l15 * 32 + lg * 8];
    const short8 c1f1 = *(const short8*)&ws[W1C_OFF + (16 + l15) * 32 + lg * 8];

    const int img0 = blockIdx.x * IPB;
    {   // prologue: stage image 0 (fp32 -> hi|lo packed)
        int im = img0 < B ? img0 : B - 1;
        const float* xg = x + (size_t)im * 784;
        {
            const float v = xg[tid];
            const unsigned short h = f2bf(v);
            const unsigned short l = f2bf(v - bf2f(h));
            xsp[tid] = (unsigned int)h | ((unsigned int)l << 16);
        }
        if (tid + BLOCK < 784) {
            const float v = xg[tid + BLOCK];
            const unsigned short h = f2bf(v);
            const unsigned short l = f2bf(v - bf2f(h));
            xsp[tid + BLOCK] = (unsigned int)h | ((unsigned int)l << 16);
        }
    }
    __syncthreads();

    for (int it = 0; it < IPB; ++it) {
        // ---- issue next image's global loads early (latency hides under conv1) ----
        float f0 = 0.f, f1 = 0.f;
        const bool have_next = (it + 1 < IPB);
        if (have_next) {
            int im2 = img0 + it + 1; if (im2 >= B) im2 = B - 1;
            const float* xg2 = x + (size_t)im2 * 784;
            f0 = xg2[tid];
            if (tid + BLOCK < 784) f1 = xg2[tid + BLOCK];
        }

        // ---- conv1: A-fragments built in registers from xsp, MFMA, pool -> h1p ----
        for (int mt = wid; mt < 43; mt += 8) {
            int wsrc = mt * 4 + (l15 >> 2); if (wsrc > 168) wsrc = 168;
            const int s  = l15 & 3;
            const int cy = 2 * (wsrc / 13) + (s >> 1);
            const int cx = 2 * (wsrc % 13) + (s & 1);
            const unsigned int* xb = &xsp[cy * 28 + cx];
            const unsigned int t0 = xb[0],  t1 = xb[1],  t2 = xb[2];
            const unsigned int t3 = xb[28], t4 = xb[29], t5 = xb[30];
            const unsigned int t6 = xb[56], t7 = xb[57], t8 = xb[58];
            // row layout: k0-8 = xh taps, k9-17 = xh taps, k18-26 = xl taps, k27-31 = 0
            unsigned int a0, a1, a2, a3;
            if (lg == 0)      { a0 = pk_lo(t0, t1); a1 = pk_lo(t2, t3); a2 = pk_lo(t4, t5); a3 = pk_lo(t6, t7); }
            else if (lg == 1) { a0 = pk_lo(t8, t0); a1 = pk_lo(t1, t2); a2 = pk_lo(t3, t4); a3 = pk_lo(t5, t6); }
            else if (lg == 2) { a0 = pk_lo(t7, t8); a1 = pk_hi(t0, t1); a2 = pk_hi(t2, t3); a3 = pk_hi(t4, t5); }
            else              { a0 = pk_hi(t6, t7); a1 = (t8 >> 16);    a2 = 0u;            a3 = 0u; }
            const uint4 av = make_uint4(a0, a1, a2, a3);
            const short8 af = __builtin_bit_cast(short8, av);
            f32x4 p0 = {0.f, 0.f, 0.f, 0.f};
            f32x4 p1 = {0.f, 0.f, 0.f, 0.f};
            p0 = __builtin_amdgcn_mfma_f32_16x16x32_bf16(af, c1f0, p0, 0, 0, 0);
            p1 = __builtin_amdgcn_mfma_f32_16x16x32_bf16(af, c1f1, p1, 0, 0, 0);
            const int window = mt * 4 + lg;        // lane's 4 accs = one 2x2 pool window
            if (window < 169) {
                const float m0 = fmaxf(fmaxf(p0.x, p0.y), fmaxf(p0.z, p0.w)) + b1s[l15];
                const float m1 = fmaxf(fmaxf(p1.x, p1.y), fmaxf(p1.z, p1.w)) + b1s[16 + l15];
                h1p[window * 40 + l15]      = f2bf(fmaxf(m0, 0.f));
                h1p[window * 40 + 16 + l15] = f2bf(fmaxf(m1, 0.f));
            }
        }
        __syncthreads();   // h1p ready; xsp free

        // ---- conv2 phase: write next x to xsp, then implicit-GEMM + pool -> featbuf ----
        if (have_next) {
            const unsigned short h = f2bf(f0);
            const unsigned short l = f2bf(f0 - bf2f(h));
            xsp[tid] = (unsigned int)h | ((unsigned int)l << 16);
            if (tid + BLOCK < 784) {
                const unsigned short h2 = f2bf(f1);
                const unsigned short l2 = f2bf(f1 - bf2f(h2));
                xsp[tid + BLOCK] = (unsigned int)h2 | ((unsigned int)l2 << 16);
            }
        }
        #pragma unroll
        for (int mi = 0; mi < 2; ++mi) {
            const int mt = mt0 + mi * 4;
            const int m = mt * 16 + l15;
            int wsrc = m >> 2; if (wsrc > 24) wsrc = 24;
            const int s = m & 3;
            const int cy = 2 * (wsrc / 5) + (s >> 1);
            const int cx = 2 * (wsrc % 5) + (s & 1);
            const char* abase = (const char*)h1p + (cy * 13 + cx) * 80 + lg * 16;
            f32x4 a0 = {0.f, 0.f, 0.f, 0.f};
            f32x4 a1 = {0.f, 0.f, 0.f, 0.f};
            #pragma unroll
            for (int ky = 0; ky < 3; ky++) {
                #pragma unroll
                for (int kx = 0; kx < 3; kx++) {
                    const short8 af = *(const short8*)(abase + (ky * 13 + kx) * 80);
                    a0 = __builtin_amdgcn_mfma_f32_16x16x32_bf16(af, bfA[ky * 3 + kx], a0, 0, 0, 0);
                    a1 = __builtin_amdgcn_mfma_f32_16x16x32_bf16(af, bfB[ky * 3 + kx], a1, 0, 0, 0);
                }
            }
            const int wv = mt * 4 + lg;
            if (wv < 25) {
                const int oc0 = n0 * 16 + l15;
                const float m0 = fmaxf(fmaxf(a0.x, a0.y), fmaxf(a0.z, a0.w)) + b2s[oc0];
                const float m1 = fmaxf(fmaxf(a1.x, a1.y), fmaxf(a1.z, a1.w)) + b2s[oc0 + 16];
                featbuf[it * FB_STRIDE + wv * 64 + oc0]      = f2bf(fmaxf(m0, 0.f));
                featbuf[it * FB_STRIDE + wv * 64 + oc0 + 16] = f2bf(fmaxf(m1, 0.f));
            }
        }
        __syncthreads();   // featbuf[it] ready; xsp ready; h1p free
    } // it

    // ---- experts + gate GEMM, split-K over 8 waves: [IPB x 1600] @ [1600 x 55] ----
    {
        const unsigned short* ewt = ws + EWT_OFF;
        const int kh = wid >> 2;
        const int ntE = wid & 3;
        const int bc = ntE * 16 + l15;
        const int arow = l15 & (IPB - 1);   // image row (others duplicated)
        f32x4 acc = {0.f, 0.f, 0.f, 0.f};
        const int ks0 = kh * 25;
        for (int ks = ks0; ks < ks0 + 25; ++ks) {
            const short8 af = *(const short8*)&featbuf[arow * FB_STRIDE + ks * 32 + lg * 8];
            const short8 bf = *(const short8*)&ewt[(ks * 64 + bc) * 32 + lg * 8];
            acc = __builtin_amdgcn_mfma_f32_16x16x32_bf16(af, bf, acc, 0, 0, 0);
        }
        if (lane < 16 && bc < 56) {         // lg==0 -> C rows 0..3 = the 4 images
            allC[kh][0 * 56 + bc] = acc.x;
            allC[kh][1 * 56 + bc] = acc.y;
            allC[kh][2 * 56 + bc] = acc.z;
            allC[kh][3 * 56 + bc] = acc.w;
        }
    }
    __syncthreads();

    // ---- epilogue: gate softmax, top-3 (bitmask), combine, final softmax ----
    if (tid < IPB) {
        const int img = img0 + tid;
        if (img < B) {
            float gv[5], mx = -1e30f;
            #pragma unroll
            for (int g = 0; g < 5; g++) {
                gv[g] = allC[0][tid * 56 + 50 + g] + allC[1][tid * 56 + 50 + g] + gb[g];
                mx = fmaxf(mx, gv[g]);
            }
            float ssum = 0.f;
            #pragma unroll
            for (int g = 0; g < 5; g++) { gv[g] = expf(gv[g] - mx); ssum += gv[g]; }
            const float inv = 1.f / ssum;
            #pragma unroll
            for (int g = 0; g < 5; g++) gv[g] *= inv;

            int idx0, idx1, idx2; float wv0, wv1, wv2;
            unsigned usedMask = 0;
            {
                int bi = 0; float bv = -1e30f;
                #pragma unroll
                for (int g = 0; g < 5; g++)
                    if (gv[g] > bv) { bv = gv[g]; bi = g; }   // strict >: lowest idx on tie
                idx0 = bi; wv0 = bv; usedMask |= (1u << bi);
            }
            {
                int bi = 0; float bv = -1e30f;
                #pragma unroll
                for (int g = 0; g < 5; g++)
                    if (!(usedMask & (1u << g)) && gv[g] > bv) { bv = gv[g]; bi = g; }
                idx1 = bi; wv1 = bv; usedMask |= (1u << bi);
            }
            {
                int bi = 0; float bv = -1e30f;
                #pragma unroll
                for (int g = 0; g < 5; g++)
                    if (!(usedMask & (1u << g)) && gv[g] > bv) { bv = gv[g]; bi = g; }
                idx2 = bi; wv2 = bv;
            }
            float comb[10];
            #pragma unroll
            for (int cc = 0; cc < 10; cc++) {
                comb[cc] = wv0 * (allC[0][tid * 56 + idx0 * 10 + cc] + allC[1][tid * 56 + idx0 * 10 + cc] + eb[idx0 * 10 + cc])
                         + wv1 * (allC[0][tid * 56 + idx1 * 10 + cc] + allC[1][tid * 56 + idx1 * 10 + cc] + eb[idx1 * 10 + cc])
                         + wv2 * (allC[0][tid * 56 + idx2 * 10 + cc] + allC[1][tid * 56 + idx2 * 10 + cc] + eb[idx2 * 10 + cc]);
            }
            float m2 = -1e30f;
            #pragma unroll
            for (int cc = 0; cc < 10; cc++) m2 = fmaxf(m2, comb[cc]);
            float e[10], s2 = 0.f;
            #pragma unroll
            for (int cc = 0; cc < 10; cc++) { e[cc] = expf(comb[cc] - m2); s2 += e[cc]; }
            const float inv2 = 1.f / s2;
            #pragma unroll
            for (int cc = 0; cc < 10; cc++) out[(size_t)img * 10 + cc] = e[cc] * inv2;
        }
    }
}

// ---------------- fallback (round-1 style, used only if ws too small) ----------------
__global__ __launch_bounds__(BLOCK, 1)
void moe_fused_fallback(const float* __restrict__ x, const float* __restrict__ w1,
                        const float* __restrict__ b1, const float* __restrict__ w2,
                        const float* __restrict__ b2, const float* __restrict__ gw,
                        const float* __restrict__ gb, const float* __restrict__ ew,
                        const float* __restrict__ eb, float* __restrict__ out)
{
    __shared__ float xs[784];
    __shared__ float w1s[288];
    __shared__ float b1s[32];
    __shared__ float w2s[18432];
    __shared__ float b2s[64];
    __shared__ float h1[5408];
    __shared__ float feat[1600];
    __shared__ float allout[5][10];
    __shared__ float gsm[5];

    const int tid = threadIdx.x;
    const int img = blockIdx.x;
    const float* xg = x + img * 784;
    for (int i = tid; i < 784; i += BLOCK) xs[i] = xg[i];
    for (int i = tid; i < 288; i += BLOCK) w1s[i] = w1[i];
    if (tid < 32) b1s[tid] = b1[tid];
    for (int i = tid; i < 18432; i += BLOCK) w2s[i] = w2[i];
    if (tid < 64) b2s[tid] = b2[tid];
    __syncthreads();

    for (int i = tid; i < 5408; i += BLOCK) {
        const int oc = i & 31, sp = i >> 5, px = sp % 13, py = sp / 13;
        float a0 = 0.f, a1 = 0.f, a2 = 0.f, a3 = 0.f;
        #pragma unroll
        for (int ky = 0; ky < 3; ky++)
            #pragma unroll
            for (int kx = 0; kx < 3; kx++) {
                const float w = w1s[(ky * 3 + kx) * 32 + oc];
                const int r0 = 2 * py + ky, c0 = 2 * px + kx;
                a0 += w * xs[r0 * 28 + c0];       a1 += w * xs[r0 * 28 + c0 + 1];
                a2 += w * xs[(r0 + 1) * 28 + c0]; a3 += w * xs[(r0 + 1) * 28 + c0 + 1];
            }
        h1[i] = fmaxf(fmaxf(fmaxf(a0, a1), fmaxf(a2, a3)) + b1s[oc], 0.f);
    }
    __syncthreads();

    for (int i = tid; i < 1600; i += BLOCK) {
        const int oc = i & 63, sp = i >> 6, px = sp % 5, py = sp / 5;
        float a0 = 0.f, a1 = 0.f, a2 = 0.f, a3 = 0.f;
        #pragma unroll
        for (int ky = 0; ky < 3; ky++)
            #pragma unroll
            for (int kx = 0; kx < 3; kx++) {
                const int hb = ((2 * py + ky) * 13 + (2 * px + kx)) * 32;
                const float* wrow = &w2s[((ky * 3 + kx) * 32) * 64 + oc];
                #pragma unroll 8
                for (int ic = 0; ic < 32; ic++) {
                    const float w = wrow[ic * 64];
                    a0 += w * h1[hb + ic];        a1 += w * h1[hb + 32 + ic];
                    a2 += w * h1[hb + 416 + ic];  a3 += w * h1[hb + 448 + ic];
                }
            }
        feat[i] = fmaxf(fmaxf(fmaxf(a0, a1), fmaxf(a2, a3)) + b2s[oc], 0.f);
    }
    __syncthreads();

    const int wid = tid >> 6, lane = tid & 63;
    if (wid < 5) {
        const float* ewp = ew + wid * 16000;
        float acc[10];
        #pragma unroll
        for (int c = 0; c < 10; c++) acc[c] = 0.f;
        for (int d = lane; d < 1600; d += 64) {
            const float f = feat[d]; const float* wr = ewp + d * 10;
            #pragma unroll
            for (int c = 0; c < 10; c++) acc[c] += f * wr[c];
        }
        #pragma unroll
        for (int c = 0; c < 10; c++)
            for (int off = 32; off; off >>= 1) acc[c] += __shfl_down(acc[c], off);
        if (lane == 0)
            #pragma unroll
            for (int c = 0; c < 10; c++) allout[wid][c] = acc[c] + eb[wid * 10 + c];
    } else if (wid == 5) {
        float acc[5] = {0.f, 0.f, 0.f, 0.f, 0.f};
        for (int d = lane; d < 1600; d += 64) {
            const float f = feat[d]; const float* wr = gw + d * 5;
            #pragma unroll
            for (int g = 0; g < 5; g++) acc[g] += f * wr[g];
        }
        #pragma unroll
        for (int g = 0; g < 5; g++)
            for (int off = 32; off; off >>= 1) acc[g] += __shfl_down(acc[g], off);
        if (lane == 0) {
            float l[5], mx = -1e30f;
            #pragma unroll
            for (int g = 0; g < 5; g++) { l[g] = acc[g] + gb[g]; mx = fmaxf(mx, l[g]); }
            float s = 0.f;
            #pragma unroll
            for (int g = 0; g < 5; g++) { l[g] = expf(l[g] - mx); s += l[g]; }
            const float inv = 1.f / s;
            #pragma unroll
            for (int g = 0; g < 5; g++) gsm[g] = l[g] * inv;
        }
    }
    __syncthreads();

    if (tid == 0) {
        float gv[5];
        #pragma unroll
        for (int g = 0; g < 5; g++) gv[g] = gsm[g];
        int idx0, idx1, idx2; float wv0, wv1, wv2;
        unsigned usedMask = 0;
        {
            int bi = 0; float bv = -1e30f;
            #pragma unroll
            for (int g = 0; g < 5; g++) if (gv[g] > bv) { bv = gv[g]; bi = g; }
            idx0 = bi; wv0 = bv; usedMask |= (1u << bi);
        }
        {
            int bi = 0; float bv = -1e30f;
            #pragma unroll
            for (int g = 0; g < 5; g++) if (!(usedMask & (1u << g)) && gv[g] > bv) { bv = gv[g]; bi = g; }
            idx1 = bi; wv1 = bv; usedMask |= (1u << bi);
        }
        {
            int bi = 0; float bv = -1e30f;
            #pragma unroll
            for (int g = 0; g < 5; g++) if (!(usedMask & (1u << g)) && gv[g] > bv) { bv = gv[g]; bi = g; }
            idx2 = bi; wv2 = bv;
        }
        float comb[10];
        #pragma unroll
        for (int cc = 0; cc < 10; cc++)
            comb[cc] = wv0 * allout[idx0][cc] + wv1 * allout[idx1][cc] + wv2 * allout[idx2][cc];
        float mx = -1e30f;
        #pragma unroll
        for (int cc = 0; cc < 10; cc++) mx = fmaxf(mx, comb[cc]);
        float e[10], s = 0.f;
        #pragma unroll
        for (int cc = 0; cc < 10; cc++) { e[cc] = expf(comb[cc] - mx); s += e[cc]; }
        const float inv = 1.f / s;
        #pragma unroll
        for (int cc = 0; cc < 10; cc++) out[img * 10 + cc] = e[cc] * inv;
    }
}

extern "C" void kernel_launch(void* const* d_in, const int* in_sizes, int n_in,
                              void* d_out, int out_size, void* d_ws, size_t ws_size,
                              hipStream_t stream) {
    const float* x   = (const float*)d_in[0];
    const float* w1  = (const float*)d_in[1];
    const float* b1  = (const float*)d_in[2];
    const float* w2  = (const float*)d_in[3];
    const float* b2  = (const float*)d_in[4];
    const float* gw  = (const float*)d_in[5];
    const float* gb  = (const float*)d_in[6];
    const float* ew  = (const float*)d_in[7];
    const float* eb  = (const float*)d_in[8];
    float* out = (float*)d_out;
    const int B = in_sizes[0] / 784;

    const size_t WS_NEEDED = WS_SHORTS * sizeof(unsigned short);
    if (ws_size >= WS_NEEDED) {
        unsigned short* ws = (unsigned short*)d_ws;
        moe_prep<<<(WS_SHORTS + 255) / 256, 256, 0, stream>>>(w2, gw, ew, w1, ws);
        const int nblk = (B + IPB - 1) / IPB;
        moe_main<<<nblk, BLOCK, 0, stream>>>(x, b1, b2, gb, eb, ws, out, B);
    } else {
        moe_fused_fallback<<<B, BLOCK, 0, stream>>>(x, w1, b1, w2, b2, gw, gb, ew, eb, out);
    }
}

// Round 9
// 102.590 us; speedup vs baseline: 2.2120x; 1.0675x over previous
//
#include <hip/hip_runtime.h>
#include <hip/hip_bf16.h>

#define BLOCK 512
#define IPB 4            // images per block
#define FB_STRIDE 1616   // featbuf row stride in shorts: 808 dw = 8 mod 32 -> 4-row reads conflict-free
#define H1_STRIDE 48     // h1p row stride in shorts: 96 B = 16B-aligned, 2-way-free writes

// ws layout (shorts):
#define W2T_OFF 0        // [kpos=9][oc=64][j=32]  (j = ic-pair-interleaved)   18432
#define EWT_OFF 18432    // [ks=50][n=64][k=32] experts+gate (k perm'd)        102400
#define W1C_OFF 120832   // [n=32][k=32] conv1 hi/lo B matrix                  1024
#define WS_SHORTS 121856

typedef __attribute__((ext_vector_type(8))) short short8;
typedef __attribute__((ext_vector_type(4))) float f32x4;

#define SEL_LO 0x05040100u   // perm(y,x,SEL_LO)  = (x&0xffff)|(y<<16)   : low halves (xh)
#define SEL_HI 0x07060302u   // perm(y,x,SEL_HI)  = (x>>16)|(y&0xffff0000): high halves (xl)

static __device__ __forceinline__ unsigned short f2bf(float f) {
    unsigned int u = __builtin_bit_cast(unsigned int, f);
    u = (u + 0x7FFFu + ((u >> 16) & 1u)) >> 16;   // RNE
    return (unsigned short)u;
}
static __device__ __forceinline__ float bf2f(unsigned short h) {
    unsigned int u = ((unsigned int)h) << 16;
    return __builtin_bit_cast(float, u);
}
static __device__ __forceinline__ unsigned int pack_hl(float v) {
    // (hi bf16 | lo bf16<<16), RNE both
    const unsigned short h = f2bf(v);
    const unsigned short l = f2bf(v - bf2f(h));
    return (unsigned int)h | ((unsigned int)l << 16);
}
static __device__ __forceinline__ unsigned int pkbf2(float a, float b) {
    return (unsigned int)f2bf(a) | ((unsigned int)f2bf(b) << 16);   // a low, b high
}

// ---------------- prep kernel: build bf16 weight layouts in d_ws ----------------
__global__ void moe_prep(const float* __restrict__ w2, const float* __restrict__ gw,
                         const float* __restrict__ ew, const float* __restrict__ w1,
                         unsigned short* __restrict__ ws) {
    int i = blockIdx.x * 256 + threadIdx.x;
    if (i < 18432) {
        int kpos = i >> 11, rem = i & 2047, oc = rem >> 5, j = rem & 31;
        int ic = ((j & 1) << 4) | (j >> 1);        // h1p pair-interleave: j=2*l+h <-> ic=h*16+l
        ws[W2T_OFF + i] = f2bf(w2[(kpos * 32 + ic) * 64 + oc]);
    }
    int j2 = i - EWT_OFF;
    if (j2 >= 0 && j2 < 102400) {
        int ks = j2 >> 11, rem = j2 & 2047, n = rem >> 5, k = rem & 31;
        int kk = ks * 32 + k;                      // permuted flatten index
        int wv = kk >> 6, jj = kk & 63;
        int r = jj & 31;
        int oc = ((jj >> 5) << 5) | ((r & 1) << 4) | (r >> 1);   // featbuf pair-interleave
        int d = wv * 64 + oc;                      // original flatten dim
        float v = 0.f;
        if (n < 50)      v = ew[(n / 10) * 16000 + d * 10 + (n % 10)];
        else if (n < 55) v = gw[d * 5 + (n - 50)];
        ws[EWT_OFF + j2] = f2bf(v);
    }
    int p = i - W1C_OFF;
    if (p >= 0 && p < 1024) {
        // conv1 B: [n=32][k=32]; k 0-8: w1hi(tap k), 9-17: w1lo(tap k-9), 18-26: w1hi(tap k-18)
        int n = p >> 5, k = p & 31;
        unsigned short val = 0;
        if (k < 27) {
            int t = (k < 9) ? k : (k < 18 ? k - 9 : k - 18);
            float w = w1[t * 32 + n];
            unsigned short hi = f2bf(w);
            val = (k >= 9 && k < 18) ? f2bf(w - bf2f(hi)) : hi;
        }
        ws[W1C_OFF + p] = val;
    }
}

// ---------------- main fused kernel ----------------
// NOTE: this toolchain treats __launch_bounds__ arg2 as min BLOCKS/CU (CUDA semantics).
// N=4 -> 64-VGPR cap = 4 blocks/CU (32 waves). Verified: N=6 -> 40 (spills), N=2 -> 128.
__global__ __launch_bounds__(BLOCK, 4)
void moe_main(const float* __restrict__ x, const float* __restrict__ b1,
              const float* __restrict__ b2, const float* __restrict__ gb,
              const float* __restrict__ eb, const unsigned short* __restrict__ ws,
              float* __restrict__ out, int B)
{
    __shared__ unsigned int xsp[784];                          // (hi|lo) packed x, 3136 B
    __shared__ __align__(16) unsigned short h1p[169 * H1_STRIDE];      // 16224 B
    __shared__ __align__(16) unsigned short featbuf[IPB * FB_STRIDE];  // 12928 B
    __shared__ float b1s[32];
    __shared__ float b2s[64];
    __shared__ float allC[2][IPB * 56];                        // split-K halves

    const int tid  = threadIdx.x;
    const int wid  = tid >> 6;
    const int lane = tid & 63;
    const int l15  = lane & 15;
    const int lg   = lane >> 4;

    if (tid < 32) b1s[tid] = b1[tid];
    if (tid < 64) b2s[tid] = b2[tid];

    // ---- conv2: wave owns M-tiles {mt0, mt0+4} x N-tiles {n0, n0+1}; bfrag persistent ----
    const int mt0 = wid >> 1;
    const int n0  = (wid & 1) * 2;
    short8 bfA[9], bfB[9];
    #pragma unroll
    for (int kp = 0; kp < 9; kp++) {
        bfA[kp] = *(const short8*)&ws[W2T_OFF + (kp * 64 + n0 * 16 + l15) * 32 + lg * 8];
        bfB[kp] = *(const short8*)&ws[W2T_OFF + (kp * 64 + (n0 + 1) * 16 + l15) * 32 + lg * 8];
    }
    // ---- conv1 B fragments (both 16-col tiles), persistent ----
    const short8 c1f0 = *(const short8*)&ws[W1C_OFF + l15 * 32 + lg * 8];
    const short8 c1f1 = *(const short8*)&ws[W1C_OFF + (16 + l15) * 32 + lg * 8];

    const int img0 = blockIdx.x * IPB;
    {   // prologue: stage image 0 (fp32 -> hi|lo packed)
        int im = img0 < B ? img0 : B - 1;
        const float* xg = x + (size_t)im * 784;
        xsp[tid] = pack_hl(xg[tid]);
        if (tid + BLOCK < 784) xsp[tid + BLOCK] = pack_hl(xg[tid + BLOCK]);
    }
    __syncthreads();

    for (int it = 0; it < IPB; ++it) {
        // ---- issue next image's global loads early (latency hides under conv1) ----
        float f0 = 0.f, f1 = 0.f;
        const bool have_next = (it + 1 < IPB);
        if (have_next) {
            int im2 = img0 + it + 1; if (im2 >= B) im2 = B - 1;
            const float* xg2 = x + (size_t)im2 * 784;
            f0 = xg2[tid];
            if (tid + BLOCK < 784) f1 = xg2[tid + BLOCK];
        }

        // ---- conv1: A-fragments built in registers from xsp, MFMA, pool -> h1p ----
        for (int mt = wid; mt < 43; mt += 8) {
            int wsrc = mt * 4 + (l15 >> 2); if (wsrc > 168) wsrc = 168;
            const int s  = l15 & 3;
            const int cy = 2 * (wsrc / 13) + (s >> 1);
            const int cx = 2 * (wsrc % 13) + (s & 1);
            const unsigned int* xb = &xsp[cy * 28 + cx];
            const unsigned int t0 = xb[0],  t1 = xb[1],  t2 = xb[2];
            const unsigned int t3 = xb[28], t4 = xb[29], t5 = xb[30];
            const unsigned int t6 = xb[56], t7 = xb[57], t8 = xb[58];
            // A row: k0-8 = xh taps, k9-17 = xh taps, k18-26 = xl taps, k27-31 = 0
            unsigned int a0, a1, a2, a3;
            if (lg == 0)      { a0 = __builtin_amdgcn_perm(t1, t0, SEL_LO);
                                a1 = __builtin_amdgcn_perm(t3, t2, SEL_LO);
                                a2 = __builtin_amdgcn_perm(t5, t4, SEL_LO);
                                a3 = __builtin_amdgcn_perm(t7, t6, SEL_LO); }
            else if (lg == 1) { a0 = __builtin_amdgcn_perm(t0, t8, SEL_LO);
                                a1 = __builtin_amdgcn_perm(t2, t1, SEL_LO);
                                a2 = __builtin_amdgcn_perm(t4, t3, SEL_LO);
                                a3 = __builtin_amdgcn_perm(t6, t5, SEL_LO); }
            else if (lg == 2) { a0 = __builtin_amdgcn_perm(t8, t7, SEL_LO);
                                a1 = __builtin_amdgcn_perm(t1, t0, SEL_HI);
                                a2 = __builtin_amdgcn_perm(t3, t2, SEL_HI);
                                a3 = __builtin_amdgcn_perm(t5, t4, SEL_HI); }
            else              { a0 = __builtin_amdgcn_perm(t7, t6, SEL_HI);
                                a1 = (t8 >> 16); a2 = 0u; a3 = 0u; }
            const uint4 av = make_uint4(a0, a1, a2, a3);
            const short8 af = __builtin_bit_cast(short8, av);
            f32x4 p0 = {0.f, 0.f, 0.f, 0.f};
            f32x4 p1 = {0.f, 0.f, 0.f, 0.f};
            p0 = __builtin_amdgcn_mfma_f32_16x16x32_bf16(af, c1f0, p0, 0, 0, 0);
            p1 = __builtin_amdgcn_mfma_f32_16x16x32_bf16(af, c1f1, p1, 0, 0, 0);
            const int window = mt * 4 + lg;        // lane's 4 accs = one 2x2 pool window
            if (window < 169) {
                const float m0 = fmaxf(fmaxf(p0.x, p0.y), fmaxf(p0.z, p0.w)) + b1s[l15];
                const float m1 = fmaxf(fmaxf(p1.x, p1.y), fmaxf(p1.z, p1.w)) + b1s[16 + l15];
                // paired write: j=2*l15 -> oc=l15, j=2*l15+1 -> oc=16+l15 (w2t prep compensates)
                *(unsigned int*)&h1p[window * H1_STRIDE + 2 * l15] =
                    pkbf2(fmaxf(m0, 0.f), fmaxf(m1, 0.f));
            }
        }
        __syncthreads();   // h1p ready; xsp free

        // ---- conv2 phase: write next x to xsp, then implicit-GEMM + pool -> featbuf ----
        if (have_next) {
            xsp[tid] = pack_hl(f0);
            if (tid + BLOCK < 784) xsp[tid + BLOCK] = pack_hl(f1);
        }
        #pragma unroll
        for (int mi = 0; mi < 2; ++mi) {
            const int mt = mt0 + mi * 4;
            const int m = mt * 16 + l15;
            int wsrc = m >> 2; if (wsrc > 24) wsrc = 24;
            const int s = m & 3;
            const int cy = 2 * (wsrc / 5) + (s >> 1);
            const int cx = 2 * (wsrc % 5) + (s & 1);
            const char* abase = (const char*)h1p + (cy * 13 + cx) * (H1_STRIDE * 2) + lg * 16;
            f32x4 a0 = {0.f, 0.f, 0.f, 0.f};
            f32x4 a1 = {0.f, 0.f, 0.f, 0.f};
            #pragma unroll
            for (int ky = 0; ky < 3; ky++) {
                #pragma unroll
                for (int kx = 0; kx < 3; kx++) {
                    const short8 af = *(const short8*)(abase + (ky * 13 + kx) * (H1_STRIDE * 2));
                    a0 = __builtin_amdgcn_mfma_f32_16x16x32_bf16(af, bfA[ky * 3 + kx], a0, 0, 0, 0);
                    a1 = __builtin_amdgcn_mfma_f32_16x16x32_bf16(af, bfB[ky * 3 + kx], a1, 0, 0, 0);
                }
            }
            const int wv = mt * 4 + lg;
            if (wv < 25) {
                const int oc0 = n0 * 16 + l15;
                const float m0 = fmaxf(fmaxf(a0.x, a0.y), fmaxf(a0.z, a0.w)) + b2s[oc0];
                const float m1 = fmaxf(fmaxf(a1.x, a1.y), fmaxf(a1.z, a1.w)) + b2s[oc0 + 16];
                // paired write at jj = 32*(n0>>1) + 2*l15 (+1); ewt prep compensates
                *(unsigned int*)&featbuf[it * FB_STRIDE + wv * 64 + ((n0 >> 1) << 5) + 2 * l15] =
                    pkbf2(fmaxf(m0, 0.f), fmaxf(m1, 0.f));
            }
        }
        __syncthreads();   // featbuf[it] ready; xsp ready; h1p free
    } // it

    // ---- experts + gate GEMM, split-K over 8 waves: [IPB x 1600] @ [1600 x 55] ----
    {
        const unsigned short* ewt = ws + EWT_OFF;
        const int kh = wid >> 2;
        const int ntE = wid & 3;
        const int bc = ntE * 16 + l15;
        const int arow = l15 & (IPB - 1);   // image row (others duplicated)
        f32x4 acc = {0.f, 0.f, 0.f, 0.f};
        const int ks0 = kh * 25;
        for (int ks = ks0; ks < ks0 + 25; ++ks) {
            const short8 af = *(const short8*)&featbuf[arow * FB_STRIDE + ks * 32 + lg * 8];
            const short8 bf = *(const short8*)&ewt[(ks * 64 + bc) * 32 + lg * 8];
            acc = __builtin_amdgcn_mfma_f32_16x16x32_bf16(af, bf, acc, 0, 0, 0);
        }
        if (lane < 16 && bc < 56) {         // lg==0 -> C rows 0..3 = the 4 images
            allC[kh][0 * 56 + bc] = acc.x;
            allC[kh][1 * 56 + bc] = acc.y;
            allC[kh][2 * 56 + bc] = acc.z;
            allC[kh][3 * 56 + bc] = acc.w;
        }
    }
    __syncthreads();

    // ---- epilogue: gate softmax, top-3 (bitmask), combine, final softmax ----
    if (tid < IPB) {
        const int img = img0 + tid;
        if (img < B) {
            float gv[5], mx = -1e30f;
            #pragma unroll
            for (int g = 0; g < 5; g++) {
                gv[g] = allC[0][tid * 56 + 50 + g] + allC[1][tid * 56 + 50 + g] + gb[g];
                mx = fmaxf(mx, gv[g]);
            }
            float ssum = 0.f;
            #pragma unroll
            for (int g = 0; g < 5; g++) { gv[g] = expf(gv[g] - mx); ssum += gv[g]; }
            const float inv = 1.f / ssum;
            #pragma unroll
            for (int g = 0; g < 5; g++) gv[g] *= inv;

            int idx0, idx1, idx2; float wv0, wv1, wv2;
            unsigned usedMask = 0;
            {
                int bi = 0; float bv = -1e30f;
                #pragma unroll
                for (int g = 0; g < 5; g++)
                    if (gv[g] > bv) { bv = gv[g]; bi = g; }   // strict >: lowest idx on tie
                idx0 = bi; wv0 = bv; usedMask |= (1u << bi);
            }
            {
                int bi = 0; float bv = -1e30f;
                #pragma unroll
                for (int g = 0; g < 5; g++)
                    if (!(usedMask & (1u << g)) && gv[g] > bv) { bv = gv[g]; bi = g; }
                idx1 = bi; wv1 = bv; usedMask |= (1u << bi);
            }
            {
                int bi = 0; float bv = -1e30f;
                #pragma unroll
                for (int g = 0; g < 5; g++)
                    if (!(usedMask & (1u << g)) && gv[g] > bv) { bv = gv[g]; bi = g; }
                idx2 = bi; wv2 = bv;
            }
            float comb[10];
            #pragma unroll
            for (int cc = 0; cc < 10; cc++) {
                comb[cc] = wv0 * (allC[0][tid * 56 + idx0 * 10 + cc] + allC[1][tid * 56 + idx0 * 10 + cc] + eb[idx0 * 10 + cc])
                         + wv1 * (allC[0][tid * 56 + idx1 * 10 + cc] + allC[1][tid * 56 + idx1 * 10 + cc] + eb[idx1 * 10 + cc])
                         + wv2 * (allC[0][tid * 56 + idx2 * 10 + cc] + allC[1][tid * 56 + idx2 * 10 + cc] + eb[idx2 * 10 + cc]);
            }
            float m2 = -1e30f;
            #pragma unroll
            for (int cc = 0; cc < 10; cc++) m2 = fmaxf(m2, comb[cc]);
            float e[10], s2 = 0.f;
            #pragma unroll
            for (int cc = 0; cc < 10; cc++) { e[cc] = expf(comb[cc] - m2); s2 += e[cc]; }
            const float inv2 = 1.f / s2;
            #pragma unroll
            for (int cc = 0; cc < 10; cc++) out[(size_t)img * 10 + cc] = e[cc] * inv2;
        }
    }
}

// ---------------- fallback (round-1 style, used only if ws too small) ----------------
__global__ __launch_bounds__(BLOCK, 1)
void moe_fused_fallback(const float* __restrict__ x, const float* __restrict__ w1,
                        const float* __restrict__ b1, const float* __restrict__ w2,
                        const float* __restrict__ b2, const float* __restrict__ gw,
                        const float* __restrict__ gb, const float* __restrict__ ew,
                        const float* __restrict__ eb, float* __restrict__ out)
{
    __shared__ float xs[784];
    __shared__ float w1s[288];
    __shared__ float b1s[32];
    __shared__ float w2s[18432];
    __shared__ float b2s[64];
    __shared__ float h1[5408];
    __shared__ float feat[1600];
    __shared__ float allout[5][10];
    __shared__ float gsm[5];

    const int tid = threadIdx.x;
    const int img = blockIdx.x;
    const float* xg = x + img * 784;
    for (int i = tid; i < 784; i += BLOCK) xs[i] = xg[i];
    for (int i = tid; i < 288; i += BLOCK) w1s[i] = w1[i];
    if (tid < 32) b1s[tid] = b1[tid];
    for (int i = tid; i < 18432; i += BLOCK) w2s[i] = w2[i];
    if (tid < 64) b2s[tid] = b2[tid];
    __syncthreads();

    for (int i = tid; i < 5408; i += BLOCK) {
        const int oc = i & 31, sp = i >> 5, px = sp % 13, py = sp / 13;
        float a0 = 0.f, a1 = 0.f, a2 = 0.f, a3 = 0.f;
        #pragma unroll
        for (int ky = 0; ky < 3; ky++)
            #pragma unroll
            for (int kx = 0; kx < 3; kx++) {
                const float w = w1s[(ky * 3 + kx) * 32 + oc];
                const int r0 = 2 * py + ky, c0 = 2 * px + kx;
                a0 += w * xs[r0 * 28 + c0];       a1 += w * xs[r0 * 28 + c0 + 1];
                a2 += w * xs[(r0 + 1) * 28 + c0]; a3 += w * xs[(r0 + 1) * 28 + c0 + 1];
            }
        h1[i] = fmaxf(fmaxf(fmaxf(a0, a1), fmaxf(a2, a3)) + b1s[oc], 0.f);
    }
    __syncthreads();

    for (int i = tid; i < 1600; i += BLOCK) {
        const int oc = i & 63, sp = i >> 6, px = sp % 5, py = sp / 5;
        float a0 = 0.f, a1 = 0.f, a2 = 0.f, a3 = 0.f;
        #pragma unroll
        for (int ky = 0; ky < 3; ky++)
            #pragma unroll
            for (int kx = 0; kx < 3; kx++) {
                const int hb = ((2 * py + ky) * 13 + (2 * px + kx)) * 32;
                const float* wrow = &w2s[((ky * 3 + kx) * 32) * 64 + oc];
                #pragma unroll 8
                for (int ic = 0; ic < 32; ic++) {
                    const float w = wrow[ic * 64];
                    a0 += w * h1[hb + ic];        a1 += w * h1[hb + 32 + ic];
                    a2 += w * h1[hb + 416 + ic];  a3 += w * h1[hb + 448 + ic];
                }
            }
        feat[i] = fmaxf(fmaxf(fmaxf(a0, a1), fmaxf(a2, a3)) + b2s[oc], 0.f);
    }
    __syncthreads();

    const int wid = tid >> 6, lane = tid & 63;
    if (wid < 5) {
        const float* ewp = ew + wid * 16000;
        float acc[10];
        #pragma unroll
        for (int c = 0; c < 10; c++) acc[c] = 0.f;
        for (int d = lane; d < 1600; d += 64) {
            const float f = feat[d]; const float* wr = ewp + d * 10;
            #pragma unroll
            for (int c = 0; c < 10; c++) acc[c] += f * wr[c];
        }
        #pragma unroll
        for (int c = 0; c < 10; c++)
            for (int off = 32; off; off >>= 1) acc[c] += __shfl_down(acc[c], off);
        if (lane == 0)
            #pragma unroll
            for (int c = 0; c < 10; c++) allout[wid][c] = acc[c] + eb[wid * 10 + c];
    } else if (wid == 5) {
        float acc[5] = {0.f, 0.f, 0.f, 0.f, 0.f};
        for (int d = lane; d < 1600; d += 64) {
            const float f = feat[d]; const float* wr = gw + d * 5;
            #pragma unroll
            for (int g = 0; g < 5; g++) acc[g] += f * wr[g];
        }
        #pragma unroll
        for (int g = 0; g < 5; g++)
            for (int off = 32; off; off >>= 1) acc[g] += __shfl_down(acc[g], off);
        if (lane == 0) {
            float l[5], mx = -1e30f;
            #pragma unroll
            for (int g = 0; g < 5; g++) { l[g] = acc[g] + gb[g]; mx = fmaxf(mx, l[g]); }
            float s = 0.f;
            #pragma unroll
            for (int g = 0; g < 5; g++) { l[g] = expf(l[g] - mx); s += l[g]; }
            const float inv = 1.f / s;
            #pragma unroll
            for (int g = 0; g < 5; g++) gsm[g] = l[g] * inv;
        }
    }
    __syncthreads();

    if (tid == 0) {
        float gv[5];
        #pragma unroll
        for (int g = 0; g < 5; g++) gv[g] = gsm[g];
        int idx0, idx1, idx2; float wv0, wv1, wv2;
        unsigned usedMask = 0;
        {
            int bi = 0; float bv = -1e30f;
            #pragma unroll
            for (int g = 0; g < 5; g++) if (gv[g] > bv) { bv = gv[g]; bi = g; }
            idx0 = bi; wv0 = bv; usedMask |= (1u << bi);
        }
        {
            int bi = 0; float bv = -1e30f;
            #pragma unroll
            for (int g = 0; g < 5; g++) if (!(usedMask & (1u << g)) && gv[g] > bv) { bv = gv[g]; bi = g; }
            idx1 = bi; wv1 = bv; usedMask |= (1u << bi);
        }
        {
            int bi = 0; float bv = -1e30f;
            #pragma unroll
            for (int g = 0; g < 5; g++) if (!(usedMask & (1u << g)) && gv[g] > bv) { bv = gv[g]; bi = g; }
            idx2 = bi; wv2 = bv;
        }
        float comb[10];
        #pragma unroll
        for (int cc = 0; cc < 10; cc++)
            comb[cc] = wv0 * allout[idx0][cc] + wv1 * allout[idx1][cc] + wv2 * allout[idx2][cc];
        float mx = -1e30f;
        #pragma unroll
        for (int cc = 0; cc < 10; cc++) mx = fmaxf(mx, comb[cc]);
        float e[10], s = 0.f;
        #pragma unroll
        for (int cc = 0; cc < 10; cc++) { e[cc] = expf(comb[cc] - mx); s += e[cc]; }
        const float inv = 1.f / s;
        #pragma unroll
        for (int cc = 0; cc < 10; cc++) out[img * 10 + cc] = e[cc] * inv;
    }
}

extern "C" void kernel_launch(void* const* d_in, const int* in_sizes, int n_in,
                              void* d_out, int out_size, void* d_ws, size_t ws_size,
                              hipStream_t stream) {
    const float* x   = (const float*)d_in[0];
    const float* w1  = (const float*)d_in[1];
    const float* b1  = (const float*)d_in[2];
    const float* w2  = (const float*)d_in[3];
    const float* b2  = (const float*)d_in[4];
    const float* gw  = (const float*)d_in[5];
    const float* gb  = (const float*)d_in[6];
    const float* ew  = (const float*)d_in[7];
    const float* eb  = (const float*)d_in[8];
    float* out = (float*)d_out;
    const int B = in_sizes[0] / 784;

    const size_t WS_NEEDED = WS_SHORTS * sizeof(unsigned short);
    if (ws_size >= WS_NEEDED) {
        unsigned short* ws = (unsigned short*)d_ws;
        moe_prep<<<(WS_SHORTS + 255) / 256, 256, 0, stream>>>(w2, gw, ew, w1, ws);
        const int nblk = (B + IPB - 1) / IPB;
        moe_main<<<nblk, BLOCK, 0, stream>>>(x, b1, b2, gb, eb, ws, out, B);
    } else {
        moe_fused_fallback<<<B, BLOCK, 0, stream>>>(x, w1, b1, w2, b2, gw, gb, ew, eb, out);
    }
}

// Round 10
// 101.611 us; speedup vs baseline: 2.2334x; 1.0096x over previous
//
#include <hip/hip_runtime.h>
#include <hip/hip_bf16.h>

#define BLOCK 512
#define IPB 4            // images per block
#define FB_STRIDE 1616   // featbuf row stride in shorts: 808 dw = 8 mod 32 -> 4-row reads conflict-free
#define H1_STRIDE 40     // h1p row stride in shorts: 80 B = 16B-aligned

// ws layout (shorts):
#define W2T_OFF 0        // [kpos=9][oc=64][j=32]  (j = ic-pair-interleaved)   18432
#define EWT_OFF 18432    // [ks=50][n=64][k=32] experts+gate (k perm'd)        102400
#define W1C_OFF 120832   // [n=32][k=32] conv1 hi/lo B matrix                  1024
#define WS_SHORTS 121856

typedef __attribute__((ext_vector_type(8))) short short8;
typedef __attribute__((ext_vector_type(4))) float f32x4;

#define SEL_LO 0x05040100u   // perm(y,x,SEL_LO)  = (x&0xffff)|(y<<16)   : low halves (xh)
#define SEL_HI 0x07060302u   // perm(y,x,SEL_HI)  = (x>>16)|(y&0xffff0000): high halves (xl)

static __device__ __forceinline__ unsigned short f2bf(float f) {
    unsigned int u = __builtin_bit_cast(unsigned int, f);
    u = (u + 0x7FFFu + ((u >> 16) & 1u)) >> 16;   // RNE
    return (unsigned short)u;
}
static __device__ __forceinline__ float bf2f(unsigned short h) {
    unsigned int u = ((unsigned int)h) << 16;
    return __builtin_bit_cast(float, u);
}
static __device__ __forceinline__ unsigned int pack_hl(float v) {
    const unsigned short h = f2bf(v);
    const unsigned short l = f2bf(v - bf2f(h));
    return (unsigned int)h | ((unsigned int)l << 16);
}
static __device__ __forceinline__ unsigned int pkbf2(float a, float b) {
    return (unsigned int)f2bf(a) | ((unsigned int)f2bf(b) << 16);   // a low, b high
}

// ---------------- prep kernel: build bf16 weight layouts in d_ws ----------------
__global__ void moe_prep(const float* __restrict__ w2, const float* __restrict__ gw,
                         const float* __restrict__ ew, const float* __restrict__ w1,
                         unsigned short* __restrict__ ws) {
    int i = blockIdx.x * 256 + threadIdx.x;
    if (i < 18432) {
        int kpos = i >> 11, rem = i & 2047, oc = rem >> 5, j = rem & 31;
        int ic = ((j & 1) << 4) | (j >> 1);        // h1p pair-interleave: j=2*l+h <-> ic=h*16+l
        ws[W2T_OFF + i] = f2bf(w2[(kpos * 32 + ic) * 64 + oc]);
    }
    int j2 = i - EWT_OFF;
    if (j2 >= 0 && j2 < 102400) {
        int ks = j2 >> 11, rem = j2 & 2047, n = rem >> 5, k = rem & 31;
        int kk = ks * 32 + k;                      // permuted flatten index
        int wv = kk >> 6, jj = kk & 63;
        int r = jj & 31;
        int oc = ((jj >> 5) << 5) | ((r & 1) << 4) | (r >> 1);   // featbuf pair-interleave
        int d = wv * 64 + oc;                      // original flatten dim
        float v = 0.f;
        if (n < 50)      v = ew[(n / 10) * 16000 + d * 10 + (n % 10)];
        else if (n < 55) v = gw[d * 5 + (n - 50)];
        ws[EWT_OFF + j2] = f2bf(v);
    }
    int p = i - W1C_OFF;
    if (p >= 0 && p < 1024) {
        // conv1 B: [n=32][k=32]; k 0-8: w1hi(tap k), 9-17: w1lo(tap k-9), 18-26: w1hi(tap k-18)
        int n = p >> 5, k = p & 31;
        unsigned short val = 0;
        if (k < 27) {
            int t = (k < 9) ? k : (k < 18 ? k - 9 : k - 18);
            float w = w1[t * 32 + n];
            unsigned short hi = f2bf(w);
            val = (k >= 9 && k < 18) ? f2bf(w - bf2f(hi)) : hi;
        }
        ws[W1C_OFF + p] = val;
    }
}

// ---------------- main fused kernel ----------------
// NOTE: this toolchain treats __launch_bounds__ arg2 as min BLOCKS/CU (CUDA semantics).
// N=3 -> 85-VGPR cap, 3 blocks/CU at 48.4 KB LDS (24 waves/CU).
__global__ __launch_bounds__(BLOCK, 3)
void moe_main(const float* __restrict__ x, const float* __restrict__ b1,
              const float* __restrict__ b2, const float* __restrict__ gb,
              const float* __restrict__ eb, const unsigned short* __restrict__ ws,
              float* __restrict__ out, int B)
{
    __shared__ unsigned int xsp[2][784];                        // (hi|lo) packed x, 6272 B
    __shared__ __align__(16) unsigned short h1p[2][169 * H1_STRIDE];   // 27040 B
    __shared__ __align__(16) unsigned short featbuf[IPB * FB_STRIDE];  // 12928 B
    __shared__ float b1s[32];
    __shared__ float b2s[64];
    __shared__ float allC[2][IPB * 56];                         // split-K halves

    const int tid  = threadIdx.x;
    const int wid  = tid >> 6;
    const int lane = tid & 63;
    const int l15  = lane & 15;
    const int lg   = lane >> 4;

    if (tid < 32) b1s[tid] = b1[tid];
    if (tid < 64) b2s[tid] = b2[tid];

    // ---- conv2: wave owns M-tiles {mt0, mt0+4} x N-tiles {n0, n0+1}; bfrag persistent ----
    const int mt0 = wid >> 1;
    const int n0  = (wid & 1) * 2;
    short8 bfA[9], bfB[9];
    #pragma unroll
    for (int kp = 0; kp < 9; kp++) {
        bfA[kp] = *(const short8*)&ws[W2T_OFF + (kp * 64 + n0 * 16 + l15) * 32 + lg * 8];
        bfB[kp] = *(const short8*)&ws[W2T_OFF + (kp * 64 + (n0 + 1) * 16 + l15) * 32 + lg * 8];
    }
    // ---- conv1 B fragments (both 16-col tiles), persistent ----
    const short8 c1f0 = *(const short8*)&ws[W1C_OFF + l15 * 32 + lg * 8];
    const short8 c1f1 = *(const short8*)&ws[W1C_OFF + (16 + l15) * 32 + lg * 8];

    const int img0 = blockIdx.x * IPB;
    {   // prologue: stage image 0 (fp32 -> hi|lo packed) into xsp[0]
        int im = img0 < B ? img0 : B - 1;
        const float* xg = x + (size_t)im * 784;
        xsp[0][tid] = pack_hl(xg[tid]);
        if (tid + BLOCK < 784) xsp[0][tid + BLOCK] = pack_hl(xg[tid + BLOCK]);
    }
    __syncthreads();

    // ---- software-pipelined phases: phase p = conv2(img p-1) || conv1(img p) ----
    #pragma unroll
    for (int p = 0; p <= IPB; ++p) {
        const bool do_c1 = (p < IPB);
        const bool do_c2 = (p >= 1);
        const bool pre   = (p + 1 < IPB);

        // issue next-next image's global loads early
        float f0 = 0.f, f1 = 0.f;
        if (pre) {
            int im2 = img0 + p + 1; if (im2 >= B) im2 = B - 1;
            const float* xg2 = x + (size_t)im2 * 784;
            f0 = xg2[tid];
            if (tid + BLOCK < 784) f1 = xg2[tid + BLOCK];
        }

        // ---- conv2(img p-1): implicit-GEMM MFMA, h1p[(p-1)&1] -> featbuf[p-1] ----
        if (do_c2) {
            const int it = p - 1;
            const unsigned short* h1cur = h1p[it & 1];
            #pragma unroll
            for (int mi = 0; mi < 2; ++mi) {
                const int mt = mt0 + mi * 4;
                const int m = mt * 16 + l15;
                int wsrc = m >> 2; if (wsrc > 24) wsrc = 24;
                const int s = m & 3;
                const int cy = 2 * (wsrc / 5) + (s >> 1);
                const int cx = 2 * (wsrc % 5) + (s & 1);
                const char* abase = (const char*)h1cur + (cy * 13 + cx) * (H1_STRIDE * 2) + lg * 16;
                f32x4 a0 = {0.f, 0.f, 0.f, 0.f};
                f32x4 a1 = {0.f, 0.f, 0.f, 0.f};
                #pragma unroll
                for (int ky = 0; ky < 3; ky++) {
                    #pragma unroll
                    for (int kx = 0; kx < 3; kx++) {
                        const short8 af = *(const short8*)(abase + (ky * 13 + kx) * (H1_STRIDE * 2));
                        a0 = __builtin_amdgcn_mfma_f32_16x16x32_bf16(af, bfA[ky * 3 + kx], a0, 0, 0, 0);
                        a1 = __builtin_amdgcn_mfma_f32_16x16x32_bf16(af, bfB[ky * 3 + kx], a1, 0, 0, 0);
                    }
                }
                const int wv = mt * 4 + lg;
                if (wv < 25) {
                    const int oc0 = n0 * 16 + l15;
                    const float m0 = fmaxf(fmaxf(a0.x, a0.y), fmaxf(a0.z, a0.w)) + b2s[oc0];
                    const float m1 = fmaxf(fmaxf(a1.x, a1.y), fmaxf(a1.z, a1.w)) + b2s[oc0 + 16];
                    *(unsigned int*)&featbuf[it * FB_STRIDE + wv * 64 + ((n0 >> 1) << 5) + 2 * l15] =
                        pkbf2(fmaxf(m0, 0.f), fmaxf(m1, 0.f));
                }
            }
        }

        // ---- conv1(img p): reg-built A-fragments from xsp[p&1], MFMA, pool -> h1p[p&1] ----
        if (do_c1) {
            const unsigned int* xcur = xsp[p & 1];
            unsigned short* h1dst = h1p[p & 1];
            for (int mt = wid; mt < 43; mt += 8) {
                int wsrc = mt * 4 + (l15 >> 2); if (wsrc > 168) wsrc = 168;
                const int s  = l15 & 3;
                const int cy = 2 * (wsrc / 13) + (s >> 1);
                const int cx = 2 * (wsrc % 13) + (s & 1);
                const unsigned int* xb = &xcur[cy * 28 + cx];
                const unsigned int t0 = xb[0],  t1 = xb[1],  t2 = xb[2];
                const unsigned int t3 = xb[28], t4 = xb[29], t5 = xb[30];
                const unsigned int t6 = xb[56], t7 = xb[57], t8 = xb[58];
                unsigned int a0, a1, a2, a3;
                if (lg == 0)      { a0 = __builtin_amdgcn_perm(t1, t0, SEL_LO);
                                    a1 = __builtin_amdgcn_perm(t3, t2, SEL_LO);
                                    a2 = __builtin_amdgcn_perm(t5, t4, SEL_LO);
                                    a3 = __builtin_amdgcn_perm(t7, t6, SEL_LO); }
                else if (lg == 1) { a0 = __builtin_amdgcn_perm(t0, t8, SEL_LO);
                                    a1 = __builtin_amdgcn_perm(t2, t1, SEL_LO);
                                    a2 = __builtin_amdgcn_perm(t4, t3, SEL_LO);
                                    a3 = __builtin_amdgcn_perm(t6, t5, SEL_LO); }
                else if (lg == 2) { a0 = __builtin_amdgcn_perm(t8, t7, SEL_LO);
                                    a1 = __builtin_amdgcn_perm(t1, t0, SEL_HI);
                                    a2 = __builtin_amdgcn_perm(t3, t2, SEL_HI);
                                    a3 = __builtin_amdgcn_perm(t5, t4, SEL_HI); }
                else              { a0 = __builtin_amdgcn_perm(t7, t6, SEL_HI);
                                    a1 = (t8 >> 16); a2 = 0u; a3 = 0u; }
                const uint4 av = make_uint4(a0, a1, a2, a3);
                const short8 af = __builtin_bit_cast(short8, av);
                f32x4 p0 = {0.f, 0.f, 0.f, 0.f};
                f32x4 p1 = {0.f, 0.f, 0.f, 0.f};
                p0 = __builtin_amdgcn_mfma_f32_16x16x32_bf16(af, c1f0, p0, 0, 0, 0);
                p1 = __builtin_amdgcn_mfma_f32_16x16x32_bf16(af, c1f1, p1, 0, 0, 0);
                const int window = mt * 4 + lg;
                if (window < 169) {
                    const float m0 = fmaxf(fmaxf(p0.x, p0.y), fmaxf(p0.z, p0.w)) + b1s[l15];
                    const float m1 = fmaxf(fmaxf(p1.x, p1.y), fmaxf(p1.z, p1.w)) + b1s[16 + l15];
                    *(unsigned int*)&h1dst[window * H1_STRIDE + 2 * l15] =
                        pkbf2(fmaxf(m0, 0.f), fmaxf(m1, 0.f));
                }
            }
        }

        // ---- write next image into the other xsp buffer (read next phase) ----
        if (pre) {
            xsp[(p + 1) & 1][tid] = pack_hl(f0);
            if (tid + BLOCK < 784) xsp[(p + 1) & 1][tid + BLOCK] = pack_hl(f1);
        }
        __syncthreads();
    } // p

    // ---- experts + gate GEMM, split-K over 8 waves: [IPB x 1600] @ [1600 x 55] ----
    {
        const unsigned short* ewt = ws + EWT_OFF;
        const int kh = wid >> 2;
        const int ntE = wid & 3;
        const int bc = ntE * 16 + l15;
        const int arow = l15 & (IPB - 1);   // image row (others duplicated)
        f32x4 acc = {0.f, 0.f, 0.f, 0.f};
        const int ks0 = kh * 25;
        for (int ks = ks0; ks < ks0 + 25; ++ks) {
            const short8 af = *(const short8*)&featbuf[arow * FB_STRIDE + ks * 32 + lg * 8];
            const short8 bf = *(const short8*)&ewt[(ks * 64 + bc) * 32 + lg * 8];
            acc = __builtin_amdgcn_mfma_f32_16x16x32_bf16(af, bf, acc, 0, 0, 0);
        }
        if (lane < 16 && bc < 56) {         // lg==0 -> C rows 0..3 = the 4 images
            allC[kh][0 * 56 + bc] = acc.x;
            allC[kh][1 * 56 + bc] = acc.y;
            allC[kh][2 * 56 + bc] = acc.z;
            allC[kh][3 * 56 + bc] = acc.w;
        }
    }
    __syncthreads();

    // ---- epilogue: gate softmax, top-3 (bitmask), combine, final softmax ----
    if (tid < IPB) {
        const int img = img0 + tid;
        if (img < B) {
            float gv[5], mx = -1e30f;
            #pragma unroll
            for (int g = 0; g < 5; g++) {
                gv[g] = allC[0][tid * 56 + 50 + g] + allC[1][tid * 56 + 50 + g] + gb[g];
                mx = fmaxf(mx, gv[g]);
            }
            float ssum = 0.f;
            #pragma unroll
            for (int g = 0; g < 5; g++) { gv[g] = expf(gv[g] - mx); ssum += gv[g]; }
            const float inv = 1.f / ssum;
            #pragma unroll
            for (int g = 0; g < 5; g++) gv[g] *= inv;

            int idx0, idx1, idx2; float wv0, wv1, wv2;
            unsigned usedMask = 0;
            {
                int bi = 0; float bv = -1e30f;
                #pragma unroll
                for (int g = 0; g < 5; g++)
                    if (gv[g] > bv) { bv = gv[g]; bi = g; }   // strict >: lowest idx on tie
                idx0 = bi; wv0 = bv; usedMask |= (1u << bi);
            }
            {
                int bi = 0; float bv = -1e30f;
                #pragma unroll
                for (int g = 0; g < 5; g++)
                    if (!(usedMask & (1u << g)) && gv[g] > bv) { bv = gv[g]; bi = g; }
                idx1 = bi; wv1 = bv; usedMask |= (1u << bi);
            }
            {
                int bi = 0; float bv = -1e30f;
                #pragma unroll
                for (int g = 0; g < 5; g++)
                    if (!(usedMask & (1u << g)) && gv[g] > bv) { bv = gv[g]; bi = g; }
                idx2 = bi; wv2 = bv;
            }
            float comb[10];
            #pragma unroll
            for (int cc = 0; cc < 10; cc++) {
                comb[cc] = wv0 * (allC[0][tid * 56 + idx0 * 10 + cc] + allC[1][tid * 56 + idx0 * 10 + cc] + eb[idx0 * 10 + cc])
                         + wv1 * (allC[0][tid * 56 + idx1 * 10 + cc] + allC[1][tid * 56 + idx1 * 10 + cc] + eb[idx1 * 10 + cc])
                         + wv2 * (allC[0][tid * 56 + idx2 * 10 + cc] + allC[1][tid * 56 + idx2 * 10 + cc] + eb[idx2 * 10 + cc]);
            }
            float m2 = -1e30f;
            #pragma unroll
            for (int cc = 0; cc < 10; cc++) m2 = fmaxf(m2, comb[cc]);
            float e[10], s2 = 0.f;
            #pragma unroll
            for (int cc = 0; cc < 10; cc++) { e[cc] = expf(comb[cc] - m2); s2 += e[cc]; }
            const float inv2 = 1.f / s2;
            #pragma unroll
            for (int cc = 0; cc < 10; cc++) out[(size_t)img * 10 + cc] = e[cc] * inv2;
        }
    }
}

// ---------------- fallback (round-1 style, used only if ws too small) ----------------
__global__ __launch_bounds__(BLOCK, 1)
void moe_fused_fallback(const float* __restrict__ x, const float* __restrict__ w1,
                        const float* __restrict__ b1, const float* __restrict__ w2,
                        const float* __restrict__ b2, const float* __restrict__ gw,
                        const float* __restrict__ gb, const float* __restrict__ ew,
                        const float* __restrict__ eb, float* __restrict__ out)
{
    __shared__ float xs[784];
    __shared__ float w1s[288];
    __shared__ float b1s[32];
    __shared__ float w2s[18432];
    __shared__ float b2s[64];
    __shared__ float h1[5408];
    __shared__ float feat[1600];
    __shared__ float allout[5][10];
    __shared__ float gsm[5];

    const int tid = threadIdx.x;
    const int img = blockIdx.x;
    const float* xg = x + img * 784;
    for (int i = tid; i < 784; i += BLOCK) xs[i] = xg[i];
    for (int i = tid; i < 288; i += BLOCK) w1s[i] = w1[i];
    if (tid < 32) b1s[tid] = b1[tid];
    for (int i = tid; i < 18432; i += BLOCK) w2s[i] = w2[i];
    if (tid < 64) b2s[tid] = b2[tid];
    __syncthreads();

    for (int i = tid; i < 5408; i += BLOCK) {
        const int oc = i & 31, sp = i >> 5, px = sp % 13, py = sp / 13;
        float a0 = 0.f, a1 = 0.f, a2 = 0.f, a3 = 0.f;
        #pragma unroll
        for (int ky = 0; ky < 3; ky++)
            #pragma unroll
            for (int kx = 0; kx < 3; kx++) {
                const float w = w1s[(ky * 3 + kx) * 32 + oc];
                const int r0 = 2 * py + ky, c0 = 2 * px + kx;
                a0 += w * xs[r0 * 28 + c0];       a1 += w * xs[r0 * 28 + c0 + 1];
                a2 += w * xs[(r0 + 1) * 28 + c0]; a3 += w * xs[(r0 + 1) * 28 + c0 + 1];
            }
        h1[i] = fmaxf(fmaxf(fmaxf(a0, a1), fmaxf(a2, a3)) + b1s[oc], 0.f);
    }
    __syncthreads();

    for (int i = tid; i < 1600; i += BLOCK) {
        const int oc = i & 63, sp = i >> 6, px = sp % 5, py = sp / 5;
        float a0 = 0.f, a1 = 0.f, a2 = 0.f, a3 = 0.f;
        #pragma unroll
        for (int ky = 0; ky < 3; ky++)
            #pragma unroll
            for (int kx = 0; kx < 3; kx++) {
                const int hb = ((2 * py + ky) * 13 + (2 * px + kx)) * 32;
                const float* wrow = &w2s[((ky * 3 + kx) * 32) * 64 + oc];
                #pragma unroll 8
                for (int ic = 0; ic < 32; ic++) {
                    const float w = wrow[ic * 64];
                    a0 += w * h1[hb + ic];        a1 += w * h1[hb + 32 + ic];
                    a2 += w * h1[hb + 416 + ic];  a3 += w * h1[hb + 448 + ic];
                }
            }
        feat[i] = fmaxf(fmaxf(fmaxf(a0, a1), fmaxf(a2, a3)) + b2s[oc], 0.f);
    }
    __syncthreads();

    const int wid = tid >> 6, lane = tid & 63;
    if (wid < 5) {
        const float* ewp = ew + wid * 16000;
        float acc[10];
        #pragma unroll
        for (int c = 0; c < 10; c++) acc[c] = 0.f;
        for (int d = lane; d < 1600; d += 64) {
            const float f = feat[d]; const float* wr = ewp + d * 10;
            #pragma unroll
            for (int c = 0; c < 10; c++) acc[c] += f * wr[c];
        }
        #pragma unroll
        for (int c = 0; c < 10; c++)
            for (int off = 32; off; off >>= 1) acc[c] += __shfl_down(acc[c], off);
        if (lane == 0)
            #pragma unroll
            for (int c = 0; c < 10; c++) allout[wid][c] = acc[c] + eb[wid * 10 + c];
    } else if (wid == 5) {
        float acc[5] = {0.f, 0.f, 0.f, 0.f, 0.f};
        for (int d = lane; d < 1600; d += 64) {
            const float f = feat[d]; const float* wr = gw + d * 5;
            #pragma unroll
            for (int g = 0; g < 5; g++) acc[g] += f * wr[g];
        }
        #pragma unroll
        for (int g = 0; g < 5; g++)
            for (int off = 32; off; off >>= 1) acc[g] += __shfl_down(acc[g], off);
        if (lane == 0) {
            float l[5], mx = -1e30f;
            #pragma unroll
            for (int g = 0; g < 5; g++) { l[g] = acc[g] + gb[g]; mx = fmaxf(mx, l[g]); }
            float s = 0.f;
            #pragma unroll
            for (int g = 0; g < 5; g++) { l[g] = expf(l[g] - mx); s += l[g]; }
            const float inv = 1.f / s;
            #pragma unroll
            for (int g = 0; g < 5; g++) gsm[g] = l[g] * inv;
        }
    }
    __syncthreads();

    if (tid == 0) {
        float gv[5];
        #pragma unroll
        for (int g = 0; g < 5; g++) gv[g] = gsm[g];
        int idx0, idx1, idx2; float wv0, wv1, wv2;
        unsigned usedMask = 0;
        {
            int bi = 0; float bv = -1e30f;
            #pragma unroll
            for (int g = 0; g < 5; g++) if (gv[g] > bv) { bv = gv[g]; bi = g; }
            idx0 = bi; wv0 = bv; usedMask |= (1u << bi);
        }
        {
            int bi = 0; float bv = -1e30f;
            #pragma unroll
            for (int g = 0; g < 5; g++) if (!(usedMask & (1u << g)) && gv[g] > bv) { bv = gv[g]; bi = g; }
            idx1 = bi; wv1 = bv; usedMask |= (1u << bi);
        }
        {
            int bi = 0; float bv = -1e30f;
            #pragma unroll
            for (int g = 0; g < 5; g++) if (!(usedMask & (1u << g)) && gv[g] > bv) { bv = gv[g]; bi = g; }
            idx2 = bi; wv2 = bv;
        }
        float comb[10];
        #pragma unroll
        for (int cc = 0; cc < 10; cc++)
            comb[cc] = wv0 * allout[idx0][cc] + wv1 * allout[idx1][cc] + wv2 * allout[idx2][cc];
        float mx = -1e30f;
        #pragma unroll
        for (int cc = 0; cc < 10; cc++) mx = fmaxf(mx, comb[cc]);
        float e[10], s = 0.f;
        #pragma unroll
        for (int cc = 0; cc < 10; cc++) { e[cc] = expf(comb[cc] - mx); s += e[cc]; }
        const float inv = 1.f / s;
        #pragma unroll
        for (int cc = 0; cc < 10; cc++) out[img * 10 + cc] = e[cc] * inv;
    }
}

extern "C" void kernel_launch(void* const* d_in, const int* in_sizes, int n_in,
                              void* d_out, int out_size, void* d_ws, size_t ws_size,
                              hipStream_t stream) {
    const float* x   = (const float*)d_in[0];
    const float* w1  = (const float*)d_in[1];
    const float* b1  = (const float*)d_in[2];
    const float* w2  = (const float*)d_in[3];
    const float* b2  = (const float*)d_in[4];
    const float* gw  = (const float*)d_in[5];
    const float* gb  = (const float*)d_in[6];
    const float* ew  = (const float*)d_in[7];
    const float* eb  = (const float*)d_in[8];
    float* out = (float*)d_out;
    const int B = in_sizes[0] / 784;

    const size_t WS_NEEDED = WS_SHORTS * sizeof(unsigned short);
    if (ws_size >= WS_NEEDED) {
        unsigned short* ws = (unsigned short*)d_ws;
        moe_prep<<<(WS_SHORTS + 255) / 256, 256, 0, stream>>>(w2, gw, ew, w1, ws);
        const int nblk = (B + IPB - 1) / IPB;
        moe_main<<<nblk, BLOCK, 0, stream>>>(x, b1, b2, gb, eb, ws, out, B);
    } else {
        moe_fused_fallback<<<B, BLOCK, 0, stream>>>(x, w1, b1, w2, b2, gw, gb, ew, eb, out);
    }
}

// Round 11
// 97.989 us; speedup vs baseline: 2.3159x; 1.0370x over previous
//
#include <hip/hip_runtime.h>
#include <hip/hip_bf16.h>

#define BLOCK 512
#define IPB 4            // images per block (conv kernel)
#define EIPB 16          // images per block (expert kernel)
#define FB_STRIDE 1616   // fused-path featbuf stride (shorts)
#define ES_STRIDE 1608   // expert featS stride: 804 dw = 4 mod 32 -> 16-row reads ~2-way
#define H1_STRIDE 40     // h1p row stride in shorts: 80 B, 16B-aligned

// ws layout (shorts):
#define W2T_OFF 0        // [kpos=9][oc=64][j=32]  (j = ic-pair-interleaved)   18432
#define EWT_OFF 18432    // [ks=50][n=64][k=32] experts+gate (k perm'd)        102400
#define W1C_OFF 120832   // [n=32][k=32] conv1 hi/lo B matrix                  1024
#define WS_SHORTS 121856
#define FEAT_OFF 121856  // [B][1600] bf16 feat (k perm'd) — full path only

typedef __attribute__((ext_vector_type(8))) short short8;
typedef __attribute__((ext_vector_type(4))) float f32x4;

#define SEL_LO 0x05040100u   // perm(y,x,SEL_LO)  = (x&0xffff)|(y<<16)    : low halves (xh)
#define SEL_HI 0x07060302u   // perm(y,x,SEL_HI)  = (x>>16)|(y&0xffff0000): high halves (xl)

static __device__ __forceinline__ unsigned short f2bf(float f) {
    unsigned int u = __builtin_bit_cast(unsigned int, f);
    u = (u + 0x7FFFu + ((u >> 16) & 1u)) >> 16;   // RNE
    return (unsigned short)u;
}
static __device__ __forceinline__ float bf2f(unsigned short h) {
    unsigned int u = ((unsigned int)h) << 16;
    return __builtin_bit_cast(float, u);
}
static __device__ __forceinline__ unsigned int pack_hl(float v) {
    const unsigned short h = f2bf(v);
    const unsigned short l = f2bf(v - bf2f(h));
    return (unsigned int)h | ((unsigned int)l << 16);
}
static __device__ __forceinline__ unsigned int pkbf2(float a, float b) {
    return (unsigned int)f2bf(a) | ((unsigned int)f2bf(b) << 16);   // a low, b high
}

// ---------------- prep kernel: build bf16 weight layouts in d_ws ----------------
__global__ void moe_prep(const float* __restrict__ w2, const float* __restrict__ gw,
                         const float* __restrict__ ew, const float* __restrict__ w1,
                         unsigned short* __restrict__ ws) {
    int i = blockIdx.x * 256 + threadIdx.x;
    if (i < 18432) {
        int kpos = i >> 11, rem = i & 2047, oc = rem >> 5, j = rem & 31;
        int ic = ((j & 1) << 4) | (j >> 1);        // h1p pair-interleave: j=2*l+h <-> ic=h*16+l
        ws[W2T_OFF + i] = f2bf(w2[(kpos * 32 + ic) * 64 + oc]);
    }
    int j2 = i - EWT_OFF;
    if (j2 >= 0 && j2 < 102400) {
        int ks = j2 >> 11, rem = j2 & 2047, n = rem >> 5, k = rem & 31;
        int kk = ks * 32 + k;                      // permuted flatten index
        int wv = kk >> 6, jj = kk & 63;
        int r = jj & 31;
        int oc = ((jj >> 5) << 5) | ((r & 1) << 4) | (r >> 1);   // feat pair-interleave
        int d = wv * 64 + oc;                      // original flatten dim
        float v = 0.f;
        if (n < 50)      v = ew[(n / 10) * 16000 + d * 10 + (n % 10)];
        else if (n < 55) v = gw[d * 5 + (n - 50)];
        ws[EWT_OFF + j2] = f2bf(v);
    }
    int p = i - W1C_OFF;
    if (p >= 0 && p < 1024) {
        // conv1 B: [n=32][k=32]; k 0-8: w1hi(tap k), 9-17: w1lo(tap k-9), 18-26: w1hi(tap k-18)
        int n = p >> 5, k = p & 31;
        unsigned short val = 0;
        if (k < 27) {
            int t = (k < 9) ? k : (k < 18 ? k - 9 : k - 18);
            float w = w1[t * 32 + n];
            unsigned short hi = f2bf(w);
            val = (k >= 9 && k < 18) ? f2bf(w - bf2f(hi)) : hi;
        }
        ws[W1C_OFF + p] = val;
    }
}

// ---------------- conv kernel: conv1+pool -> conv2+pool -> feat (global) ----------------
// NOTE: this toolchain treats __launch_bounds__ arg2 as min BLOCKS/CU (CUDA semantics).
// N=4 -> 64-VGPR cap; LDS 33.4KB -> 4 blocks/CU = 32 waves (full wave cap).
__global__ __launch_bounds__(BLOCK, 4)
void moe_conv(const float* __restrict__ x, const float* __restrict__ b1,
              const float* __restrict__ b2, const unsigned short* __restrict__ ws,
              unsigned short* __restrict__ feat, int B)
{
    __shared__ unsigned int xsp[2][784];                        // (hi|lo) packed x, 6272 B
    __shared__ __align__(16) unsigned short h1p[2][169 * H1_STRIDE];   // 27040 B
    __shared__ float b1s[32];
    __shared__ float b2s[64];

    const int tid  = threadIdx.x;
    const int wid  = tid >> 6;
    const int lane = tid & 63;
    const int l15  = lane & 15;
    const int lg   = lane >> 4;

    if (tid < 32) b1s[tid] = b1[tid];
    if (tid < 64) b2s[tid] = b2[tid];

    // conv2: wave owns M-tiles {mt0, mt0+4} x N-tiles {n0, n0+1}; bfrag persistent
    const int mt0 = wid >> 1;
    const int n0  = (wid & 1) * 2;
    short8 bfA[9], bfB[9];
    #pragma unroll
    for (int kp = 0; kp < 9; kp++) {
        bfA[kp] = *(const short8*)&ws[W2T_OFF + (kp * 64 + n0 * 16 + l15) * 32 + lg * 8];
        bfB[kp] = *(const short8*)&ws[W2T_OFF + (kp * 64 + (n0 + 1) * 16 + l15) * 32 + lg * 8];
    }
    const short8 c1f0 = *(const short8*)&ws[W1C_OFF + l15 * 32 + lg * 8];
    const short8 c1f1 = *(const short8*)&ws[W1C_OFF + (16 + l15) * 32 + lg * 8];

    const int img0 = blockIdx.x * IPB;
    {   // prologue: stage image 0
        int im = img0 < B ? img0 : B - 1;
        const float* xg = x + (size_t)im * 784;
        xsp[0][tid] = pack_hl(xg[tid]);
        if (tid + BLOCK < 784) xsp[0][tid + BLOCK] = pack_hl(xg[tid + BLOCK]);
    }
    __syncthreads();

    // software-pipelined phases: phase p = conv2(img p-1) || conv1(img p)
    #pragma unroll
    for (int p = 0; p <= IPB; ++p) {
        const bool do_c1 = (p < IPB);
        const bool do_c2 = (p >= 1);
        const bool pre   = (p + 1 < IPB);

        float f0 = 0.f, f1 = 0.f;
        if (pre) {
            int im2 = img0 + p + 1; if (im2 >= B) im2 = B - 1;
            const float* xg2 = x + (size_t)im2 * 784;
            f0 = xg2[tid];
            if (tid + BLOCK < 784) f1 = xg2[tid + BLOCK];
        }

        // conv2(img p-1): implicit-GEMM MFMA, h1p[(p-1)&1] -> global feat
        if (do_c2) {
            const int it = p - 1;
            const int img = img0 + it;
            const unsigned short* h1cur = h1p[it & 1];
            unsigned short* frow = feat + (size_t)img * 1600;
            #pragma unroll
            for (int mi = 0; mi < 2; ++mi) {
                const int mt = mt0 + mi * 4;
                const int m = mt * 16 + l15;
                int wsrc = m >> 2; if (wsrc > 24) wsrc = 24;
                const int s = m & 3;
                const int cy = 2 * (wsrc / 5) + (s >> 1);
                const int cx = 2 * (wsrc % 5) + (s & 1);
                const char* abase = (const char*)h1cur + (cy * 13 + cx) * (H1_STRIDE * 2) + lg * 16;
                f32x4 a0 = {0.f, 0.f, 0.f, 0.f};
                f32x4 a1 = {0.f, 0.f, 0.f, 0.f};
                #pragma unroll
                for (int ky = 0; ky < 3; ky++) {
                    #pragma unroll
                    for (int kx = 0; kx < 3; kx++) {
                        const short8 af = *(const short8*)(abase + (ky * 13 + kx) * (H1_STRIDE * 2));
                        a0 = __builtin_amdgcn_mfma_f32_16x16x32_bf16(af, bfA[ky * 3 + kx], a0, 0, 0, 0);
                        a1 = __builtin_amdgcn_mfma_f32_16x16x32_bf16(af, bfB[ky * 3 + kx], a1, 0, 0, 0);
                    }
                }
                const int wv = mt * 4 + lg;
                if (wv < 25 && img < B) {
                    const int oc0 = n0 * 16 + l15;
                    const float m0 = fmaxf(fmaxf(a0.x, a0.y), fmaxf(a0.z, a0.w)) + b2s[oc0];
                    const float m1 = fmaxf(fmaxf(a1.x, a1.y), fmaxf(a1.z, a1.w)) + b2s[oc0 + 16];
                    *(unsigned int*)&frow[wv * 64 + ((n0 >> 1) << 5) + 2 * l15] =
                        pkbf2(fmaxf(m0, 0.f), fmaxf(m1, 0.f));
                }
            }
        }

        // conv1(img p): reg-built A-fragments from xsp[p&1], MFMA, pool -> h1p[p&1]
        if (do_c1) {
            const unsigned int* xcur = xsp[p & 1];
            unsigned short* h1dst = h1p[p & 1];
            for (int mt = wid; mt < 43; mt += 8) {
                int wsrc = mt * 4 + (l15 >> 2); if (wsrc > 168) wsrc = 168;
                const int s  = l15 & 3;
                const int cy = 2 * (wsrc / 13) + (s >> 1);
                const int cx = 2 * (wsrc % 13) + (s & 1);
                const unsigned int* xb = &xcur[cy * 28 + cx];
                const unsigned int t0 = xb[0],  t1 = xb[1],  t2 = xb[2];
                const unsigned int t3 = xb[28], t4 = xb[29], t5 = xb[30];
                const unsigned int t6 = xb[56], t7 = xb[57], t8 = xb[58];
                unsigned int a0, a1, a2, a3;
                if (lg == 0)      { a0 = __builtin_amdgcn_perm(t1, t0, SEL_LO);
                                    a1 = __builtin_amdgcn_perm(t3, t2, SEL_LO);
                                    a2 = __builtin_amdgcn_perm(t5, t4, SEL_LO);
                                    a3 = __builtin_amdgcn_perm(t7, t6, SEL_LO); }
                else if (lg == 1) { a0 = __builtin_amdgcn_perm(t0, t8, SEL_LO);
                                    a1 = __builtin_amdgcn_perm(t2, t1, SEL_LO);
                                    a2 = __builtin_amdgcn_perm(t4, t3, SEL_LO);
                                    a3 = __builtin_amdgcn_perm(t6, t5, SEL_LO); }
                else if (lg == 2) { a0 = __builtin_amdgcn_perm(t8, t7, SEL_LO);
                                    a1 = __builtin_amdgcn_perm(t1, t0, SEL_HI);
                                    a2 = __builtin_amdgcn_perm(t3, t2, SEL_HI);
                                    a3 = __builtin_amdgcn_perm(t5, t4, SEL_HI); }
                else              { a0 = __builtin_amdgcn_perm(t7, t6, SEL_HI);
                                    a1 = (t8 >> 16); a2 = 0u; a3 = 0u; }
                const uint4 av = make_uint4(a0, a1, a2, a3);
                const short8 af = __builtin_bit_cast(short8, av);
                f32x4 p0 = {0.f, 0.f, 0.f, 0.f};
                f32x4 p1 = {0.f, 0.f, 0.f, 0.f};
                p0 = __builtin_amdgcn_mfma_f32_16x16x32_bf16(af, c1f0, p0, 0, 0, 0);
                p1 = __builtin_amdgcn_mfma_f32_16x16x32_bf16(af, c1f1, p1, 0, 0, 0);
                const int window = mt * 4 + lg;
                if (window < 169) {
                    const float m0 = fmaxf(fmaxf(p0.x, p0.y), fmaxf(p0.z, p0.w)) + b1s[l15];
                    const float m1 = fmaxf(fmaxf(p1.x, p1.y), fmaxf(p1.z, p1.w)) + b1s[16 + l15];
                    *(unsigned int*)&h1dst[window * H1_STRIDE + 2 * l15] =
                        pkbf2(fmaxf(m0, 0.f), fmaxf(m1, 0.f));
                }
            }
        }

        if (pre) {
            xsp[(p + 1) & 1][tid] = pack_hl(f0);
            if (tid + BLOCK < 784) xsp[(p + 1) & 1][tid + BLOCK] = pack_hl(f1);
        }
        __syncthreads();
    } // p
}

// ---------------- expert kernel: [B x 1600] @ [1600 x 55] + gate/top3/softmax ----------------
__global__ __launch_bounds__(BLOCK, 2)
void moe_expert(const unsigned short* __restrict__ ws, const float* __restrict__ gb,
                const float* __restrict__ eb, float* __restrict__ out, int B)
{
    __shared__ __align__(16) unsigned short featS[EIPB * ES_STRIDE];   // 51456 B
    __shared__ float allC[2][EIPB][64];                                 // 8192 B

    const int tid  = threadIdx.x;
    const int wid  = tid >> 6;
    const int lane = tid & 63;
    const int l15  = lane & 15;
    const int lg   = lane >> 4;

    const unsigned short* feat = ws + FEAT_OFF;
    const unsigned short* ewt  = ws + EWT_OFF;
    const int img0 = blockIdx.x * EIPB;

    // stage 16 images' feat rows into LDS (coalesced dword copies)
    for (int i = tid; i < EIPB * 800; i += BLOCK) {
        const int r = i / 800, c = i - r * 800;
        const int img = img0 + r;
        unsigned int v = 0u;
        if (img < B) v = *(const unsigned int*)&feat[(size_t)img * 1600 + 2 * c];
        *(unsigned int*)&featS[r * ES_STRIDE + 2 * c] = v;
    }
    __syncthreads();

    // GEMM: M=16 images (no duplication), N=64 (4 tiles), split-K halves over 8 waves
    {
        const int kh  = wid >> 2;
        const int ntE = wid & 3;
        const int bc  = ntE * 16 + l15;
        f32x4 acc = {0.f, 0.f, 0.f, 0.f};
        const int ks0 = kh * 25;
        for (int ks = ks0; ks < ks0 + 25; ++ks) {
            const short8 af = *(const short8*)&featS[l15 * ES_STRIDE + ks * 32 + lg * 8];
            const short8 bf = *(const short8*)&ewt[(ks * 64 + bc) * 32 + lg * 8];
            acc = __builtin_amdgcn_mfma_f32_16x16x32_bf16(af, bf, acc, 0, 0, 0);
        }
        // D: row (image) = lg*4 + reg, col = bc
        const int r0 = lg * 4;
        allC[kh][r0 + 0][bc] = acc.x;
        allC[kh][r0 + 1][bc] = acc.y;
        allC[kh][r0 + 2][bc] = acc.z;
        allC[kh][r0 + 3][bc] = acc.w;
    }
    __syncthreads();

    // epilogue: gate softmax, top-3 (bitmask), combine, final softmax
    if (tid < EIPB) {
        const int img = img0 + tid;
        if (img < B) {
            float gv[5], mx = -1e30f;
            #pragma unroll
            for (int g = 0; g < 5; g++) {
                gv[g] = allC[0][tid][50 + g] + allC[1][tid][50 + g] + gb[g];
                mx = fmaxf(mx, gv[g]);
            }
            float ssum = 0.f;
            #pragma unroll
            for (int g = 0; g < 5; g++) { gv[g] = expf(gv[g] - mx); ssum += gv[g]; }
            const float inv = 1.f / ssum;
            #pragma unroll
            for (int g = 0; g < 5; g++) gv[g] *= inv;

            int idx0, idx1, idx2; float wv0, wv1, wv2;
            unsigned usedMask = 0;
            {
                int bi = 0; float bv = -1e30f;
                #pragma unroll
                for (int g = 0; g < 5; g++)
                    if (gv[g] > bv) { bv = gv[g]; bi = g; }   // strict >: lowest idx on tie
                idx0 = bi; wv0 = bv; usedMask |= (1u << bi);
            }
            {
                int bi = 0; float bv = -1e30f;
                #pragma unroll
                for (int g = 0; g < 5; g++)
                    if (!(usedMask & (1u << g)) && gv[g] > bv) { bv = gv[g]; bi = g; }
                idx1 = bi; wv1 = bv; usedMask |= (1u << bi);
            }
            {
                int bi = 0; float bv = -1e30f;
                #pragma unroll
                for (int g = 0; g < 5; g++)
                    if (!(usedMask & (1u << g)) && gv[g] > bv) { bv = gv[g]; bi = g; }
                idx2 = bi; wv2 = bv;
            }
            float comb[10];
            #pragma unroll
            for (int cc = 0; cc < 10; cc++) {
                comb[cc] = wv0 * (allC[0][tid][idx0 * 10 + cc] + allC[1][tid][idx0 * 10 + cc] + eb[idx0 * 10 + cc])
                         + wv1 * (allC[0][tid][idx1 * 10 + cc] + allC[1][tid][idx1 * 10 + cc] + eb[idx1 * 10 + cc])
                         + wv2 * (allC[0][tid][idx2 * 10 + cc] + allC[1][tid][idx2 * 10 + cc] + eb[idx2 * 10 + cc]);
            }
            float m2 = -1e30f;
            #pragma unroll
            for (int cc = 0; cc < 10; cc++) m2 = fmaxf(m2, comb[cc]);
            float e[10], s2 = 0.f;
            #pragma unroll
            for (int cc = 0; cc < 10; cc++) { e[cc] = expf(comb[cc] - m2); s2 += e[cc]; }
            const float inv2 = 1.f / s2;
            #pragma unroll
            for (int cc = 0; cc < 10; cc++) out[(size_t)img * 10 + cc] = e[cc] * inv2;
        }
    }
}

// ---------------- fused fallback (round-10 kernel, used when ws can't hold feat) ----------------
__global__ __launch_bounds__(BLOCK, 3)
void moe_main_fused(const float* __restrict__ x, const float* __restrict__ b1,
                    const float* __restrict__ b2, const float* __restrict__ gb,
                    const float* __restrict__ eb, const unsigned short* __restrict__ ws,
                    float* __restrict__ out, int B)
{
    __shared__ unsigned int xsp[2][784];
    __shared__ __align__(16) unsigned short h1p[2][169 * H1_STRIDE];
    __shared__ __align__(16) unsigned short featbuf[IPB * FB_STRIDE];
    __shared__ float b1s[32];
    __shared__ float b2s[64];
    __shared__ float allC[2][IPB * 56];

    const int tid  = threadIdx.x;
    const int wid  = tid >> 6;
    const int lane = tid & 63;
    const int l15  = lane & 15;
    const int lg   = lane >> 4;

    if (tid < 32) b1s[tid] = b1[tid];
    if (tid < 64) b2s[tid] = b2[tid];

    const int mt0 = wid >> 1;
    const int n0  = (wid & 1) * 2;
    short8 bfA[9], bfB[9];
    #pragma unroll
    for (int kp = 0; kp < 9; kp++) {
        bfA[kp] = *(const short8*)&ws[W2T_OFF + (kp * 64 + n0 * 16 + l15) * 32 + lg * 8];
        bfB[kp] = *(const short8*)&ws[W2T_OFF + (kp * 64 + (n0 + 1) * 16 + l15) * 32 + lg * 8];
    }
    const short8 c1f0 = *(const short8*)&ws[W1C_OFF + l15 * 32 + lg * 8];
    const short8 c1f1 = *(const short8*)&ws[W1C_OFF + (16 + l15) * 32 + lg * 8];

    const int img0 = blockIdx.x * IPB;
    {
        int im = img0 < B ? img0 : B - 1;
        const float* xg = x + (size_t)im * 784;
        xsp[0][tid] = pack_hl(xg[tid]);
        if (tid + BLOCK < 784) xsp[0][tid + BLOCK] = pack_hl(xg[tid + BLOCK]);
    }
    __syncthreads();

    #pragma unroll
    for (int p = 0; p <= IPB; ++p) {
        const bool do_c1 = (p < IPB);
        const bool do_c2 = (p >= 1);
        const bool pre   = (p + 1 < IPB);

        float f0 = 0.f, f1 = 0.f;
        if (pre) {
            int im2 = img0 + p + 1; if (im2 >= B) im2 = B - 1;
            const float* xg2 = x + (size_t)im2 * 784;
            f0 = xg2[tid];
            if (tid + BLOCK < 784) f1 = xg2[tid + BLOCK];
        }

        if (do_c2) {
            const int it = p - 1;
            const unsigned short* h1cur = h1p[it & 1];
            #pragma unroll
            for (int mi = 0; mi < 2; ++mi) {
                const int mt = mt0 + mi * 4;
                const int m = mt * 16 + l15;
                int wsrc = m >> 2; if (wsrc > 24) wsrc = 24;
                const int s = m & 3;
                const int cy = 2 * (wsrc / 5) + (s >> 1);
                const int cx = 2 * (wsrc % 5) + (s & 1);
                const char* abase = (const char*)h1cur + (cy * 13 + cx) * (H1_STRIDE * 2) + lg * 16;
                f32x4 a0 = {0.f, 0.f, 0.f, 0.f};
                f32x4 a1 = {0.f, 0.f, 0.f, 0.f};
                #pragma unroll
                for (int ky = 0; ky < 3; ky++) {
                    #pragma unroll
                    for (int kx = 0; kx < 3; kx++) {
                        const short8 af = *(const short8*)(abase + (ky * 13 + kx) * (H1_STRIDE * 2));
                        a0 = __builtin_amdgcn_mfma_f32_16x16x32_bf16(af, bfA[ky * 3 + kx], a0, 0, 0, 0);
                        a1 = __builtin_amdgcn_mfma_f32_16x16x32_bf16(af, bfB[ky * 3 + kx], a1, 0, 0, 0);
                    }
                }
                const int wv = mt * 4 + lg;
                if (wv < 25) {
                    const int oc0 = n0 * 16 + l15;
                    const float m0 = fmaxf(fmaxf(a0.x, a0.y), fmaxf(a0.z, a0.w)) + b2s[oc0];
                    const float m1 = fmaxf(fmaxf(a1.x, a1.y), fmaxf(a1.z, a1.w)) + b2s[oc0 + 16];
                    *(unsigned int*)&featbuf[it * FB_STRIDE + wv * 64 + ((n0 >> 1) << 5) + 2 * l15] =
                        pkbf2(fmaxf(m0, 0.f), fmaxf(m1, 0.f));
                }
            }
        }

        if (do_c1) {
            const unsigned int* xcur = xsp[p & 1];
            unsigned short* h1dst = h1p[p & 1];
            for (int mt = wid; mt < 43; mt += 8) {
                int wsrc = mt * 4 + (l15 >> 2); if (wsrc > 168) wsrc = 168;
                const int s  = l15 & 3;
                const int cy = 2 * (wsrc / 13) + (s >> 1);
                const int cx = 2 * (wsrc % 13) + (s & 1);
                const unsigned int* xb = &xcur[cy * 28 + cx];
                const unsigned int t0 = xb[0],  t1 = xb[1],  t2 = xb[2];
                const unsigned int t3 = xb[28], t4 = xb[29], t5 = xb[30];
                const unsigned int t6 = xb[56], t7 = xb[57], t8 = xb[58];
                unsigned int a0, a1, a2, a3;
                if (lg == 0)      { a0 = __builtin_amdgcn_perm(t1, t0, SEL_LO);
                                    a1 = __builtin_amdgcn_perm(t3, t2, SEL_LO);
                                    a2 = __builtin_amdgcn_perm(t5, t4, SEL_LO);
                                    a3 = __builtin_amdgcn_perm(t7, t6, SEL_LO); }
                else if (lg == 1) { a0 = __builtin_amdgcn_perm(t0, t8, SEL_LO);
                                    a1 = __builtin_amdgcn_perm(t2, t1, SEL_LO);
                                    a2 = __builtin_amdgcn_perm(t4, t3, SEL_LO);
                                    a3 = __builtin_amdgcn_perm(t6, t5, SEL_LO); }
                else if (lg == 2) { a0 = __builtin_amdgcn_perm(t8, t7, SEL_LO);
                                    a1 = __builtin_amdgcn_perm(t1, t0, SEL_HI);
                                    a2 = __builtin_amdgcn_perm(t3, t2, SEL_HI);
                                    a3 = __builtin_amdgcn_perm(t5, t4, SEL_HI); }
                else              { a0 = __builtin_amdgcn_perm(t7, t6, SEL_HI);
                                    a1 = (t8 >> 16); a2 = 0u; a3 = 0u; }
                const uint4 av = make_uint4(a0, a1, a2, a3);
                const short8 af = __builtin_bit_cast(short8, av);
                f32x4 p0 = {0.f, 0.f, 0.f, 0.f};
                f32x4 p1 = {0.f, 0.f, 0.f, 0.f};
                p0 = __builtin_amdgcn_mfma_f32_16x16x32_bf16(af, c1f0, p0, 0, 0, 0);
                p1 = __builtin_amdgcn_mfma_f32_16x16x32_bf16(af, c1f1, p1, 0, 0, 0);
                const int window = mt * 4 + lg;
                if (window < 169) {
                    const float m0 = fmaxf(fmaxf(p0.x, p0.y), fmaxf(p0.z, p0.w)) + b1s[l15];
                    const float m1 = fmaxf(fmaxf(p1.x, p1.y), fmaxf(p1.z, p1.w)) + b1s[16 + l15];
                    *(unsigned int*)&h1dst[window * H1_STRIDE + 2 * l15] =
                        pkbf2(fmaxf(m0, 0.f), fmaxf(m1, 0.f));
                }
            }
        }

        if (pre) {
            xsp[(p + 1) & 1][tid] = pack_hl(f0);
            if (tid + BLOCK < 784) xsp[(p + 1) & 1][tid + BLOCK] = pack_hl(f1);
        }
        __syncthreads();
    } // p

    {
        const unsigned short* ewt = ws + EWT_OFF;
        const int kh = wid >> 2;
        const int ntE = wid & 3;
        const int bc = ntE * 16 + l15;
        const int arow = l15 & (IPB - 1);
        f32x4 acc = {0.f, 0.f, 0.f, 0.f};
        const int ks0 = kh * 25;
        for (int ks = ks0; ks < ks0 + 25; ++ks) {
            const short8 af = *(const short8*)&featbuf[arow * FB_STRIDE + ks * 32 + lg * 8];
            const short8 bf = *(const short8*)&ewt[(ks * 64 + bc) * 32 + lg * 8];
            acc = __builtin_amdgcn_mfma_f32_16x16x32_bf16(af, bf, acc, 0, 0, 0);
        }
        if (lane < 16 && bc < 56) {
            allC[kh][0 * 56 + bc] = acc.x;
            allC[kh][1 * 56 + bc] = acc.y;
            allC[kh][2 * 56 + bc] = acc.z;
            allC[kh][3 * 56 + bc] = acc.w;
        }
    }
    __syncthreads();

    if (tid < IPB) {
        const int img = img0 + tid;
        if (img < B) {
            float gv[5], mx = -1e30f;
            #pragma unroll
            for (int g = 0; g < 5; g++) {
                gv[g] = allC[0][tid * 56 + 50 + g] + allC[1][tid * 56 + 50 + g] + gb[g];
                mx = fmaxf(mx, gv[g]);
            }
            float ssum = 0.f;
            #pragma unroll
            for (int g = 0; g < 5; g++) { gv[g] = expf(gv[g] - mx); ssum += gv[g]; }
            const float inv = 1.f / ssum;
            #pragma unroll
            for (int g = 0; g < 5; g++) gv[g] *= inv;

            int idx0, idx1, idx2; float wv0, wv1, wv2;
            unsigned usedMask = 0;
            {
                int bi = 0; float bv = -1e30f;
                #pragma unroll
                for (int g = 0; g < 5; g++)
                    if (gv[g] > bv) { bv = gv[g]; bi = g; }
                idx0 = bi; wv0 = bv; usedMask |= (1u << bi);
            }
            {
                int bi = 0; float bv = -1e30f;
                #pragma unroll
                for (int g = 0; g < 5; g++)
                    if (!(usedMask & (1u << g)) && gv[g] > bv) { bv = gv[g]; bi = g; }
                idx1 = bi; wv1 = bv; usedMask |= (1u << bi);
            }
            {
                int bi = 0; float bv = -1e30f;
                #pragma unroll
                for (int g = 0; g < 5; g++)
                    if (!(usedMask & (1u << g)) && gv[g] > bv) { bv = gv[g]; bi = g; }
                idx2 = bi; wv2 = bv;
            }
            float comb[10];
            #pragma unroll
            for (int cc = 0; cc < 10; cc++) {
                comb[cc] = wv0 * (allC[0][tid * 56 + idx0 * 10 + cc] + allC[1][tid * 56 + idx0 * 10 + cc] + eb[idx0 * 10 + cc])
                         + wv1 * (allC[0][tid * 56 + idx1 * 10 + cc] + allC[1][tid * 56 + idx1 * 10 + cc] + eb[idx1 * 10 + cc])
                         + wv2 * (allC[0][tid * 56 + idx2 * 10 + cc] + allC[1][tid * 56 + idx2 * 10 + cc] + eb[idx2 * 10 + cc]);
            }
            float m2 = -1e30f;
            #pragma unroll
            for (int cc = 0; cc < 10; cc++) m2 = fmaxf(m2, comb[cc]);
            float e[10], s2 = 0.f;
            #pragma unroll
            for (int cc = 0; cc < 10; cc++) { e[cc] = expf(comb[cc] - m2); s2 += e[cc]; }
            const float inv2 = 1.f / s2;
            #pragma unroll
            for (int cc = 0; cc < 10; cc++) out[(size_t)img * 10 + cc] = e[cc] * inv2;
        }
    }
}

extern "C" void kernel_launch(void* const* d_in, const int* in_sizes, int n_in,
                              void* d_out, int out_size, void* d_ws, size_t ws_size,
                              hipStream_t stream) {
    const float* x   = (const float*)d_in[0];
    const float* w1  = (const float*)d_in[1];
    const float* b1  = (const float*)d_in[2];
    const float* w2  = (const float*)d_in[3];
    const float* b2  = (const float*)d_in[4];
    const float* gw  = (const float*)d_in[5];
    const float* gb  = (const float*)d_in[6];
    const float* ew  = (const float*)d_in[7];
    const float* eb  = (const float*)d_in[8];
    float* out = (float*)d_out;
    const int B = in_sizes[0] / 784;

    unsigned short* ws = (unsigned short*)d_ws;
    const size_t ws_full = ((size_t)WS_SHORTS + (size_t)B * 1600) * sizeof(unsigned short);

    moe_prep<<<(WS_SHORTS + 255) / 256, 256, 0, stream>>>(w2, gw, ew, w1, ws);
    if (ws_size >= ws_full) {
        moe_conv<<<(B + IPB - 1) / IPB, BLOCK, 0, stream>>>(x, b1, b2, ws, ws + FEAT_OFF, B);
        moe_expert<<<(B + EIPB - 1) / EIPB, BLOCK, 0, stream>>>(ws, gb, eb, out, B);
    } else {
        moe_main_fused<<<(B + IPB - 1) / IPB, BLOCK, 0, stream>>>(x, b1, b2, gb, eb, ws, out, B);
    }
}

// Round 12
// 81.355 us; speedup vs baseline: 2.7894x; 1.2045x over previous
//
#include <hip/hip_runtime.h>
#include <hip/hip_bf16.h>

#define BLOCK 512
#define IPB 8            // images per block (conv kernel)
#define EIPB 16          // images per block (expert kernel)
#define FB_STRIDE 1616   // fused-path featbuf stride (shorts)
#define ES_STRIDE 1608   // expert featS stride: 804 dw = 4 mod 32 -> 16-row reads ~2-way
#define H1_STRIDE 40     // h1p row stride in shorts: 80 B, 16B-aligned

// ws layout (shorts):
#define W2T_OFF 0        // [kpos=9][oc=64][j=32]  (j = ic-pair-interleaved)   18432
#define EWT_OFF 18432    // [ks=50][n=64][k=32] experts+gate (k perm'd)        102400
#define W1C_OFF 120832   // [n=32][k=32] conv1 B: k0-8 w1hi, k9-17 w1lo, rest 0
#define WS_SHORTS 121856
#define FEAT_OFF 121856  // [B][1600] bf16 feat (k perm'd) — full path only

typedef __attribute__((ext_vector_type(8))) short short8;
typedef __attribute__((ext_vector_type(4))) float f32x4;

#define SEL_LO 0x05040100u   // perm(y,x,SEL_LO) = (x&0xffff)|(y<<16) : low halves
#define SEL_HI 0x07060302u   // perm(y,x,SEL_HI) = (x>>16)|(y&0xffff0000)

static __device__ __forceinline__ unsigned short f2bf(float f) {
    unsigned int u = __builtin_bit_cast(unsigned int, f);
    u = (u + 0x7FFFu + ((u >> 16) & 1u)) >> 16;   // RNE
    return (unsigned short)u;
}
static __device__ __forceinline__ float bf2f(unsigned short h) {
    unsigned int u = ((unsigned int)h) << 16;
    return __builtin_bit_cast(float, u);
}
// single-instruction RNE pack: low16 = bf16(a), high16 = bf16(b)
static __device__ __forceinline__ unsigned int cvtpk(float a, float b) {
    unsigned int r;
    asm("v_cvt_pk_bf16_f32 %0, %1, %2" : "=v"(r) : "v"(a), "v"(b));
    return r;
}

// ---------------- prep kernel: build bf16 weight layouts in d_ws ----------------
__global__ void moe_prep(const float* __restrict__ w2, const float* __restrict__ gw,
                         const float* __restrict__ ew, const float* __restrict__ w1,
                         unsigned short* __restrict__ ws) {
    int i = blockIdx.x * 256 + threadIdx.x;
    if (i < 18432) {
        int kpos = i >> 11, rem = i & 2047, oc = rem >> 5, j = rem & 31;
        int ic = ((j & 1) << 4) | (j >> 1);        // h1p pair-interleave: j=2*l+h <-> ic=h*16+l
        ws[W2T_OFF + i] = f2bf(w2[(kpos * 32 + ic) * 64 + oc]);
    }
    int j2 = i - EWT_OFF;
    if (j2 >= 0 && j2 < 102400) {
        int ks = j2 >> 11, rem = j2 & 2047, n = rem >> 5, k = rem & 31;
        int kk = ks * 32 + k;                      // permuted flatten index
        int wv = kk >> 6, jj = kk & 63;
        int r = jj & 31;
        int oc = ((jj >> 5) << 5) | ((r & 1) << 4) | (r >> 1);   // feat pair-interleave
        int d = wv * 64 + oc;                      // original flatten dim
        float v = 0.f;
        if (n < 50)      v = ew[(n / 10) * 16000 + d * 10 + (n % 10)];
        else if (n < 55) v = gw[d * 5 + (n - 50)];
        ws[EWT_OFF + j2] = f2bf(v);
    }
    int p = i - W1C_OFF;
    if (p >= 0 && p < 1024) {
        // conv1 B: k0-8 = w1hi(tap k), k9-17 = w1lo(tap k-9), k18-31 = 0
        int n = p >> 5, k = p & 31;
        unsigned short val = 0;
        if (k < 18) {
            int t = (k < 9) ? k : k - 9;
            float w = w1[t * 32 + n];
            unsigned short hi = f2bf(w);
            val = (k >= 9) ? f2bf(w - bf2f(hi)) : hi;
        }
        ws[W1C_OFF + p] = val;
    }
}

// ---------------- conv kernel: conv1+pool -> conv2+pool -> feat (global) ----------------
// NOTE: this toolchain treats __launch_bounds__ arg2 as min BLOCKS/CU (CUDA semantics).
// N=3 -> 85-VGPR cap (3 blocks/CU; occupancy counter showed wave count isn't the limiter).
__global__ __launch_bounds__(BLOCK, 3)
void moe_conv(const float* __restrict__ x, const float* __restrict__ b1,
              const float* __restrict__ b2, const unsigned short* __restrict__ ws,
              unsigned short* __restrict__ feat, int B)
{
    __shared__ unsigned int xsp[2][784];                        // bf16(x) dup-packed, 6272 B
    __shared__ __align__(16) unsigned short h1p[2][169 * H1_STRIDE];   // 27040 B
    __shared__ float b1s[32];
    __shared__ float b2s[64];

    const int tid  = threadIdx.x;
    const int wid  = tid >> 6;
    const int lane = tid & 63;
    const int l15  = lane & 15;
    const int lg   = lane >> 4;

    if (tid < 32) b1s[tid] = b1[tid];
    if (tid < 64) b2s[tid] = b2[tid];

    // conv2: wave owns M-tiles {mt0, mt0+4} x N-tiles {n0, n0+1}
    const int mt0 = wid >> 1;
    const int n0  = (wid & 1) * 2;
    short8 bfA[9], bfB[9];
    #pragma unroll
    for (int kp = 0; kp < 9; kp++) {
        bfA[kp] = *(const short8*)&ws[W2T_OFF + (kp * 64 + n0 * 16 + l15) * 32 + lg * 8];
        bfB[kp] = *(const short8*)&ws[W2T_OFF + (kp * 64 + (n0 + 1) * 16 + l15) * 32 + lg * 8];
    }
    const short8 c1f0 = *(const short8*)&ws[W1C_OFF + l15 * 32 + lg * 8];
    const short8 c1f1 = *(const short8*)&ws[W1C_OFF + (16 + l15) * 32 + lg * 8];

    // ---- image-invariant conv1 addressing (hoisted out of image loop) ----
    int xoff1[6], hoff1[6];
    bool val1[6];
    #pragma unroll
    for (int j = 0; j < 6; ++j) {
        const int mt = wid + 8 * j;
        int wsrc = mt * 4 + (l15 >> 2); if (wsrc > 168) wsrc = 168;
        const int s = l15 & 3;
        const int cy = 2 * (wsrc / 13) + (s >> 1);
        const int cx = 2 * (wsrc % 13) + (s & 1);
        xoff1[j] = cy * 28 + cx;
        const int window = mt * 4 + lg;
        val1[j] = (mt < 43) && (window < 169);
        hoff1[j] = (window < 169 ? window : 0) * H1_STRIDE + 2 * l15;
    }
    // ---- image-invariant conv2 addressing ----
    int aoff2[2], foff2[2];
    bool val2[2];
    #pragma unroll
    for (int mi = 0; mi < 2; ++mi) {
        const int mt = mt0 + mi * 4;
        const int m = mt * 16 + l15;
        int wsrc = m >> 2; if (wsrc > 24) wsrc = 24;
        const int s = m & 3;
        const int cy = 2 * (wsrc / 5) + (s >> 1);
        const int cx = 2 * (wsrc % 5) + (s & 1);
        aoff2[mi] = (cy * 13 + cx) * (H1_STRIDE * 2) + lg * 16;   // byte offset into h1p
        const int wv = mt * 4 + lg;
        val2[mi] = (wv < 25);
        foff2[mi] = (wv < 25 ? wv : 0) * 64 + ((n0 >> 1) << 5) + 2 * l15;
    }

    const int img0 = blockIdx.x * IPB;
    {   // prologue: stage image 0 (bf16 dup-packed, 1 cvt_pk per element)
        int im = img0 < B ? img0 : B - 1;
        const float* xg = x + (size_t)im * 784;
        xsp[0][tid] = cvtpk(xg[tid], xg[tid]);
        if (tid + BLOCK < 784) xsp[0][tid + BLOCK] = cvtpk(xg[tid + BLOCK], xg[tid + BLOCK]);
    }
    __syncthreads();

    // software-pipelined phases: phase p = conv2(img p-1) || conv1(img p)
    #pragma unroll
    for (int p = 0; p <= IPB; ++p) {
        const bool do_c1 = (p < IPB);
        const bool do_c2 = (p >= 1);
        const bool pre   = (p + 1 < IPB);

        float f0 = 0.f, f1 = 0.f;
        if (pre) {
            int im2 = img0 + p + 1; if (im2 >= B) im2 = B - 1;
            const float* xg2 = x + (size_t)im2 * 784;
            f0 = xg2[tid];
            if (tid + BLOCK < 784) f1 = xg2[tid + BLOCK];
        }

        // conv2(img p-1): implicit-GEMM MFMA, h1p[(p-1)&1] -> global feat
        if (do_c2) {
            const int it = p - 1;
            const int img = img0 + it;
            const unsigned short* h1cur = h1p[it & 1];
            unsigned short* frow = feat + (size_t)img * 1600;
            #pragma unroll
            for (int mi = 0; mi < 2; ++mi) {
                const char* abase = (const char*)h1cur + aoff2[mi];
                f32x4 a0 = {0.f, 0.f, 0.f, 0.f};
                f32x4 a1 = {0.f, 0.f, 0.f, 0.f};
                #pragma unroll
                for (int kp = 0; kp < 9; kp++) {
                    const int ky = kp / 3, kx = kp % 3;
                    const short8 af = *(const short8*)(abase + (ky * 13 + kx) * (H1_STRIDE * 2));
                    a0 = __builtin_amdgcn_mfma_f32_16x16x32_bf16(af, bfA[kp], a0, 0, 0, 0);
                    a1 = __builtin_amdgcn_mfma_f32_16x16x32_bf16(af, bfB[kp], a1, 0, 0, 0);
                }
                if (val2[mi] && img < B) {
                    const int oc0 = n0 * 16 + l15;
                    const float m0 = fmaxf(fmaxf(a0.x, a0.y), fmaxf(a0.z, a0.w)) + b2s[oc0];
                    const float m1 = fmaxf(fmaxf(a1.x, a1.y), fmaxf(a1.z, a1.w)) + b2s[oc0 + 16];
                    *(unsigned int*)&frow[foff2[mi]] = cvtpk(fmaxf(m0, 0.f), fmaxf(m1, 0.f));
                }
            }
        }

        // conv1(img p): reg-built A-fragments from xsp[p&1], MFMA, pool -> h1p[p&1]
        if (do_c1) {
            const unsigned int* xcur = xsp[p & 1];
            unsigned short* h1dst = h1p[p & 1];
            #pragma unroll
            for (int j = 0; j < 6; ++j) {
                if (wid + 8 * j < 43) {
                    const unsigned int* xb = xcur + xoff1[j];
                    const unsigned int t0 = xb[0],  t1 = xb[1],  t2 = xb[2];
                    const unsigned int t3 = xb[28], t4 = xb[29], t5 = xb[30];
                    const unsigned int t6 = xb[56], t7 = xb[57], t8 = xb[58];
                    // A row: k0-8 + k9-17 = xh taps (w1hi + w1lo); k18-31 hit zero weights
                    unsigned int a0, a1, a2, a3;
                    if (lg == 0)      { a0 = __builtin_amdgcn_perm(t1, t0, SEL_LO);
                                        a1 = __builtin_amdgcn_perm(t3, t2, SEL_LO);
                                        a2 = __builtin_amdgcn_perm(t5, t4, SEL_LO);
                                        a3 = __builtin_amdgcn_perm(t7, t6, SEL_LO); }
                    else if (lg == 1) { a0 = __builtin_amdgcn_perm(t0, t8, SEL_LO);
                                        a1 = __builtin_amdgcn_perm(t2, t1, SEL_LO);
                                        a2 = __builtin_amdgcn_perm(t4, t3, SEL_LO);
                                        a3 = __builtin_amdgcn_perm(t6, t5, SEL_LO); }
                    else if (lg == 2) { a0 = __builtin_amdgcn_perm(t8, t7, SEL_LO);
                                        a1 = 0u; a2 = 0u; a3 = 0u; }
                    else              { a0 = 0u; a1 = 0u; a2 = 0u; a3 = 0u; }
                    const uint4 av = make_uint4(a0, a1, a2, a3);
                    const short8 af = __builtin_bit_cast(short8, av);
                    f32x4 p0 = {0.f, 0.f, 0.f, 0.f};
                    f32x4 p1 = {0.f, 0.f, 0.f, 0.f};
                    p0 = __builtin_amdgcn_mfma_f32_16x16x32_bf16(af, c1f0, p0, 0, 0, 0);
                    p1 = __builtin_amdgcn_mfma_f32_16x16x32_bf16(af, c1f1, p1, 0, 0, 0);
                    if (val1[j]) {
                        const float m0 = fmaxf(fmaxf(p0.x, p0.y), fmaxf(p0.z, p0.w)) + b1s[l15];
                        const float m1 = fmaxf(fmaxf(p1.x, p1.y), fmaxf(p1.z, p1.w)) + b1s[16 + l15];
                        *(unsigned int*)&h1dst[hoff1[j]] = cvtpk(fmaxf(m0, 0.f), fmaxf(m1, 0.f));
                    }
                }
            }
        }

        if (pre) {
            xsp[(p + 1) & 1][tid] = cvtpk(f0, f0);
            if (tid + BLOCK < 784) xsp[(p + 1) & 1][tid + BLOCK] = cvtpk(f1, f1);
        }
        __syncthreads();
    } // p
}

// ---------------- expert kernel: [B x 1600] @ [1600 x 55] + gate/top3/softmax ----------------
__global__ __launch_bounds__(BLOCK, 2)
void moe_expert(const unsigned short* __restrict__ ws, const float* __restrict__ gb,
                const float* __restrict__ eb, float* __restrict__ out, int B)
{
    __shared__ __align__(16) unsigned short featS[EIPB * ES_STRIDE];   // 51456 B
    __shared__ float allC[2][EIPB][64];                                 // 8192 B

    const int tid  = threadIdx.x;
    const int wid  = tid >> 6;
    const int lane = tid & 63;
    const int l15  = lane & 15;
    const int lg   = lane >> 4;

    const unsigned short* feat = ws + FEAT_OFF;
    const unsigned short* ewt  = ws + EWT_OFF;
    const int img0 = blockIdx.x * EIPB;

    for (int i = tid; i < EIPB * 800; i += BLOCK) {
        const int r = i / 800, c = i - r * 800;
        const int img = img0 + r;
        unsigned int v = 0u;
        if (img < B) v = *(const unsigned int*)&feat[(size_t)img * 1600 + 2 * c];
        *(unsigned int*)&featS[r * ES_STRIDE + 2 * c] = v;
    }
    __syncthreads();

    {
        const int kh  = wid >> 2;
        const int ntE = wid & 3;
        const int bc  = ntE * 16 + l15;
        f32x4 acc = {0.f, 0.f, 0.f, 0.f};
        const int ks0 = kh * 25;
        for (int ks = ks0; ks < ks0 + 25; ++ks) {
            const short8 af = *(const short8*)&featS[l15 * ES_STRIDE + ks * 32 + lg * 8];
            const short8 bf = *(const short8*)&ewt[(ks * 64 + bc) * 32 + lg * 8];
            acc = __builtin_amdgcn_mfma_f32_16x16x32_bf16(af, bf, acc, 0, 0, 0);
        }
        const int r0 = lg * 4;
        allC[kh][r0 + 0][bc] = acc.x;
        allC[kh][r0 + 1][bc] = acc.y;
        allC[kh][r0 + 2][bc] = acc.z;
        allC[kh][r0 + 3][bc] = acc.w;
    }
    __syncthreads();

    if (tid < EIPB) {
        const int img = img0 + tid;
        if (img < B) {
            float gv[5], mx = -1e30f;
            #pragma unroll
            for (int g = 0; g < 5; g++) {
                gv[g] = allC[0][tid][50 + g] + allC[1][tid][50 + g] + gb[g];
                mx = fmaxf(mx, gv[g]);
            }
            float ssum = 0.f;
            #pragma unroll
            for (int g = 0; g < 5; g++) { gv[g] = expf(gv[g] - mx); ssum += gv[g]; }
            const float inv = 1.f / ssum;
            #pragma unroll
            for (int g = 0; g < 5; g++) gv[g] *= inv;

            int idx0, idx1, idx2; float wv0, wv1, wv2;
            unsigned usedMask = 0;
            {
                int bi = 0; float bv = -1e30f;
                #pragma unroll
                for (int g = 0; g < 5; g++)
                    if (gv[g] > bv) { bv = gv[g]; bi = g; }   // strict >: lowest idx on tie
                idx0 = bi; wv0 = bv; usedMask |= (1u << bi);
            }
            {
                int bi = 0; float bv = -1e30f;
                #pragma unroll
                for (int g = 0; g < 5; g++)
                    if (!(usedMask & (1u << g)) && gv[g] > bv) { bv = gv[g]; bi = g; }
                idx1 = bi; wv1 = bv; usedMask |= (1u << bi);
            }
            {
                int bi = 0; float bv = -1e30f;
                #pragma unroll
                for (int g = 0; g < 5; g++)
                    if (!(usedMask & (1u << g)) && gv[g] > bv) { bv = gv[g]; bi = g; }
                idx2 = bi; wv2 = bv;
            }
            float comb[10];
            #pragma unroll
            for (int cc = 0; cc < 10; cc++) {
                comb[cc] = wv0 * (allC[0][tid][idx0 * 10 + cc] + allC[1][tid][idx0 * 10 + cc] + eb[idx0 * 10 + cc])
                         + wv1 * (allC[0][tid][idx1 * 10 + cc] + allC[1][tid][idx1 * 10 + cc] + eb[idx1 * 10 + cc])
                         + wv2 * (allC[0][tid][idx2 * 10 + cc] + allC[1][tid][idx2 * 10 + cc] + eb[idx2 * 10 + cc]);
            }
            float m2 = -1e30f;
            #pragma unroll
            for (int cc = 0; cc < 10; cc++) m2 = fmaxf(m2, comb[cc]);
            float e[10], s2 = 0.f;
            #pragma unroll
            for (int cc = 0; cc < 10; cc++) { e[cc] = expf(comb[cc] - m2); s2 += e[cc]; }
            const float inv2 = 1.f / s2;
            #pragma unroll
            for (int cc = 0; cc < 10; cc++) out[(size_t)img * 10 + cc] = e[cc] * inv2;
        }
    }
}

// ---------------- fused fallback (round-10 style, used when ws can't hold feat) ----------------
__global__ __launch_bounds__(BLOCK, 3)
void moe_main_fused(const float* __restrict__ x, const float* __restrict__ b1,
                    const float* __restrict__ b2, const float* __restrict__ gb,
                    const float* __restrict__ eb, const unsigned short* __restrict__ ws,
                    float* __restrict__ out, int B)
{
    __shared__ unsigned int xsp[2][784];
    __shared__ __align__(16) unsigned short h1p[2][169 * H1_STRIDE];
    __shared__ __align__(16) unsigned short featbuf[4 * FB_STRIDE];
    __shared__ float b1s[32];
    __shared__ float b2s[64];
    __shared__ float allC[2][4 * 56];

    const int tid  = threadIdx.x;
    const int wid  = tid >> 6;
    const int lane = tid & 63;
    const int l15  = lane & 15;
    const int lg   = lane >> 4;

    if (tid < 32) b1s[tid] = b1[tid];
    if (tid < 64) b2s[tid] = b2[tid];

    const int mt0 = wid >> 1;
    const int n0  = (wid & 1) * 2;
    short8 bfA[9], bfB[9];
    #pragma unroll
    for (int kp = 0; kp < 9; kp++) {
        bfA[kp] = *(const short8*)&ws[W2T_OFF + (kp * 64 + n0 * 16 + l15) * 32 + lg * 8];
        bfB[kp] = *(const short8*)&ws[W2T_OFF + (kp * 64 + (n0 + 1) * 16 + l15) * 32 + lg * 8];
    }
    const short8 c1f0 = *(const short8*)&ws[W1C_OFF + l15 * 32 + lg * 8];
    const short8 c1f1 = *(const short8*)&ws[W1C_OFF + (16 + l15) * 32 + lg * 8];

    const int img0 = blockIdx.x * 4;
    {
        int im = img0 < B ? img0 : B - 1;
        const float* xg = x + (size_t)im * 784;
        xsp[0][tid] = cvtpk(xg[tid], xg[tid]);
        if (tid + BLOCK < 784) xsp[0][tid + BLOCK] = cvtpk(xg[tid + BLOCK], xg[tid + BLOCK]);
    }
    __syncthreads();

    #pragma unroll
    for (int p = 0; p <= 4; ++p) {
        const bool do_c1 = (p < 4);
        const bool do_c2 = (p >= 1);
        const bool pre   = (p + 1 < 4);

        float f0 = 0.f, f1 = 0.f;
        if (pre) {
            int im2 = img0 + p + 1; if (im2 >= B) im2 = B - 1;
            const float* xg2 = x + (size_t)im2 * 784;
            f0 = xg2[tid];
            if (tid + BLOCK < 784) f1 = xg2[tid + BLOCK];
        }

        if (do_c2) {
            const int it = p - 1;
            const unsigned short* h1cur = h1p[it & 1];
            #pragma unroll
            for (int mi = 0; mi < 2; ++mi) {
                const int mt = mt0 + mi * 4;
                const int m = mt * 16 + l15;
                int wsrc = m >> 2; if (wsrc > 24) wsrc = 24;
                const int s = m & 3;
                const int cy = 2 * (wsrc / 5) + (s >> 1);
                const int cx = 2 * (wsrc % 5) + (s & 1);
                const char* abase = (const char*)h1cur + (cy * 13 + cx) * (H1_STRIDE * 2) + lg * 16;
                f32x4 a0 = {0.f, 0.f, 0.f, 0.f};
                f32x4 a1 = {0.f, 0.f, 0.f, 0.f};
                #pragma unroll
                for (int kp = 0; kp < 9; kp++) {
                    const int ky = kp / 3, kx = kp % 3;
                    const short8 af = *(const short8*)(abase + (ky * 13 + kx) * (H1_STRIDE * 2));
                    a0 = __builtin_amdgcn_mfma_f32_16x16x32_bf16(af, bfA[kp], a0, 0, 0, 0);
                    a1 = __builtin_amdgcn_mfma_f32_16x16x32_bf16(af, bfB[kp], a1, 0, 0, 0);
                }
                const int wv = mt * 4 + lg;
                if (wv < 25) {
                    const int oc0 = n0 * 16 + l15;
                    const float m0 = fmaxf(fmaxf(a0.x, a0.y), fmaxf(a0.z, a0.w)) + b2s[oc0];
                    const float m1 = fmaxf(fmaxf(a1.x, a1.y), fmaxf(a1.z, a1.w)) + b2s[oc0 + 16];
                    *(unsigned int*)&featbuf[it * FB_STRIDE + wv * 64 + ((n0 >> 1) << 5) + 2 * l15] =
                        cvtpk(fmaxf(m0, 0.f), fmaxf(m1, 0.f));
                }
            }
        }

        if (do_c1) {
            const unsigned int* xcur = xsp[p & 1];
            unsigned short* h1dst = h1p[p & 1];
            for (int mt = wid; mt < 43; mt += 8) {
                int wsrc = mt * 4 + (l15 >> 2); if (wsrc > 168) wsrc = 168;
                const int s  = l15 & 3;
                const int cy = 2 * (wsrc / 13) + (s >> 1);
                const int cx = 2 * (wsrc % 13) + (s & 1);
                const unsigned int* xb = &xcur[cy * 28 + cx];
                const unsigned int t0 = xb[0],  t1 = xb[1],  t2 = xb[2];
                const unsigned int t3 = xb[28], t4 = xb[29], t5 = xb[30];
                const unsigned int t6 = xb[56], t7 = xb[57], t8 = xb[58];
                unsigned int a0, a1, a2, a3;
                if (lg == 0)      { a0 = __builtin_amdgcn_perm(t1, t0, SEL_LO);
                                    a1 = __builtin_amdgcn_perm(t3, t2, SEL_LO);
                                    a2 = __builtin_amdgcn_perm(t5, t4, SEL_LO);
                                    a3 = __builtin_amdgcn_perm(t7, t6, SEL_LO); }
                else if (lg == 1) { a0 = __builtin_amdgcn_perm(t0, t8, SEL_LO);
                                    a1 = __builtin_amdgcn_perm(t2, t1, SEL_LO);
                                    a2 = __builtin_amdgcn_perm(t4, t3, SEL_LO);
                                    a3 = __builtin_amdgcn_perm(t6, t5, SEL_LO); }
                else if (lg == 2) { a0 = __builtin_amdgcn_perm(t8, t7, SEL_LO);
                                    a1 = 0u; a2 = 0u; a3 = 0u; }
                else              { a0 = 0u; a1 = 0u; a2 = 0u; a3 = 0u; }
                const uint4 av = make_uint4(a0, a1, a2, a3);
                const short8 af = __builtin_bit_cast(short8, av);
                f32x4 p0 = {0.f, 0.f, 0.f, 0.f};
                f32x4 p1 = {0.f, 0.f, 0.f, 0.f};
                p0 = __builtin_amdgcn_mfma_f32_16x16x32_bf16(af, c1f0, p0, 0, 0, 0);
                p1 = __builtin_amdgcn_mfma_f32_16x16x32_bf16(af, c1f1, p1, 0, 0, 0);
                const int window = mt * 4 + lg;
                if (window < 169) {
                    const float m0 = fmaxf(fmaxf(p0.x, p0.y), fmaxf(p0.z, p0.w)) + b1s[l15];
                    const float m1 = fmaxf(fmaxf(p1.x, p1.y), fmaxf(p1.z, p1.w)) + b1s[16 + l15];
                    *(unsigned int*)&h1dst[window * H1_STRIDE + 2 * l15] =
                        cvtpk(fmaxf(m0, 0.f), fmaxf(m1, 0.f));
                }
            }
        }

        if (pre) {
            xsp[(p + 1) & 1][tid] = cvtpk(f0, f0);
            if (tid + BLOCK < 784) xsp[(p + 1) & 1][tid + BLOCK] = cvtpk(f1, f1);
        }
        __syncthreads();
    } // p

    {
        const unsigned short* ewt = ws + EWT_OFF;
        const int kh = wid >> 2;
        const int ntE = wid & 3;
        const int bc = ntE * 16 + l15;
        const int arow = l15 & 3;
        f32x4 acc = {0.f, 0.f, 0.f, 0.f};
        const int ks0 = kh * 25;
        for (int ks = ks0; ks < ks0 + 25; ++ks) {
            const short8 af = *(const short8*)&featbuf[arow * FB_STRIDE + ks * 32 + lg * 8];
            const short8 bf = *(const short8*)&ewt[(ks * 64 + bc) * 32 + lg * 8];
            acc = __builtin_amdgcn_mfma_f32_16x16x32_bf16(af, bf, acc, 0, 0, 0);
        }
        if (lane < 16 && bc < 56) {
            allC[kh][0 * 56 + bc] = acc.x;
            allC[kh][1 * 56 + bc] = acc.y;
            allC[kh][2 * 56 + bc] = acc.z;
            allC[kh][3 * 56 + bc] = acc.w;
        }
    }
    __syncthreads();

    if (tid < 4) {
        const int img = img0 + tid;
        if (img < B) {
            float gv[5], mx = -1e30f;
            #pragma unroll
            for (int g = 0; g < 5; g++) {
                gv[g] = allC[0][tid * 56 + 50 + g] + allC[1][tid * 56 + 50 + g] + gb[g];
                mx = fmaxf(mx, gv[g]);
            }
            float ssum = 0.f;
            #pragma unroll
            for (int g = 0; g < 5; g++) { gv[g] = expf(gv[g] - mx); ssum += gv[g]; }
            const float inv = 1.f / ssum;
            #pragma unroll
            for (int g = 0; g < 5; g++) gv[g] *= inv;

            int idx0, idx1, idx2; float wv0, wv1, wv2;
            unsigned usedMask = 0;
            {
                int bi = 0; float bv = -1e30f;
                #pragma unroll
                for (int g = 0; g < 5; g++)
                    if (gv[g] > bv) { bv = gv[g]; bi = g; }
                idx0 = bi; wv0 = bv; usedMask |= (1u << bi);
            }
            {
                int bi = 0; float bv = -1e30f;
                #pragma unroll
                for (int g = 0; g < 5; g++)
                    if (!(usedMask & (1u << g)) && gv[g] > bv) { bv = gv[g]; bi = g; }
                idx1 = bi; wv1 = bv; usedMask |= (1u << bi);
            }
            {
                int bi = 0; float bv = -1e30f;
                #pragma unroll
                for (int g = 0; g < 5; g++)
                    if (!(usedMask & (1u << g)) && gv[g] > bv) { bv = gv[g]; bi = g; }
                idx2 = bi; wv2 = bv;
            }
            float comb[10];
            #pragma unroll
            for (int cc = 0; cc < 10; cc++) {
                comb[cc] = wv0 * (allC[0][tid * 56 + idx0 * 10 + cc] + allC[1][tid * 56 + idx0 * 10 + cc] + eb[idx0 * 10 + cc])
                         + wv1 * (allC[0][tid * 56 + idx1 * 10 + cc] + allC[1][tid * 56 + idx1 * 10 + cc] + eb[idx1 * 10 + cc])
                         + wv2 * (allC[0][tid * 56 + idx2 * 10 + cc] + allC[1][tid * 56 + idx2 * 10 + cc] + eb[idx2 * 10 + cc]);
            }
            float m2 = -1e30f;
            #pragma unroll
            for (int cc = 0; cc < 10; cc++) m2 = fmaxf(m2, comb[cc]);
            float e[10], s2 = 0.f;
            #pragma unroll
            for (int cc = 0; cc < 10; cc++) { e[cc] = expf(comb[cc] - m2); s2 += e[cc]; }
            const float inv2 = 1.f / s2;
            #pragma unroll
            for (int cc = 0; cc < 10; cc++) out[(size_t)img * 10 + cc] = e[cc] * inv2;
        }
    }
}

extern "C" void kernel_launch(void* const* d_in, const int* in_sizes, int n_in,
                              void* d_out, int out_size, void* d_ws, size_t ws_size,
                              hipStream_t stream) {
    const float* x   = (const float*)d_in[0];
    const float* w1  = (const float*)d_in[1];
    const float* b1  = (const float*)d_in[2];
    const float* w2  = (const float*)d_in[3];
    const float* b2  = (const float*)d_in[4];
    const float* gw  = (const float*)d_in[5];
    const float* gb  = (const float*)d_in[6];
    const float* ew  = (const float*)d_in[7];
    const float* eb  = (const float*)d_in[8];
    float* out = (float*)d_out;
    const int B = in_sizes[0] / 784;

    unsigned short* ws = (unsigned short*)d_ws;
    const size_t ws_full = ((size_t)WS_SHORTS + (size_t)B * 1600) * sizeof(unsigned short);

    moe_prep<<<(WS_SHORTS + 255) / 256, 256, 0, stream>>>(w2, gw, ew, w1, ws);
    if (ws_size >= ws_full) {
        moe_conv<<<(B + IPB - 1) / IPB, BLOCK, 0, stream>>>(x, b1, b2, ws, ws + FEAT_OFF, B);
        moe_expert<<<(B + EIPB - 1) / EIPB, BLOCK, 0, stream>>>(ws, gb, eb, out, B);
    } else {
        moe_main_fused<<<(B + 3) / 4, BLOCK, 0, stream>>>(x, b1, b2, gb, eb, ws, out, B);
    }
}